// Round 21
// baseline (512.593 us; speedup 1.0000x reference)
//
#include <hip/hip_runtime.h>

#define NPROT 20000
#define NDRUG 4000
#define INDRUG 4000
#define NET 128
#define NBASE 32
#define NEMBED 48
#define PDDIM 16
#define H1C 32
#define H2C 16
#define RGCNIN 64
#define EPP 800000
#define EDP 400000
#define EDD 1000000
#define NBLK 256
#define EKCH 160            // 5 k-steps of 32 per chunk
#define KSPLIT 25           // 4000 / 160
#define PBLKS 4035          // ceil(EDD/256) + NET
#define PEDD (PBLKS*256)    // padded edge capacity

typedef __attribute__((ext_vector_type(8))) __bf16 bf16x8;
typedef __attribute__((ext_vector_type(4))) float f32x4;

__device__ __forceinline__ unsigned int f2bf(float f){
  unsigned int u = __float_as_uint(f);
  u += 0x7fffu + ((u >> 16) & 1u);     // RNE
  return u >> 16;
}
__device__ __forceinline__ float bf2f(unsigned int s){
  return __uint_as_float(s << 16);
}
__device__ __forceinline__ unsigned long long pack4(const f32x4& c){
  unsigned long long lo = (unsigned long long)(f2bf(c[0]) | (f2bf(c[1]) << 16));
  unsigned long long hi = (unsigned long long)(f2bf(c[2]) | (f2bf(c[3]) << 16));
  return lo | (hi << 32);
}

// ======================= shared kernels =======================

template<int K, int NC, bool RELU_IN>
__global__ void k_gemm(const float* __restrict__ A, const float* __restrict__ W,
                       float* __restrict__ C, int M){
  __shared__ float Ws[K*NC];
  for(int i = threadIdx.x; i < K*NC; i += 256) Ws[i] = W[i];
  __syncthreads();
  int idx = blockIdx.x*256 + threadIdx.x;
  int row = idx / NC, col = idx % NC;
  if(row >= M) return;
  const float* a = A + row*K;
  float acc = 0.f;
  #pragma unroll
  for(int k = 0; k < K; k++){
    float v = a[k];
    if(RELU_IN) v = fmaxf(v, 0.f);
    acc = fmaf(v, Ws[k*NC + col], acc);
  }
  C[idx] = acc;
}

// h1s = (x_prot @ W1) * dis[row]   (K=64, NC=32)
__global__ void k_gemm_s(const float* __restrict__ A, const float* __restrict__ W,
                         const float* __restrict__ dis, float* __restrict__ C, int M){
  __shared__ float Ws[64*32];
  for(int i = threadIdx.x; i < 64*32; i += 256) Ws[i] = W[i];
  __syncthreads();
  int idx = blockIdx.x*256 + threadIdx.x;
  int row = idx >> 5, col = idx & 31;
  if(row >= M) return;
  const float* a = A + row*64;
  float acc = 0.f;
  #pragma unroll
  for(int k = 0; k < 64; k++)
    acc = fmaf(a[k], Ws[k*32 + col], acc);
  C[idx] = acc * dis[row];
}

__global__ void k_wet(const float* __restrict__ att, const float* __restrict__ basis,
                      float* __restrict__ wet, int inout){
  int gid = blockIdx.x*256 + threadIdx.x;
  if(gid >= NET * inout) return;
  int et = gid / inout, ij = gid % inout;
  float acc = 0.f;
  #pragma unroll
  for(int b = 0; b < NBASE; b++)
    acc = fmaf(att[et*NBASE + b], basis[b*inout + ij], acc);
  wet[gid] = acc;
}

// bf16 fragment build DIRECT from att/basis: wetb1[et][f][l][j], f = kt*2+nt
__global__ void k_wetb1(const float* __restrict__ att, const float* __restrict__ basis,
                        unsigned short* __restrict__ wetb){
  int gid = blockIdx.x*256 + threadIdx.x;
  if(gid >= NET*2048) return;
  int et = gid >> 11, r = gid & 2047;
  int f = r >> 9, l = (r >> 3) & 63, j = r & 7;
  int kt = f >> 1, nt = f & 1;
  int k = kt*32 + ((l >> 4) << 3) + j;
  int c = nt*16 + (l & 15);
  float acc = 0.f;
  #pragma unroll
  for(int b = 0; b < NBASE; b++)
    acc = fmaf(att[et*NBASE + b], basis[b*2048 + k*32 + c], acc);
  wetb[gid] = (unsigned short)f2bf(acc);
}

__global__ void k_wetb2(const float* __restrict__ att, const float* __restrict__ basis,
                        unsigned short* __restrict__ wetb){
  int gid = blockIdx.x*256 + threadIdx.x;
  if(gid >= NET*512) return;
  int et = gid >> 9, r = gid & 511;
  int l = r >> 3, j = r & 7;
  int k = ((l >> 4) << 3) + j;
  int c = l & 15;
  float acc = 0.f;
  #pragma unroll
  for(int b = 0; b < NBASE; b++)
    acc = fmaf(att[et*NBASE + b], basis[b*512 + k*16 + c], acc);
  wetb[gid] = (unsigned short)f2bf(acc);
}

// embed B-fragment table: embb[kt][f][l][j], kt=0..124, f=0..2
__global__ void k_embb(const float* __restrict__ embed, unsigned short* __restrict__ embb){
  int gid = blockIdx.x*256 + threadIdx.x;
  if(gid >= 125*1536) return;
  int kt = gid / 1536, r = gid % 1536;
  int f = r / 512, l = (r >> 3) & 63, j = r & 7;
  int k = kt*32 + ((l >> 4) << 3) + j;
  int c = f*16 + (l & 15);
  embb[gid] = (unsigned short)f2bf(embed[k*48 + c]);
}

// ======================= padded edge layout =======================

__global__ void k_pstart(const int* __restrict__ range, int* __restrict__ pstart,
                         int* __restrict__ pblk){
  __shared__ int ps[NET];
  int t = threadIdx.x;
  int cnt = range[t*2+1] - range[t*2];
  int padc = (cnt + 255) & ~255;
  ps[t] = padc;
  __syncthreads();
  int myoff = 0;
  for(int i = 0; i < t; i++) myoff += ps[i];
  pstart[t] = myoff;
  if(t == NET-1) pstart[NET] = myoff + padc;
  int b0 = myoff >> 8, nb = padc >> 8;
  for(int i = 0; i < nb; i++) pblk[b0 + i] = t;
}

__global__ void k_pmap(const int* __restrict__ et, const int* __restrict__ src,
                       const int* __restrict__ range, const int* __restrict__ pstart,
                       int* __restrict__ psrc, int* __restrict__ pmape){
  int e = blockIdx.x*256 + threadIdx.x;
  if(e >= EDD) return;
  int t = et[e];
  int p = pstart[t] + (e - range[t*2]);
  psrc[p] = src[e];
  pmape[e] = p;
}

// ======================= fast path: CSR build (atomic-batched, no gh) =======================

__global__ void k_count_sub(const int* __restrict__ dst, int ne, int sub,
                            int* __restrict__ cnt){
  int i = blockIdx.x*256 + threadIdx.x;
  if(i < ne) atomicAdd(&cnt[dst[i] - sub], 1);
}

__global__ void k_scan_off(const int* __restrict__ cnt, int* __restrict__ off, int bins){
  __shared__ int ps[1024];
  int t = threadIdx.x;
  int C = (bins + 1023) >> 10;
  int lo = t*C, hi = min(lo + C, bins);
  int s = 0;
  for(int i = lo; i < hi; i++) s += cnt[i];
  ps[t] = s;
  __syncthreads();
  for(int d = 1; d < 1024; d <<= 1){
    int v = (t >= d) ? ps[t-d] : 0;
    __syncthreads();
    ps[t] += v;
    __syncthreads();
  }
  int run = ps[t] - s;   // exclusive
  for(int i = lo; i < hi; i++){ off[i] = run; run += cnt[i]; }
  if(t == 1023) off[bins] = ps[1023];
}

__global__ void k_copy_int(const int* __restrict__ in, int* __restrict__ out, int n){
  int i = blockIdx.x*256 + threadIdx.x;
  if(i < n) out[i] = in[i];
}

// block-batched scatter: LDS count -> claim contiguous base per bin -> scatter
template<int PB>
__global__ void k_scatter_b(const int* __restrict__ dst, const int* __restrict__ src,
                            int ne, int sub, int b0, int* __restrict__ cur,
                            int* __restrict__ outp){
  __shared__ int hcnt[PB];
  for(int i = threadIdx.x; i < PB; i += 256) hcnt[i] = 0;
  __syncthreads();
  int chunk = (ne + NBLK - 1) / NBLK;
  int s0 = blockIdx.x*chunk, s1 = min(s0 + chunk, ne);
  for(int i = s0 + threadIdx.x; i < s1; i += 256){
    int b = dst[i] - sub - b0;
    if(b >= 0 && b < PB) atomicAdd(&hcnt[b], 1);
  }
  __syncthreads();
  for(int i = threadIdx.x; i < PB; i += 256){
    int c = hcnt[i];
    if(c > 0) hcnt[i] = atomicAdd(&cur[b0 + i], c);
  }
  __syncthreads();
  for(int i = s0 + threadIdx.x; i < s1; i += 256){
    int b = dst[i] - sub - b0;
    if(b >= 0 && b < PB){
      int p = atomicAdd(&hcnt[b], 1);
      outp[p] = src[i];
    }
  }
}

__global__ void k_dis_off(const int* __restrict__ off, float* __restrict__ dis, int n){
  int i = blockIdx.x*256 + threadIdx.x;
  if(i < n) dis[i] = rsqrtf((float)(off[i+1] - off[i]) + 1.0f);
}

// ======================= fast path: gathers (block per dst, MLP-unrolled) =======================

// h1s = h1*dis (pre-scaled). h2out written pre-scaled by dis[d] for layer 2.
__global__ void k_gcn_gather1(const float* __restrict__ hs, const float* __restrict__ dis,
                              const int* __restrict__ off, const int* __restrict__ srcperm,
                              const float* __restrict__ b1, const float* __restrict__ W2,
                              float* __restrict__ h2s){
  __shared__ float red[4][32];
  __shared__ float m[32];
  __shared__ float W2s[512];
  int d = blockIdx.x, tid = threadIdx.x;
  for(int i = tid; i < 512; i += 256) W2s[i] = W2[i];
  int col = tid & 31, g = tid >> 5;     // 8 groups
  int o0 = off[d], cnt = off[d+1] - o0;
  float s0 = 0.f, s1 = 0.f, s2 = 0.f, s3 = 0.f;
  int i = g;
  for(; i + 24 < cnt; i += 32){
    int j0 = srcperm[o0 + i],      j1 = srcperm[o0 + i + 8];
    int j2 = srcperm[o0 + i + 16], j3 = srcperm[o0 + i + 24];
    s0 += hs[j0*32 + col]; s1 += hs[j1*32 + col];
    s2 += hs[j2*32 + col]; s3 += hs[j3*32 + col];
  }
  for(; i < cnt; i += 8) s0 += hs[srcperm[o0 + i]*32 + col];
  float s = (s0 + s1) + (s2 + s3);
  s += __shfl_xor(s, 32);
  int wv = tid >> 6, lane = tid & 63;
  if(lane < 32) red[wv][lane] = s;
  __syncthreads();
  float dd = dis[d];
  if(tid < 32){
    float v = (red[0][tid]+red[1][tid]+red[2][tid]+red[3][tid] + hs[d*32 + tid])*dd + b1[tid];
    m[tid] = fmaxf(v, 0.f);
  }
  __syncthreads();
  if(tid < 16){
    float acc = 0.f;
    #pragma unroll
    for(int k = 0; k < 32; k++) acc = fmaf(m[k], W2s[k*16 + tid], acc);
    h2s[d*16 + tid] = acc * dd;       // pre-scale for layer 2
  }
}

// agg2 = (sum_src h2s[src] + h2s[d])*dis[d] + b2   (true agg2, unscaled output)
__global__ void k_gcn_gather2(const float* __restrict__ hs, const float* __restrict__ dis,
                              const int* __restrict__ off, const int* __restrict__ srcperm,
                              const float* __restrict__ b, float* __restrict__ agg){
  __shared__ float red[4][16];
  int d = blockIdx.x;
  int tid = threadIdx.x;
  int col = tid & 15;
  int g = tid >> 4;                    // 16 groups
  int o0 = off[d], cnt = off[d+1] - o0;
  float s0 = 0.f, s1 = 0.f;
  int i = g;
  for(; i + 16 < cnt; i += 32){
    int j0 = srcperm[o0 + i], j1 = srcperm[o0 + i + 16];
    s0 += hs[j0*16 + col];
    s1 += hs[j1*16 + col];
  }
  for(; i < cnt; i += 16) s0 += hs[srcperm[o0 + i]*16 + col];
  float s = s0 + s1;
  s += __shfl_xor(s, 32);
  s += __shfl_xor(s, 16);
  int wv = tid >> 6, lane = tid & 63;
  if(lane < 16) red[wv][lane] = s;
  __syncthreads();
  if(tid < 16){
    float tot = red[0][tid] + red[1][tid] + red[2][tid] + red[3][tid];
    float dd = dis[d];
    agg[d*16 + tid] = (tot + hs[d*16 + tid])*dd + b[tid];
  }
}

__global__ void k_dp_gather(const float* __restrict__ xp2, const int* __restrict__ off,
                            const int* __restrict__ srcperm, const float* __restrict__ hg,
                            float* __restrict__ xd, unsigned short* __restrict__ xdb){
  __shared__ float red[4][16];
  __shared__ float m[16];
  int d = blockIdx.x;
  int tid = threadIdx.x;
  int col = tid & 15, g = tid >> 4;
  int o0 = off[d], cnt = off[d+1] - o0;
  float s0 = 0.f, s1 = 0.f, s2 = 0.f, s3 = 0.f;
  int i = g;
  for(; i + 48 < cnt; i += 64){
    int j0 = srcperm[o0 + i],      j1 = srcperm[o0 + i + 16];
    int j2 = srcperm[o0 + i + 32], j3 = srcperm[o0 + i + 48];
    s0 += xp2[j0*16 + col]; s1 += xp2[j1*16 + col];
    s2 += xp2[j2*16 + col]; s3 += xp2[j3*16 + col];
  }
  for(; i < cnt; i += 16) s0 += xp2[srcperm[o0 + i]*16 + col];
  float s = (s0 + s1) + (s2 + s3);
  s += __shfl_xor(s, 32);
  s += __shfl_xor(s, 16);
  int wv = tid >> 6, lane = tid & 63;
  if(lane < 16) red[wv][lane] = s;
  __syncthreads();
  if(tid < 16) m[tid] = (red[0][tid]+red[1][tid]+red[2][tid]+red[3][tid]) / fmaxf((float)cnt, 1.f);
  __syncthreads();
  if(tid < 16){
    float acc = 0.f;
    #pragma unroll
    for(int k = 0; k < 16; k++) acc = fmaf(m[k], hg[k*16 + tid], acc);
    xd[d*64 + 48 + tid] = acc;
    xdb[d*64 + 48 + tid] = (unsigned short)f2bf(acc);
  }
}

// ======================= fast path: embed GEMM via MFMA =======================

__global__ __launch_bounds__(256) void k_embed_m(
    const float* __restrict__ xdrug, const unsigned short* __restrict__ embb,
    float* __restrict__ xdp){
  int tid = threadIdx.x;
  int wv = tid >> 6, l = tid & 63;
  int rt = blockIdx.x*4 + wv;            // row tile (16 rows)
  int row = rt*16 + (l & 15);
  int kg = (l >> 4) << 3;
  int cb = blockIdx.y * EKCH;
  bool valid = row < NDRUG;
  const float* xr = xdrug + (size_t)row * INDRUG;
  f32x4 z = {0.f,0.f,0.f,0.f};
  f32x4 c0 = z, c1 = z, c2 = z;
  #pragma unroll
  for(int ks = 0; ks < EKCH/32; ks++){
    int k0 = cb + ks*32;
    float4 u = make_float4(0,0,0,0), v = make_float4(0,0,0,0);
    if(valid){
      u = *(const float4*)(xr + k0 + kg);
      v = *(const float4*)(xr + k0 + kg + 4);
    }
    bf16x8 a;
    a[0] = (__bf16)u.x; a[1] = (__bf16)u.y; a[2] = (__bf16)u.z; a[3] = (__bf16)u.w;
    a[4] = (__bf16)v.x; a[5] = (__bf16)v.y; a[6] = (__bf16)v.z; a[7] = (__bf16)v.w;
    const unsigned short* bb = embb + (size_t)(k0 >> 5)*1536 + l*8;
    bf16x8 b0 = *(const bf16x8*)(bb);
    bf16x8 b1 = *(const bf16x8*)(bb + 512);
    bf16x8 b2 = *(const bf16x8*)(bb + 1024);
    c0 = __builtin_amdgcn_mfma_f32_16x16x32_bf16(a, b0, c0, 0,0,0);
    c1 = __builtin_amdgcn_mfma_f32_16x16x32_bf16(a, b1, c1, 0,0,0);
    c2 = __builtin_amdgcn_mfma_f32_16x16x32_bf16(a, b2, c2, 0,0,0);
  }
  int col = l & 15, rb = (l >> 4) << 2;
  float* op = xdp + (size_t)blockIdx.y * NDRUG * 48;
  #pragma unroll
  for(int r = 0; r < 4; r++){
    int ro = rt*16 + rb + r;
    if(ro < NDRUG){
      op[ro*48 + col]       = c0[r];
      op[ro*48 + 16 + col]  = c1[r];
      op[ro*48 + 32 + col]  = c2[r];
    }
  }
}

__global__ void k_embed_fin2(const float* __restrict__ xdp, const float* __restrict__ dnorm,
                             float* __restrict__ xd, unsigned short* __restrict__ xdb){
  int gid = blockIdx.x*256 + threadIdx.x;
  if(gid >= NDRUG*48) return;
  int d = gid / 48, j = gid % 48;
  float s = 0.f;
  for(int y = 0; y < KSPLIT; y++) s += xdp[(size_t)y*NDRUG*48 + gid];
  float v = s / dnorm[d];
  xd[d*64 + j] = v;
  xdb[d*64 + j] = (unsigned short)f2bf(v);
}

// ======================= RGCN msgs via MFMA (padded, branch-free) =======================

__global__ __launch_bounds__(256) void k_rgcn1_msgsM(
    const unsigned short* __restrict__ xdb, const int* __restrict__ psrc,
    const int* __restrict__ pblk, const unsigned short* __restrict__ wetb,
    unsigned short* __restrict__ msgs){
  int tid = threadIdx.x;
  int wv = tid >> 6, l = tid & 63;
  int t0 = pblk[blockIdx.x];
  const unsigned short* wb = wetb + (size_t)t0*2048 + l*8;
  bf16x8 w00 = *(const bf16x8*)(wb);
  bf16x8 w01 = *(const bf16x8*)(wb + 512);
  bf16x8 w10 = *(const bf16x8*)(wb + 1024);
  bf16x8 w11 = *(const bf16x8*)(wb + 1536);
  int eb = blockIdx.x*256 + wv*64;
  int col = l & 15;
  int g4 = (l >> 4) << 3;
  int rb = (l >> 4) << 2;
  int e0 = eb + col, e1 = eb + 16 + col, e2 = eb + 32 + col, e3 = eb + 48 + col;
  int s0 = psrc[e0], s1 = psrc[e1], s2 = psrc[e2], s3 = psrc[e3];
  const unsigned short* x0 = xdb + (size_t)s0*64 + g4;
  const unsigned short* x1 = xdb + (size_t)s1*64 + g4;
  const unsigned short* x2 = xdb + (size_t)s2*64 + g4;
  const unsigned short* x3 = xdb + (size_t)s3*64 + g4;
  bf16x8 a00 = *(const bf16x8*)(x0), a01 = *(const bf16x8*)(x0 + 32);
  bf16x8 a10 = *(const bf16x8*)(x1), a11 = *(const bf16x8*)(x1 + 32);
  bf16x8 a20 = *(const bf16x8*)(x2), a21 = *(const bf16x8*)(x2 + 32);
  bf16x8 a30 = *(const bf16x8*)(x3), a31 = *(const bf16x8*)(x3 + 32);
  f32x4 z = {0.f,0.f,0.f,0.f};
  f32x4 c00=z,c01=z,c10=z,c11=z,c20=z,c21=z,c30=z,c31=z;
  c00 = __builtin_amdgcn_mfma_f32_16x16x32_bf16(w00, a00, c00, 0,0,0);
  c00 = __builtin_amdgcn_mfma_f32_16x16x32_bf16(w10, a01, c00, 0,0,0);
  c01 = __builtin_amdgcn_mfma_f32_16x16x32_bf16(w01, a00, c01, 0,0,0);
  c01 = __builtin_amdgcn_mfma_f32_16x16x32_bf16(w11, a01, c01, 0,0,0);
  c10 = __builtin_amdgcn_mfma_f32_16x16x32_bf16(w00, a10, c10, 0,0,0);
  c10 = __builtin_amdgcn_mfma_f32_16x16x32_bf16(w10, a11, c10, 0,0,0);
  c11 = __builtin_amdgcn_mfma_f32_16x16x32_bf16(w01, a10, c11, 0,0,0);
  c11 = __builtin_amdgcn_mfma_f32_16x16x32_bf16(w11, a11, c11, 0,0,0);
  c20 = __builtin_amdgcn_mfma_f32_16x16x32_bf16(w00, a20, c20, 0,0,0);
  c20 = __builtin_amdgcn_mfma_f32_16x16x32_bf16(w10, a21, c20, 0,0,0);
  c21 = __builtin_amdgcn_mfma_f32_16x16x32_bf16(w01, a20, c21, 0,0,0);
  c21 = __builtin_amdgcn_mfma_f32_16x16x32_bf16(w11, a21, c21, 0,0,0);
  c30 = __builtin_amdgcn_mfma_f32_16x16x32_bf16(w00, a30, c30, 0,0,0);
  c30 = __builtin_amdgcn_mfma_f32_16x16x32_bf16(w10, a31, c30, 0,0,0);
  c31 = __builtin_amdgcn_mfma_f32_16x16x32_bf16(w01, a30, c31, 0,0,0);
  c31 = __builtin_amdgcn_mfma_f32_16x16x32_bf16(w11, a31, c31, 0,0,0);
  *(unsigned long long*)(msgs + (size_t)e0*32 + rb)      = pack4(c00);
  *(unsigned long long*)(msgs + (size_t)e0*32 + 16 + rb) = pack4(c01);
  *(unsigned long long*)(msgs + (size_t)e1*32 + rb)      = pack4(c10);
  *(unsigned long long*)(msgs + (size_t)e1*32 + 16 + rb) = pack4(c11);
  *(unsigned long long*)(msgs + (size_t)e2*32 + rb)      = pack4(c20);
  *(unsigned long long*)(msgs + (size_t)e2*32 + 16 + rb) = pack4(c21);
  *(unsigned long long*)(msgs + (size_t)e3*32 + rb)      = pack4(c30);
  *(unsigned long long*)(msgs + (size_t)e3*32 + 16 + rb) = pack4(c31);
}

__global__ __launch_bounds__(256) void k_rgcn2_msgsM(
    const unsigned short* __restrict__ xd1b, const int* __restrict__ psrc,
    const int* __restrict__ pblk, const unsigned short* __restrict__ wetb,
    unsigned short* __restrict__ msgs){
  int tid = threadIdx.x;
  int wv = tid >> 6, l = tid & 63;
  int t0 = pblk[blockIdx.x];
  bf16x8 w0 = *(const bf16x8*)(wetb + (size_t)t0*512 + l*8);
  int eb = blockIdx.x*256 + wv*64;
  int col = l & 15;
  int g4 = (l >> 4) << 3;
  int rb = (l >> 4) << 2;
  int e0 = eb + col, e1 = eb + 16 + col, e2 = eb + 32 + col, e3 = eb + 48 + col;
  int s0 = psrc[e0], s1 = psrc[e1], s2 = psrc[e2], s3 = psrc[e3];
  bf16x8 a0 = *(const bf16x8*)(xd1b + (size_t)s0*32 + g4);
  bf16x8 a1 = *(const bf16x8*)(xd1b + (size_t)s1*32 + g4);
  bf16x8 a2 = *(const bf16x8*)(xd1b + (size_t)s2*32 + g4);
  bf16x8 a3 = *(const bf16x8*)(xd1b + (size_t)s3*32 + g4);
  f32x4 z = {0.f,0.f,0.f,0.f};
  f32x4 c0=z,c1=z,c2=z,c3=z;
  c0 = __builtin_amdgcn_mfma_f32_16x16x32_bf16(w0, a0, c0, 0,0,0);
  c1 = __builtin_amdgcn_mfma_f32_16x16x32_bf16(w0, a1, c1, 0,0,0);
  c2 = __builtin_amdgcn_mfma_f32_16x16x32_bf16(w0, a2, c2, 0,0,0);
  c3 = __builtin_amdgcn_mfma_f32_16x16x32_bf16(w0, a3, c3, 0,0,0);
  *(unsigned long long*)(msgs + (size_t)e0*16 + rb) = pack4(c0);
  *(unsigned long long*)(msgs + (size_t)e1*16 + rb) = pack4(c1);
  *(unsigned long long*)(msgs + (size_t)e2*16 + rb) = pack4(c2);
  *(unsigned long long*)(msgs + (size_t)e3*16 + rb) = pack4(c3);
}

// block per dst: 16 row-streams, gather rows via eperm (padded ids), 4-way MLP unroll
__global__ void k_rgcn1_reduce(const unsigned short* __restrict__ msgs, const int* __restrict__ off,
                               const int* __restrict__ eperm,
                               const float* __restrict__ xd, const float* __restrict__ root,
                               float* __restrict__ xd1, unsigned short* __restrict__ xd1b){
  __shared__ float red[16][32];
  int d = blockIdx.x;
  int tid = threadIdx.x;
  int cp = tid & 15, r = tid >> 4;
  int o0 = off[d], cnt = off[d+1] - o0;
  float s0 = 0.f, s1 = 0.f;
  int i = r;
  for(; i + 48 < cnt; i += 64){
    int e0 = eperm[o0 + i],      e1 = eperm[o0 + i + 16];
    int e2 = eperm[o0 + i + 32], e3 = eperm[o0 + i + 48];
    unsigned int v0 = *(const unsigned int*)(msgs + (size_t)e0*32 + cp*2);
    unsigned int v1 = *(const unsigned int*)(msgs + (size_t)e1*32 + cp*2);
    unsigned int v2 = *(const unsigned int*)(msgs + (size_t)e2*32 + cp*2);
    unsigned int v3 = *(const unsigned int*)(msgs + (size_t)e3*32 + cp*2);
    s0 += bf2f(v0 & 0xffffu) + bf2f(v1 & 0xffffu) + bf2f(v2 & 0xffffu) + bf2f(v3 & 0xffffu);
    s1 += bf2f(v0 >> 16)     + bf2f(v1 >> 16)     + bf2f(v2 >> 16)     + bf2f(v3 >> 16);
  }
  for(; i < cnt; i += 16){
    int e0 = eperm[o0 + i];
    unsigned int v = *(const unsigned int*)(msgs + (size_t)e0*32 + cp*2);
    s0 += bf2f(v & 0xffffu); s1 += bf2f(v >> 16);
  }
  red[r][cp*2] = s0; red[r][cp*2+1] = s1;
  __syncthreads();
  if(tid < 32){
    float tot = 0.f;
    #pragma unroll
    for(int r2 = 0; r2 < 16; r2++) tot += red[r2][tid];
    float rr = 0.f;
    const float* x = xd + d*64;
    #pragma unroll 8
    for(int i2 = 0; i2 < 64; i2++) rr = fmaf(x[i2], root[i2*32 + tid], rr);
    float v = fmaxf(tot / fmaxf((float)cnt, 1.0f) + rr, 0.f);
    xd1[d*32 + tid] = v;
    xd1b[d*32 + tid] = (unsigned short)f2bf(v);
  }
}

__global__ void k_rgcn2_reduce(const unsigned short* __restrict__ msgs, const int* __restrict__ off,
                               const int* __restrict__ eperm,
                               const float* __restrict__ xd1, const float* __restrict__ root,
                               float* __restrict__ out){
  __shared__ float red[32][16];
  int d = blockIdx.x;
  int tid = threadIdx.x;
  int cp = tid & 7, r = tid >> 3;
  int o0 = off[d], cnt = off[d+1] - o0;
  float s0 = 0.f, s1 = 0.f;
  int i = r;
  for(; i + 96 < cnt; i += 128){
    int e0 = eperm[o0 + i],      e1 = eperm[o0 + i + 32];
    int e2 = eperm[o0 + i + 64], e3 = eperm[o0 + i + 96];
    unsigned int v0 = *(const unsigned int*)(msgs + (size_t)e0*16 + cp*2);
    unsigned int v1 = *(const unsigned int*)(msgs + (size_t)e1*16 + cp*2);
    unsigned int v2 = *(const unsigned int*)(msgs + (size_t)e2*16 + cp*2);
    unsigned int v3 = *(const unsigned int*)(msgs + (size_t)e3*16 + cp*2);
    s0 += bf2f(v0 & 0xffffu) + bf2f(v1 & 0xffffu) + bf2f(v2 & 0xffffu) + bf2f(v3 & 0xffffu);
    s1 += bf2f(v0 >> 16)     + bf2f(v1 >> 16)     + bf2f(v2 >> 16)     + bf2f(v3 >> 16);
  }
  for(; i < cnt; i += 32){
    int e0 = eperm[o0 + i];
    unsigned int v = *(const unsigned int*)(msgs + (size_t)e0*16 + cp*2);
    s0 += bf2f(v & 0xffffu); s1 += bf2f(v >> 16);
  }
  red[r][cp*2] = s0; red[r][cp*2+1] = s1;
  __syncthreads();
  if(tid < 16){
    float tot = 0.f;
    #pragma unroll
    for(int r2 = 0; r2 < 32; r2++) tot += red[r2][tid];
    float rr = 0.f;
    const float* x = xd1 + d*32;
    #pragma unroll 8
    for(int i2 = 0; i2 < 32; i2++) rr = fmaf(x[i2], root[i2*16 + tid], rr);
    out[d*16 + tid] = tot / fmaxf((float)cnt, 1.0f) + rr;
  }
}

// ======================= fallback (round-1) kernels =======================

#define O_CNTPP   0
#define O_DIS     20000
#define O_H1      40000
#define O_AGG1    680000
#define O_H2      1320000
#define O_AGG2    1640000
#define O_DPSUM   1960000
#define O_DPCNT   2024000
#define O_XD      2028000
#define O_WET1    2284000
#define O_WET2    2546144
#define O_CNTDD   2611680
#define O_RSUM1   2615680
#define O_XD1     2743680
#define O_RSUM2   2871680

__global__ void k_count_int(const int* __restrict__ dst, int ne, int* __restrict__ cnt){
  int i = blockIdx.x*256 + threadIdx.x;
  if(i < ne) atomicAdd(&cnt[dst[i]], 1);
}

__global__ void k_dis(const int* __restrict__ cnt, float* __restrict__ dis, int n){
  int i = blockIdx.x*256 + threadIdx.x;
  if(i < n) dis[i] = rsqrtf((float)cnt[i] + 1.0f);
}

template<int NC>
__global__ void k_gcn_init(const float* __restrict__ h, const float* __restrict__ dis,
                           const float* __restrict__ b, float* __restrict__ agg, int n){
  int i = blockIdx.x*256 + threadIdx.x;
  if(i < n*NC){
    int r = i / NC, c = i % NC;
    float d = dis[r];
    agg[i] = fmaf(h[i], d*d, b[c]);
  }
}

template<int NC>
__global__ void k_gcn_scatter(const float* __restrict__ h, const float* __restrict__ dis,
                              const int* __restrict__ src, const int* __restrict__ dst,
                              int ne, float* __restrict__ agg){
  int gid = blockIdx.x*256 + threadIdx.x;
  int e = gid / NC, j = gid % NC;
  if(e >= ne) return;
  int s = src[e], d = dst[e];
  atomicAdd(&agg[d*NC + j], h[s*NC + j] * dis[s] * dis[d]);
}

__global__ void k_dp_scatter(const float* __restrict__ xp2, const int* __restrict__ src,
                             const int* __restrict__ dst, float* __restrict__ dpsum,
                             int* __restrict__ dpcnt){
  int gid = blockIdx.x*256 + threadIdx.x;
  int e = gid >> 4, j = gid & 15;
  if(e >= EDP) return;
  int s = src[e], d = dst[e] - NPROT;
  atomicAdd(&dpsum[d*16 + j], xp2[s*16 + j]);
  if(j == 0) atomicAdd(&dpcnt[d], 1);
}

__global__ void k_hier(const float* __restrict__ dpsum, const int* __restrict__ dpcnt,
                       const float* __restrict__ hg, float* __restrict__ xd){
  int gid = blockIdx.x*256 + threadIdx.x;
  int d = gid >> 4, j = gid & 15;
  if(d >= NDRUG) return;
  float inv = 1.0f / fmaxf((float)dpcnt[d], 1.0f);
  float acc = 0.f;
  #pragma unroll
  for(int k = 0; k < 16; k++) acc = fmaf(dpsum[d*16 + k] * inv, hg[k*16 + j], acc);
  xd[d*64 + 48 + j] = acc;
}

__global__ void k_embed(const float* __restrict__ xdrug, const float* __restrict__ embed,
                        float* __restrict__ xd){
  __shared__ float xs[64][65];
  __shared__ float es[64][48];
  int tid = threadIdx.x;
  int r = tid & 63;
  int cg = tid >> 6;
  int row0 = blockIdx.x * 64;
  int k0c = blockIdx.y * 512;
  float acc[12];
  #pragma unroll
  for(int j = 0; j < 12; j++) acc[j] = 0.f;
  for(int kt = 0; kt < 512; kt += 64){
    int k0 = k0c + kt;
    if(k0 >= INDRUG) break;
    __syncthreads();
    #pragma unroll
    for(int i = 0; i < 4; i++){
      int lin = tid + i*256;
      int rr = lin >> 4, kc = lin & 15;
      int grow = row0 + rr, gk = k0 + kc*4;
      float4 v = make_float4(0.f,0.f,0.f,0.f);
      if(grow < NDRUG && gk + 3 < INDRUG)
        v = *(const float4*)&xdrug[(size_t)grow * INDRUG + gk];
      xs[rr][kc*4+0]=v.x; xs[rr][kc*4+1]=v.y; xs[rr][kc*4+2]=v.z; xs[rr][kc*4+3]=v.w;
    }
    #pragma unroll
    for(int i = 0; i < 3; i++){
      int lin = tid + i*256;
      int kk = lin / 12, jc = lin % 12;
      float4 v = make_float4(0.f,0.f,0.f,0.f);
      if(k0 + kk < INDRUG)
        v = *(const float4*)&embed[(size_t)(k0 + kk) * NEMBED + jc*4];
      *(float4*)&es[kk][jc*4] = v;
    }
    __syncthreads();
    #pragma unroll 8
    for(int kk = 0; kk < 64; kk++){
      float xv = xs[r][kk];
      const float4* ep = (const float4*)&es[kk][cg*12];
      float4 e0 = ep[0], e1 = ep[1], e2 = ep[2];
      acc[0]=fmaf(xv,e0.x,acc[0]);  acc[1]=fmaf(xv,e0.y,acc[1]);
      acc[2]=fmaf(xv,e0.z,acc[2]);  acc[3]=fmaf(xv,e0.w,acc[3]);
      acc[4]=fmaf(xv,e1.x,acc[4]);  acc[5]=fmaf(xv,e1.y,acc[5]);
      acc[6]=fmaf(xv,e1.z,acc[6]);  acc[7]=fmaf(xv,e1.w,acc[7]);
      acc[8]=fmaf(xv,e2.x,acc[8]);  acc[9]=fmaf(xv,e2.y,acc[9]);
      acc[10]=fmaf(xv,e2.z,acc[10]); acc[11]=fmaf(xv,e2.w,acc[11]);
    }
  }
  int grow = row0 + r;
  if(grow < NDRUG){
    #pragma unroll
    for(int j = 0; j < 12; j++)
      atomicAdd(&xd[grow*64 + cg*12 + j], acc[j]);
  }
}

__global__ void k_embed_fin(float* __restrict__ xd, const float* __restrict__ dnorm){
  int gid = blockIdx.x*256 + threadIdx.x;
  if(gid >= NDRUG*48) return;
  int d = gid / 48, j = gid % 48;
  xd[d*64 + j] = xd[d*64 + j] / dnorm[d];
}

__global__ void k_rgcn1(const float* __restrict__ xd, const int* __restrict__ src,
                        const int* __restrict__ dst, const int* __restrict__ et,
                        const float* __restrict__ wet, float* __restrict__ rsum){
  int tid = threadIdx.x;
  int e = blockIdx.x*64 + (tid >> 2);
  if(e >= EDD) return;
  int jg = tid & 3;
  int s = src[e], d = dst[e], t = et[e];
  const float* x = xd + s*64;
  const float* w = wet + t*2048 + jg*8;
  float acc[8] = {0,0,0,0,0,0,0,0};
  #pragma unroll 8
  for(int i = 0; i < 64; i++){
    float xv = x[i];
    const float4* wp = (const float4*)(w + i*32);
    float4 w0 = wp[0], w1 = wp[1];
    acc[0]=fmaf(xv,w0.x,acc[0]); acc[1]=fmaf(xv,w0.y,acc[1]);
    acc[2]=fmaf(xv,w0.z,acc[2]); acc[3]=fmaf(xv,w0.w,acc[3]);
    acc[4]=fmaf(xv,w1.x,acc[4]); acc[5]=fmaf(xv,w1.y,acc[5]);
    acc[6]=fmaf(xv,w1.z,acc[6]); acc[7]=fmaf(xv,w1.w,acc[7]);
  }
  float* outp = rsum + d*32 + jg*8;
  #pragma unroll
  for(int j = 0; j < 8; j++) atomicAdd(&outp[j], acc[j]);
}

__global__ void k_rgcn2(const float* __restrict__ xd1, const int* __restrict__ src,
                        const int* __restrict__ dst, const int* __restrict__ et,
                        const float* __restrict__ wet, float* __restrict__ rsum){
  int tid = threadIdx.x;
  int e = blockIdx.x*128 + (tid >> 1);
  if(e >= EDD) return;
  int jg = tid & 1;
  int s = src[e], d = dst[e], t = et[e];
  const float* x = xd1 + s*32;
  const float* w = wet + t*512 + jg*8;
  float acc[8] = {0,0,0,0,0,0,0,0};
  #pragma unroll 8
  for(int i = 0; i < 32; i++){
    float xv = x[i];
    const float4* wp = (const float4*)(w + i*16);
    float4 w0 = wp[0], w1 = wp[1];
    acc[0]=fmaf(xv,w0.x,acc[0]); acc[1]=fmaf(xv,w0.y,acc[1]);
    acc[2]=fmaf(xv,w0.z,acc[2]); acc[3]=fmaf(xv,w0.w,acc[3]);
    acc[4]=fmaf(xv,w1.x,acc[4]); acc[5]=fmaf(xv,w1.y,acc[5]);
    acc[6]=fmaf(xv,w1.z,acc[6]); acc[7]=fmaf(xv,w1.w,acc[7]);
  }
  float* outp = rsum + d*16 + jg*8;
  #pragma unroll
  for(int j = 0; j < 8; j++) atomicAdd(&outp[j], acc[j]);
}

__global__ void k_root1(const float* __restrict__ rsum, const int* __restrict__ cnt,
                        const float* __restrict__ xd, const float* __restrict__ root,
                        float* __restrict__ xd1){
  int gid = blockIdx.x*256 + threadIdx.x;
  int d = gid >> 5, j = gid & 31;
  if(d >= NDRUG) return;
  float inv = 1.0f / fmaxf((float)cnt[d], 1.0f);
  float acc = rsum[d*32 + j] * inv;
  #pragma unroll
  for(int i = 0; i < 64; i++) acc = fmaf(xd[d*64 + i], root[i*32 + j], acc);
  xd1[d*32 + j] = fmaxf(acc, 0.f);
}

__global__ void k_root2(const float* __restrict__ rsum, const int* __restrict__ cnt,
                        const float* __restrict__ xd1, const float* __restrict__ root,
                        float* __restrict__ out){
  int gid = blockIdx.x*256 + threadIdx.x;
  int d = gid >> 4, j = gid & 15;
  if(d >= NDRUG) return;
  float inv = 1.0f / fmaxf((float)cnt[d], 1.0f);
  float acc = rsum[d*16 + j] * inv;
  #pragma unroll
  for(int i = 0; i < 32; i++) acc = fmaf(xd1[d*32 + i], root[i*16 + j], acc);
  out[d*16 + j] = acc;
}

// ======================= launch =======================

extern "C" void kernel_launch(void* const* d_in, const int* in_sizes, int n_in,
                              void* d_out, int out_size, void* d_ws, size_t ws_size,
                              hipStream_t stream){
  const float* x_drug  = (const float*)d_in[0];
  const float* d_norm  = (const float*)d_in[1];
  const float* x_prot  = (const float*)d_in[2];
  const int*   pp_ei   = (const int*)d_in[3];
  const int*   dp_ei   = (const int*)d_in[4];
  const int*   dd_ei   = (const int*)d_in[6];
  const int*   dd_et   = (const int*)d_in[7];
  const int*   dd_rl   = (const int*)d_in[8];
  const float* embed   = (const float*)d_in[9];
  const float* W1      = (const float*)d_in[10];
  const float* b1      = (const float*)d_in[11];
  const float* W2      = (const float*)d_in[12];
  const float* b2      = (const float*)d_in[13];
  const float* hgw     = (const float*)d_in[14];
  const float* att1    = (const float*)d_in[15];
  const float* basis1  = (const float*)d_in[16];
  const float* root1   = (const float*)d_in[17];
  const float* att2    = (const float*)d_in[18];
  const float* basis2  = (const float*)d_in[19];
  const float* root2   = (const float*)d_in[20];
  float* out = (float*)d_out;
  float* ws = (float*)d_ws;

  const int* pp_src = pp_ei;
  const int* pp_dst = pp_ei + EPP;
  const int* dp_src = dp_ei;
  const int* dp_dst = dp_ei + EDP;
  const int* dd_src = dd_ei;
  const int* dd_dst = dd_ei + EDD;

  // ---- fast-path ws layout ----
  auto pad = [](size_t n){ return (n + 15) & ~(size_t)15; };
  size_t o = 0;
  size_t oPPOFF = o; o += pad(NPROT + 1);
  size_t oDPOFF = o; o += pad(NDRUG + 1);
  size_t oDDOFF = o; o += pad(NDRUG + 1);
  size_t oDIS   = o; o += pad(NPROT);
  size_t oH1    = o; o += pad((size_t)NPROT*32);
  size_t oH2    = o; o += pad((size_t)NPROT*16);
  size_t oAGG2  = o; o += pad((size_t)NPROT*16);
  size_t oXD    = o; o += pad((size_t)NDRUG*64);
  size_t oXD1   = o; o += pad((size_t)NDRUG*32);
  size_t oXDB   = o; o += pad((size_t)NDRUG*32);
  size_t oXD1B  = o; o += pad((size_t)NDRUG*16);
  size_t oWETB1 = o; o += pad((size_t)NET*1024);
  size_t oWETB2 = o; o += pad((size_t)NET*256);
  size_t oEMBB  = o; o += pad((size_t)125*768);   // 125*1536 ushort
  size_t oSRCPP = o; o += pad(EPP);
  size_t oSRCDP = o; o += pad(EDP);
  size_t oEPERM = o; o += pad(EDD);
  size_t oPSTART= o; o += pad(NET + 1);
  size_t oPBLK  = o; o += pad(PBLKS);
  size_t oPSRC  = o; o += pad(PEDD);
  size_t oPMAPE = o; o += pad(EDD);
  size_t oCNT   = o; o += pad(NPROT);
  size_t oCUR   = o; o += pad(NPROT);
  // msgs region, aliased with xdp (disjoint lifetimes):
  size_t msgsN  = (size_t)PEDD*16;
  size_t xdpN   = (size_t)KSPLIT*NDRUG*48;
  size_t bigN   = msgsN > xdpN ? msgsN : xdpN;
  size_t oMSGS  = o; o += pad(bigN);
  size_t need_bytes = o * 4;

  if(ws_size >= need_bytes){
    // =================== FAST PATH ===================
    int* ppoff = (int*)(ws + oPPOFF);
    int* dpoff = (int*)(ws + oDPOFF);
    int* ddoff = (int*)(ws + oDDOFF);
    float* dis = ws + oDIS;
    float* h1  = ws + oH1;
    float* h2  = ws + oH2;
    float* agg2= ws + oAGG2;
    float* xd  = ws + oXD;
    float* xd1 = ws + oXD1;
    unsigned short* xdb  = (unsigned short*)(ws + oXDB);
    unsigned short* xd1b = (unsigned short*)(ws + oXD1B);
    unsigned short* wetb1 = (unsigned short*)(ws + oWETB1);
    unsigned short* wetb2 = (unsigned short*)(ws + oWETB2);
    unsigned short* embb  = (unsigned short*)(ws + oEMBB);
    int* srcpp = (int*)(ws + oSRCPP);
    int* srcdp = (int*)(ws + oSRCDP);
    int* eperm = (int*)(ws + oEPERM);
    int* pstart= (int*)(ws + oPSTART);
    int* pblk  = (int*)(ws + oPBLK);
    int* psrc  = (int*)(ws + oPSRC);
    int* pmape = (int*)(ws + oPMAPE);
    int* cnt   = (int*)(ws + oCNT);
    int* cur   = (int*)(ws + oCUR);
    float* xdp = ws + oMSGS;                              // alias (dead before msgs)
    unsigned short* msgs = (unsigned short*)(ws + oMSGS);

    // ---- padded edge layout prep ----
    hipMemsetAsync(pblk, 0, PBLKS*sizeof(int), stream);
    hipMemsetAsync(psrc, 0, PEDD*sizeof(int), stream);
    k_pstart<<<1,NET,0,stream>>>(dd_rl, pstart, pblk);
    k_pmap<<<(EDD+255)/256,256,0,stream>>>(dd_et, dd_src, dd_rl, pstart, psrc, pmape);

    // ---- PP CSR (count + batched scatter, no gh) ----
    hipMemsetAsync(cnt, 0, NPROT*sizeof(int), stream);
    k_count_sub<<<(EPP+255)/256,256,0,stream>>>(pp_dst, EPP, 0, cnt);
    k_scan_off<<<1,1024,0,stream>>>(cnt, ppoff, NPROT);
    k_copy_int<<<(NPROT+255)/256,256,0,stream>>>(ppoff, cur, NPROT);
    k_scatter_b<10000><<<NBLK,256,0,stream>>>(pp_dst, pp_src, EPP, 0, 0,     cur, srcpp);
    k_scatter_b<10000><<<NBLK,256,0,stream>>>(pp_dst, pp_src, EPP, 0, 10000, cur, srcpp);
    k_dis_off<<<(NPROT+255)/256,256,0,stream>>>(ppoff, dis, NPROT);

    // ---- PP GCN (pre-scaled features) ----
    k_gemm_s<<<(NPROT*32+255)/256,256,0,stream>>>(x_prot, W1, dis, h1, NPROT);
    k_gcn_gather1<<<NPROT,256,0,stream>>>(h1, dis, ppoff, srcpp, b1, W2, h2);
    k_gcn_gather2<<<NPROT,256,0,stream>>>(h2, dis, ppoff, srcpp, b2, agg2);

    // ---- DP CSR + hierarchy ----
    hipMemsetAsync(cnt, 0, NDRUG*sizeof(int), stream);
    k_count_sub<<<(EDP+255)/256,256,0,stream>>>(dp_dst, EDP, NPROT, cnt);
    k_scan_off<<<1,1024,0,stream>>>(cnt, dpoff, NDRUG);
    k_copy_int<<<(NDRUG+255)/256,256,0,stream>>>(dpoff, cur, NDRUG);
    k_scatter_b<4000><<<NBLK,256,0,stream>>>(dp_dst, dp_src, EDP, NPROT, 0, cur, srcdp);
    k_dp_gather<<<NDRUG,256,0,stream>>>(agg2, dpoff, srcdp, hgw, xd, xdb);

    // ---- drug embedding via MFMA (xdp aliased; consumed by fin2) ----
    k_embb<<<(125*1536+255)/256,256,0,stream>>>(embed, embb);
    {
      dim3 g(63, KSPLIT);
      k_embed_m<<<g,256,0,stream>>>(x_drug, embb, xdp);
    }
    k_embed_fin2<<<(NDRUG*48+255)/256,256,0,stream>>>(xdp, d_norm, xd, xdb);

    // ---- RGCN prep (wetb built directly from att/basis) ----
    k_wetb1<<<(NET*2048+255)/256,256,0,stream>>>(att1, basis1, wetb1);
    k_wetb2<<<(NET*512+255)/256,256,0,stream>>>(att2, basis2, wetb2);
    hipMemsetAsync(cnt, 0, NDRUG*sizeof(int), stream);
    k_count_sub<<<(EDD+255)/256,256,0,stream>>>(dd_dst, EDD, 0, cnt);
    k_scan_off<<<1,1024,0,stream>>>(cnt, ddoff, NDRUG);
    k_copy_int<<<(NDRUG+255)/256,256,0,stream>>>(ddoff, cur, NDRUG);
    // eperm[pos] = padded edge id
    k_scatter_b<4000><<<NBLK,256,0,stream>>>(dd_dst, pmape, EDD, 0, 0, cur, eperm);

    // ---- RGCN layer 1 (MFMA, padded, branch-free) ----
    k_rgcn1_msgsM<<<PBLKS,256,0,stream>>>(xdb, psrc, pblk, wetb1, msgs);
    k_rgcn1_reduce<<<NDRUG,256,0,stream>>>(msgs, ddoff, eperm, xd, root1, xd1, xd1b);
    // ---- RGCN layer 2 ----
    k_rgcn2_msgsM<<<PBLKS,256,0,stream>>>(xd1b, psrc, pblk, wetb2, msgs);
    k_rgcn2_reduce<<<NDRUG,256,0,stream>>>(msgs, ddoff, eperm, xd1, root2, out);
  } else {
    // =================== FALLBACK (round-1, atomic) ===================
    int*   cnt_pp = (int*)(ws + O_CNTPP);
    float* dis    = ws + O_DIS;
    float* h1     = ws + O_H1;
    float* agg1   = ws + O_AGG1;
    float* h2     = ws + O_H2;
    float* agg2   = ws + O_AGG2;
    float* dpsum  = ws + O_DPSUM;
    int*   dpcnt  = (int*)(ws + O_DPCNT);
    float* xd     = ws + O_XD;
    float* wet1   = ws + O_WET1;
    float* wet2   = ws + O_WET2;
    int*   cntdd  = (int*)(ws + O_CNTDD);
    float* rsum1  = ws + O_RSUM1;
    float* xd1    = ws + O_XD1;
    float* rsum2  = ws + O_RSUM2;

    hipMemsetAsync(cnt_pp, 0, NPROT*sizeof(int), stream);
    hipMemsetAsync(dpsum,  0, (64000 + 4000)*sizeof(float), stream);
    hipMemsetAsync(xd,     0, NDRUG*64*sizeof(float), stream);
    hipMemsetAsync(cntdd,  0, NDRUG*sizeof(int), stream);
    hipMemsetAsync(rsum1,  0, NDRUG*32*sizeof(float), stream);
    hipMemsetAsync(rsum2,  0, NDRUG*16*sizeof(float), stream);

    k_count_int<<<(EPP+255)/256,256,0,stream>>>(pp_dst, EPP, cnt_pp);
    k_dis<<<(NPROT+255)/256,256,0,stream>>>(cnt_pp, dis, NPROT);
    k_gemm<64,32,false><<<(NPROT*32+255)/256,256,0,stream>>>(x_prot, W1, h1, NPROT);
    k_gcn_init<32><<<(NPROT*32+255)/256,256,0,stream>>>(h1, dis, b1, agg1, NPROT);
    k_gcn_scatter<32><<<(EPP*32)/256,256,0,stream>>>(h1, dis, pp_src, pp_dst, EPP, agg1);
    k_gemm<32,16,true><<<(NPROT*16+255)/256,256,0,stream>>>(agg1, W2, h2, NPROT);
    k_gcn_init<16><<<(NPROT*16+255)/256,256,0,stream>>>(h2, dis, b2, agg2, NPROT);
    k_gcn_scatter<16><<<(EPP*16)/256,256,0,stream>>>(h2, dis, pp_src, pp_dst, EPP, agg2);
    k_dp_scatter<<<(EDP*16)/256,256,0,stream>>>(agg2, dp_src, dp_dst, dpsum, dpcnt);
    k_hier<<<(NDRUG*16+255)/256,256,0,stream>>>(dpsum, dpcnt, hgw, xd);
    {
      dim3 g((NDRUG+63)/64, 8);
      k_embed<<<g,256,0,stream>>>(x_drug, embed, xd);
    }
    k_embed_fin<<<(NDRUG*48+255)/256,256,0,stream>>>(xd, d_norm);
    k_wet<<<(NET*2048+255)/256,256,0,stream>>>(att1, basis1, wet1, 2048);
    k_wet<<<(NET*512+255)/256,256,0,stream>>>(att2, basis2, wet2, 512);
    k_count_int<<<(EDD+255)/256,256,0,stream>>>(dd_dst, EDD, cntdd);
    k_rgcn1<<<EDD/64,256,0,stream>>>(xd, dd_src, dd_dst, dd_et, wet1, rsum1);
    k_root1<<<(NDRUG*32+255)/256,256,0,stream>>>(rsum1, cntdd, xd, root1, xd1);
    k_rgcn2<<<(EDD+127)/128,256,0,stream>>>(xd1, dd_src, dd_dst, dd_et, wet2, rsum2);
    k_root2<<<(NDRUG*16+255)/256,256,0,stream>>>(rsum2, cntdd, xd1, root2, out);
  }
}

// Round 22
// 353.815 us; speedup vs baseline: 1.4488x; 1.4488x over previous
//
#include <hip/hip_runtime.h>

#define NPROT 20000
#define NDRUG 4000
#define INDRUG 4000
#define NET 128
#define NBASE 32
#define NEMBED 48
#define PDDIM 16
#define H1C 32
#define H2C 16
#define RGCNIN 64
#define EPP 800000
#define EDP 400000
#define EDD 1000000
#define NBLK 256
#define SCANG 8             // b-groups for 2-phase scan (256/32)
#define EKCH 160            // 5 k-steps of 32 per chunk
#define KSPLIT 25           // 4000 / 160
#define PBLKS 4035          // ceil(EDD/256) + NET
#define PEDD (PBLKS*256)    // padded edge capacity

typedef __attribute__((ext_vector_type(8))) __bf16 bf16x8;
typedef __attribute__((ext_vector_type(4))) float f32x4;

__device__ __forceinline__ unsigned int f2bf(float f){
  unsigned int u = __float_as_uint(f);
  u += 0x7fffu + ((u >> 16) & 1u);     // RNE
  return u >> 16;
}
__device__ __forceinline__ float bf2f(unsigned int s){
  return __uint_as_float(s << 16);
}
__device__ __forceinline__ unsigned long long pack4(const f32x4& c){
  unsigned long long lo = (unsigned long long)(f2bf(c[0]) | (f2bf(c[1]) << 16));
  unsigned long long hi = (unsigned long long)(f2bf(c[2]) | (f2bf(c[3]) << 16));
  return lo | (hi << 32);
}

// ======================= shared kernels =======================

template<int K, int NC, bool RELU_IN>
__global__ void k_gemm(const float* __restrict__ A, const float* __restrict__ W,
                       float* __restrict__ C, int M){
  __shared__ float Ws[K*NC];
  for(int i = threadIdx.x; i < K*NC; i += 256) Ws[i] = W[i];
  __syncthreads();
  int idx = blockIdx.x*256 + threadIdx.x;
  int row = idx / NC, col = idx % NC;
  if(row >= M) return;
  const float* a = A + row*K;
  float acc = 0.f;
  #pragma unroll
  for(int k = 0; k < K; k++){
    float v = a[k];
    if(RELU_IN) v = fmaxf(v, 0.f);
    acc = fmaf(v, Ws[k*NC + col], acc);
  }
  C[idx] = acc;
}

// h1s = (x_prot @ W1) * dis[row]   (K=64, NC=32)
__global__ void k_gemm_s(const float* __restrict__ A, const float* __restrict__ W,
                         const float* __restrict__ dis, float* __restrict__ C, int M){
  __shared__ float Ws[64*32];
  for(int i = threadIdx.x; i < 64*32; i += 256) Ws[i] = W[i];
  __syncthreads();
  int idx = blockIdx.x*256 + threadIdx.x;
  int row = idx >> 5, col = idx & 31;
  if(row >= M) return;
  const float* a = A + row*64;
  float acc = 0.f;
  #pragma unroll
  for(int k = 0; k < 64; k++)
    acc = fmaf(a[k], Ws[k*32 + col], acc);
  C[idx] = acc * dis[row];
}

__global__ void k_wet(const float* __restrict__ att, const float* __restrict__ basis,
                      float* __restrict__ wet, int inout){
  int gid = blockIdx.x*256 + threadIdx.x;
  if(gid >= NET * inout) return;
  int et = gid / inout, ij = gid % inout;
  float acc = 0.f;
  #pragma unroll
  for(int b = 0; b < NBASE; b++)
    acc = fmaf(att[et*NBASE + b], basis[b*inout + ij], acc);
  wet[gid] = acc;
}

// bf16 fragment build DIRECT from att/basis: wetb1[et][f][l][j], f = kt*2+nt
__global__ void k_wetb1(const float* __restrict__ att, const float* __restrict__ basis,
                        unsigned short* __restrict__ wetb){
  int gid = blockIdx.x*256 + threadIdx.x;
  if(gid >= NET*2048) return;
  int et = gid >> 11, r = gid & 2047;
  int f = r >> 9, l = (r >> 3) & 63, j = r & 7;
  int kt = f >> 1, nt = f & 1;
  int k = kt*32 + ((l >> 4) << 3) + j;
  int c = nt*16 + (l & 15);
  float acc = 0.f;
  #pragma unroll
  for(int b = 0; b < NBASE; b++)
    acc = fmaf(att[et*NBASE + b], basis[b*2048 + k*32 + c], acc);
  wetb[gid] = (unsigned short)f2bf(acc);
}

__global__ void k_wetb2(const float* __restrict__ att, const float* __restrict__ basis,
                        unsigned short* __restrict__ wetb){
  int gid = blockIdx.x*256 + threadIdx.x;
  if(gid >= NET*512) return;
  int et = gid >> 9, r = gid & 511;
  int l = r >> 3, j = r & 7;
  int k = ((l >> 4) << 3) + j;
  int c = l & 15;
  float acc = 0.f;
  #pragma unroll
  for(int b = 0; b < NBASE; b++)
    acc = fmaf(att[et*NBASE + b], basis[b*512 + k*16 + c], acc);
  wetb[gid] = (unsigned short)f2bf(acc);
}

// embed B-fragment table: embb[kt][f][l][j], kt=0..124, f=0..2
__global__ void k_embb(const float* __restrict__ embed, unsigned short* __restrict__ embb){
  int gid = blockIdx.x*256 + threadIdx.x;
  if(gid >= 125*1536) return;
  int kt = gid / 1536, r = gid % 1536;
  int f = r / 512, l = (r >> 3) & 63, j = r & 7;
  int k = kt*32 + ((l >> 4) << 3) + j;
  int c = f*16 + (l & 15);
  embb[gid] = (unsigned short)f2bf(embed[k*48 + c]);
}

// ======================= padded edge layout =======================

__global__ void k_pstart(const int* __restrict__ range, int* __restrict__ pstart,
                         int* __restrict__ pblk){
  __shared__ int ps[NET];
  int t = threadIdx.x;
  int cnt = range[t*2+1] - range[t*2];
  int padc = (cnt + 255) & ~255;
  ps[t] = padc;
  __syncthreads();
  int myoff = 0;
  for(int i = 0; i < t; i++) myoff += ps[i];
  pstart[t] = myoff;
  if(t == NET-1) pstart[NET] = myoff + padc;
  int b0 = myoff >> 8, nb = padc >> 8;
  for(int i = 0; i < nb; i++) pblk[b0 + i] = t;
}

__global__ void k_pmap(const int* __restrict__ et, const int* __restrict__ src,
                       const int* __restrict__ range, const int* __restrict__ pstart,
                       int* __restrict__ psrc, int* __restrict__ pmape){
  int e = blockIdx.x*256 + threadIdx.x;
  if(e >= EDD) return;
  int t = et[e];
  int p = pstart[t] + (e - range[t*2]);
  psrc[p] = src[e];
  pmape[e] = p;
}

// ======================= fast path: CSR build (LDS hist, 2-phase scan) =======================

template<int PB>
__global__ void k_hist(const int* __restrict__ dst, int ne, int sub, int b0,
                       int* __restrict__ gh, int bins){
  __shared__ int h[PB];
  for(int i = threadIdx.x; i < PB; i += 256) h[i] = 0;
  __syncthreads();
  int chunk = (ne + NBLK - 1) / NBLK;
  int s0 = blockIdx.x*chunk, s1 = min(s0 + chunk, ne);
  for(int i = s0 + threadIdx.x; i < s1; i += 256){
    int b = dst[i] - sub - b0;
    if(b >= 0 && b < PB) atomicAdd(&h[b], 1);
  }
  __syncthreads();
  for(int i = threadIdx.x; i < PB; i += 256) gh[(size_t)blockIdx.x*bins + b0 + i] = h[i];
}

// phase 1: psum[g][bin] = sum of gh[b][bin] for b in group g (32 rows)
__global__ void k_scan_p1(const int* __restrict__ gh, int* __restrict__ psum, int bins){
  int bin = blockIdx.x*256 + threadIdx.x;
  int g = blockIdx.y;
  if(bin >= bins) return;
  int s = 0;
  #pragma unroll 8
  for(int b = g*32; b < g*32 + 32; b++) s += gh[(size_t)b*bins + bin];
  psum[(size_t)g*bins + bin] = s;
}

// phase 2: exclusive prefix within column; g==SCANG-1 writes cnt
__global__ void k_scan_p2(int* __restrict__ gh, const int* __restrict__ psum,
                          int* __restrict__ cnt, int bins){
  int bin = blockIdx.x*256 + threadIdx.x;
  int g = blockIdx.y;
  if(bin >= bins) return;
  int run = 0;
  for(int gg = 0; gg < g; gg++) run += psum[(size_t)gg*bins + bin];
  #pragma unroll 8
  for(int b = g*32; b < g*32 + 32; b++){
    int v = gh[(size_t)b*bins + bin];
    gh[(size_t)b*bins + bin] = run;
    run += v;
  }
  if(g == SCANG-1) cnt[bin] = run;
}

__global__ void k_scan_off(const int* __restrict__ cnt, int* __restrict__ off, int bins){
  __shared__ int ps[1024];
  int t = threadIdx.x;
  int C = (bins + 1023) >> 10;
  int lo = t*C, hi = min(lo + C, bins);
  int s = 0;
  for(int i = lo; i < hi; i++) s += cnt[i];
  ps[t] = s;
  __syncthreads();
  for(int d = 1; d < 1024; d <<= 1){
    int v = (t >= d) ? ps[t-d] : 0;
    __syncthreads();
    ps[t] += v;
    __syncthreads();
  }
  int run = ps[t] - s;   // exclusive
  for(int i = lo; i < hi; i++){ off[i] = run; run += cnt[i]; }
  if(t == 1023) off[bins] = ps[1023];
}

// MODE 0: outp[pos] = src[e]
template<int PB, int MODE>
__global__ void k_scatter(const int* __restrict__ dst, const int* __restrict__ src,
                          int ne, int sub, int b0, const int* __restrict__ gh,
                          const int* __restrict__ off, int bins, int* __restrict__ outp){
  __shared__ int h[PB];
  for(int i = threadIdx.x; i < PB; i += 256)
    h[i] = off[b0 + i] + gh[(size_t)blockIdx.x*bins + b0 + i];
  __syncthreads();
  int chunk = (ne + NBLK - 1) / NBLK;
  int s0 = blockIdx.x*chunk, s1 = min(s0 + chunk, ne);
  for(int i = s0 + threadIdx.x; i < s1; i += 256){
    int b = dst[i] - sub - b0;
    if(b >= 0 && b < PB){
      int p = atomicAdd(&h[b], 1);
      outp[p] = src[i];
    }
  }
}

__global__ void k_dis_off(const int* __restrict__ off, float* __restrict__ dis, int n){
  int i = blockIdx.x*256 + threadIdx.x;
  if(i < n) dis[i] = rsqrtf((float)(off[i+1] - off[i]) + 1.0f);
}

// ======================= fast path: gathers (block per dst, MLP-unrolled) =======================

// h1s = h1*dis (pre-scaled). h2out written pre-scaled by dis[d] for layer 2.
__global__ void k_gcn_gather1(const float* __restrict__ hs, const float* __restrict__ dis,
                              const int* __restrict__ off, const int* __restrict__ srcperm,
                              const float* __restrict__ b1, const float* __restrict__ W2,
                              float* __restrict__ h2s){
  __shared__ float red[4][32];
  __shared__ float m[32];
  __shared__ float W2s[512];
  int d = blockIdx.x, tid = threadIdx.x;
  for(int i = tid; i < 512; i += 256) W2s[i] = W2[i];
  int col = tid & 31, g = tid >> 5;     // 8 groups
  int o0 = off[d], cnt = off[d+1] - o0;
  float s0 = 0.f, s1 = 0.f, s2 = 0.f, s3 = 0.f;
  int i = g;
  for(; i + 24 < cnt; i += 32){
    int j0 = srcperm[o0 + i],      j1 = srcperm[o0 + i + 8];
    int j2 = srcperm[o0 + i + 16], j3 = srcperm[o0 + i + 24];
    s0 += hs[j0*32 + col]; s1 += hs[j1*32 + col];
    s2 += hs[j2*32 + col]; s3 += hs[j3*32 + col];
  }
  for(; i < cnt; i += 8) s0 += hs[srcperm[o0 + i]*32 + col];
  float s = (s0 + s1) + (s2 + s3);
  s += __shfl_xor(s, 32);
  int wv = tid >> 6, lane = tid & 63;
  if(lane < 32) red[wv][lane] = s;
  __syncthreads();
  float dd = dis[d];
  if(tid < 32){
    float v = (red[0][tid]+red[1][tid]+red[2][tid]+red[3][tid] + hs[d*32 + tid])*dd + b1[tid];
    m[tid] = fmaxf(v, 0.f);
  }
  __syncthreads();
  if(tid < 16){
    float acc = 0.f;
    #pragma unroll
    for(int k = 0; k < 32; k++) acc = fmaf(m[k], W2s[k*16 + tid], acc);
    h2s[d*16 + tid] = acc * dd;       // pre-scale for layer 2
  }
}

// agg2 = (sum_src h2s[src] + h2s[d])*dis[d] + b2   (true agg2, unscaled output)
__global__ void k_gcn_gather2(const float* __restrict__ hs, const float* __restrict__ dis,
                              const int* __restrict__ off, const int* __restrict__ srcperm,
                              const float* __restrict__ b, float* __restrict__ agg){
  __shared__ float red[4][16];
  int d = blockIdx.x;
  int tid = threadIdx.x;
  int col = tid & 15;
  int g = tid >> 4;                    // 16 groups
  int o0 = off[d], cnt = off[d+1] - o0;
  float s0 = 0.f, s1 = 0.f;
  int i = g;
  for(; i + 16 < cnt; i += 32){
    int j0 = srcperm[o0 + i], j1 = srcperm[o0 + i + 16];
    s0 += hs[j0*16 + col];
    s1 += hs[j1*16 + col];
  }
  for(; i < cnt; i += 16) s0 += hs[srcperm[o0 + i]*16 + col];
  float s = s0 + s1;
  s += __shfl_xor(s, 32);
  s += __shfl_xor(s, 16);
  int wv = tid >> 6, lane = tid & 63;
  if(lane < 16) red[wv][lane] = s;
  __syncthreads();
  if(tid < 16){
    float tot = red[0][tid] + red[1][tid] + red[2][tid] + red[3][tid];
    float dd = dis[d];
    agg[d*16 + tid] = (tot + hs[d*16 + tid])*dd + b[tid];
  }
}

__global__ void k_dp_gather(const float* __restrict__ xp2, const int* __restrict__ off,
                            const int* __restrict__ srcperm, const float* __restrict__ hg,
                            float* __restrict__ xd, unsigned short* __restrict__ xdb){
  __shared__ float red[4][16];
  __shared__ float m[16];
  int d = blockIdx.x;
  int tid = threadIdx.x;
  int col = tid & 15, g = tid >> 4;
  int o0 = off[d], cnt = off[d+1] - o0;
  float s0 = 0.f, s1 = 0.f, s2 = 0.f, s3 = 0.f;
  int i = g;
  for(; i + 48 < cnt; i += 64){
    int j0 = srcperm[o0 + i],      j1 = srcperm[o0 + i + 16];
    int j2 = srcperm[o0 + i + 32], j3 = srcperm[o0 + i + 48];
    s0 += xp2[j0*16 + col]; s1 += xp2[j1*16 + col];
    s2 += xp2[j2*16 + col]; s3 += xp2[j3*16 + col];
  }
  for(; i < cnt; i += 16) s0 += xp2[srcperm[o0 + i]*16 + col];
  float s = (s0 + s1) + (s2 + s3);
  s += __shfl_xor(s, 32);
  s += __shfl_xor(s, 16);
  int wv = tid >> 6, lane = tid & 63;
  if(lane < 16) red[wv][lane] = s;
  __syncthreads();
  if(tid < 16) m[tid] = (red[0][tid]+red[1][tid]+red[2][tid]+red[3][tid]) / fmaxf((float)cnt, 1.f);
  __syncthreads();
  if(tid < 16){
    float acc = 0.f;
    #pragma unroll
    for(int k = 0; k < 16; k++) acc = fmaf(m[k], hg[k*16 + tid], acc);
    xd[d*64 + 48 + tid] = acc;
    xdb[d*64 + 48 + tid] = (unsigned short)f2bf(acc);
  }
}

// ======================= fast path: embed GEMM via MFMA =======================

__global__ __launch_bounds__(256) void k_embed_m(
    const float* __restrict__ xdrug, const unsigned short* __restrict__ embb,
    float* __restrict__ xdp){
  int tid = threadIdx.x;
  int wv = tid >> 6, l = tid & 63;
  int rt = blockIdx.x*4 + wv;            // row tile (16 rows)
  int row = rt*16 + (l & 15);
  int kg = (l >> 4) << 3;
  int cb = blockIdx.y * EKCH;
  bool valid = row < NDRUG;
  const float* xr = xdrug + (size_t)row * INDRUG;
  f32x4 z = {0.f,0.f,0.f,0.f};
  f32x4 c0 = z, c1 = z, c2 = z;
  #pragma unroll
  for(int ks = 0; ks < EKCH/32; ks++){
    int k0 = cb + ks*32;
    float4 u = make_float4(0,0,0,0), v = make_float4(0,0,0,0);
    if(valid){
      u = *(const float4*)(xr + k0 + kg);
      v = *(const float4*)(xr + k0 + kg + 4);
    }
    bf16x8 a;
    a[0] = (__bf16)u.x; a[1] = (__bf16)u.y; a[2] = (__bf16)u.z; a[3] = (__bf16)u.w;
    a[4] = (__bf16)v.x; a[5] = (__bf16)v.y; a[6] = (__bf16)v.z; a[7] = (__bf16)v.w;
    const unsigned short* bb = embb + (size_t)(k0 >> 5)*1536 + l*8;
    bf16x8 b0 = *(const bf16x8*)(bb);
    bf16x8 b1 = *(const bf16x8*)(bb + 512);
    bf16x8 b2 = *(const bf16x8*)(bb + 1024);
    c0 = __builtin_amdgcn_mfma_f32_16x16x32_bf16(a, b0, c0, 0,0,0);
    c1 = __builtin_amdgcn_mfma_f32_16x16x32_bf16(a, b1, c1, 0,0,0);
    c2 = __builtin_amdgcn_mfma_f32_16x16x32_bf16(a, b2, c2, 0,0,0);
  }
  int col = l & 15, rb = (l >> 4) << 2;
  float* op = xdp + (size_t)blockIdx.y * NDRUG * 48;
  #pragma unroll
  for(int r = 0; r < 4; r++){
    int ro = rt*16 + rb + r;
    if(ro < NDRUG){
      op[ro*48 + col]       = c0[r];
      op[ro*48 + 16 + col]  = c1[r];
      op[ro*48 + 32 + col]  = c2[r];
    }
  }
}

__global__ void k_embed_fin2(const float* __restrict__ xdp, const float* __restrict__ dnorm,
                             float* __restrict__ xd, unsigned short* __restrict__ xdb){
  int gid = blockIdx.x*256 + threadIdx.x;
  if(gid >= NDRUG*48) return;
  int d = gid / 48, j = gid % 48;
  float s = 0.f;
  for(int y = 0; y < KSPLIT; y++) s += xdp[(size_t)y*NDRUG*48 + gid];
  float v = s / dnorm[d];
  xd[d*64 + j] = v;
  xdb[d*64 + j] = (unsigned short)f2bf(v);
}

// ======================= RGCN msgs via MFMA (padded, branch-free) =======================

__global__ __launch_bounds__(256) void k_rgcn1_msgsM(
    const unsigned short* __restrict__ xdb, const int* __restrict__ psrc,
    const int* __restrict__ pblk, const unsigned short* __restrict__ wetb,
    unsigned short* __restrict__ msgs){
  int tid = threadIdx.x;
  int wv = tid >> 6, l = tid & 63;
  int t0 = pblk[blockIdx.x];
  const unsigned short* wb = wetb + (size_t)t0*2048 + l*8;
  bf16x8 w00 = *(const bf16x8*)(wb);
  bf16x8 w01 = *(const bf16x8*)(wb + 512);
  bf16x8 w10 = *(const bf16x8*)(wb + 1024);
  bf16x8 w11 = *(const bf16x8*)(wb + 1536);
  int eb = blockIdx.x*256 + wv*64;
  int col = l & 15;
  int g4 = (l >> 4) << 3;
  int rb = (l >> 4) << 2;
  int e0 = eb + col, e1 = eb + 16 + col, e2 = eb + 32 + col, e3 = eb + 48 + col;
  int s0 = psrc[e0], s1 = psrc[e1], s2 = psrc[e2], s3 = psrc[e3];
  const unsigned short* x0 = xdb + (size_t)s0*64 + g4;
  const unsigned short* x1 = xdb + (size_t)s1*64 + g4;
  const unsigned short* x2 = xdb + (size_t)s2*64 + g4;
  const unsigned short* x3 = xdb + (size_t)s3*64 + g4;
  bf16x8 a00 = *(const bf16x8*)(x0), a01 = *(const bf16x8*)(x0 + 32);
  bf16x8 a10 = *(const bf16x8*)(x1), a11 = *(const bf16x8*)(x1 + 32);
  bf16x8 a20 = *(const bf16x8*)(x2), a21 = *(const bf16x8*)(x2 + 32);
  bf16x8 a30 = *(const bf16x8*)(x3), a31 = *(const bf16x8*)(x3 + 32);
  f32x4 z = {0.f,0.f,0.f,0.f};
  f32x4 c00=z,c01=z,c10=z,c11=z,c20=z,c21=z,c30=z,c31=z;
  c00 = __builtin_amdgcn_mfma_f32_16x16x32_bf16(w00, a00, c00, 0,0,0);
  c00 = __builtin_amdgcn_mfma_f32_16x16x32_bf16(w10, a01, c00, 0,0,0);
  c01 = __builtin_amdgcn_mfma_f32_16x16x32_bf16(w01, a00, c01, 0,0,0);
  c01 = __builtin_amdgcn_mfma_f32_16x16x32_bf16(w11, a01, c01, 0,0,0);
  c10 = __builtin_amdgcn_mfma_f32_16x16x32_bf16(w00, a10, c10, 0,0,0);
  c10 = __builtin_amdgcn_mfma_f32_16x16x32_bf16(w10, a11, c10, 0,0,0);
  c11 = __builtin_amdgcn_mfma_f32_16x16x32_bf16(w01, a10, c11, 0,0,0);
  c11 = __builtin_amdgcn_mfma_f32_16x16x32_bf16(w11, a11, c11, 0,0,0);
  c20 = __builtin_amdgcn_mfma_f32_16x16x32_bf16(w00, a20, c20, 0,0,0);
  c20 = __builtin_amdgcn_mfma_f32_16x16x32_bf16(w10, a21, c20, 0,0,0);
  c21 = __builtin_amdgcn_mfma_f32_16x16x32_bf16(w01, a20, c21, 0,0,0);
  c21 = __builtin_amdgcn_mfma_f32_16x16x32_bf16(w11, a21, c21, 0,0,0);
  c30 = __builtin_amdgcn_mfma_f32_16x16x32_bf16(w00, a30, c30, 0,0,0);
  c30 = __builtin_amdgcn_mfma_f32_16x16x32_bf16(w10, a31, c30, 0,0,0);
  c31 = __builtin_amdgcn_mfma_f32_16x16x32_bf16(w01, a30, c31, 0,0,0);
  c31 = __builtin_amdgcn_mfma_f32_16x16x32_bf16(w11, a31, c31, 0,0,0);
  *(unsigned long long*)(msgs + (size_t)e0*32 + rb)      = pack4(c00);
  *(unsigned long long*)(msgs + (size_t)e0*32 + 16 + rb) = pack4(c01);
  *(unsigned long long*)(msgs + (size_t)e1*32 + rb)      = pack4(c10);
  *(unsigned long long*)(msgs + (size_t)e1*32 + 16 + rb) = pack4(c11);
  *(unsigned long long*)(msgs + (size_t)e2*32 + rb)      = pack4(c20);
  *(unsigned long long*)(msgs + (size_t)e2*32 + 16 + rb) = pack4(c21);
  *(unsigned long long*)(msgs + (size_t)e3*32 + rb)      = pack4(c30);
  *(unsigned long long*)(msgs + (size_t)e3*32 + 16 + rb) = pack4(c31);
}

__global__ __launch_bounds__(256) void k_rgcn2_msgsM(
    const unsigned short* __restrict__ xd1b, const int* __restrict__ psrc,
    const int* __restrict__ pblk, const unsigned short* __restrict__ wetb,
    unsigned short* __restrict__ msgs){
  int tid = threadIdx.x;
  int wv = tid >> 6, l = tid & 63;
  int t0 = pblk[blockIdx.x];
  bf16x8 w0 = *(const bf16x8*)(wetb + (size_t)t0*512 + l*8);
  int eb = blockIdx.x*256 + wv*64;
  int col = l & 15;
  int g4 = (l >> 4) << 3;
  int rb = (l >> 4) << 2;
  int e0 = eb + col, e1 = eb + 16 + col, e2 = eb + 32 + col, e3 = eb + 48 + col;
  int s0 = psrc[e0], s1 = psrc[e1], s2 = psrc[e2], s3 = psrc[e3];
  bf16x8 a0 = *(const bf16x8*)(xd1b + (size_t)s0*32 + g4);
  bf16x8 a1 = *(const bf16x8*)(xd1b + (size_t)s1*32 + g4);
  bf16x8 a2 = *(const bf16x8*)(xd1b + (size_t)s2*32 + g4);
  bf16x8 a3 = *(const bf16x8*)(xd1b + (size_t)s3*32 + g4);
  f32x4 z = {0.f,0.f,0.f,0.f};
  f32x4 c0=z,c1=z,c2=z,c3=z;
  c0 = __builtin_amdgcn_mfma_f32_16x16x32_bf16(w0, a0, c0, 0,0,0);
  c1 = __builtin_amdgcn_mfma_f32_16x16x32_bf16(w0, a1, c1, 0,0,0);
  c2 = __builtin_amdgcn_mfma_f32_16x16x32_bf16(w0, a2, c2, 0,0,0);
  c3 = __builtin_amdgcn_mfma_f32_16x16x32_bf16(w0, a3, c3, 0,0,0);
  *(unsigned long long*)(msgs + (size_t)e0*16 + rb) = pack4(c0);
  *(unsigned long long*)(msgs + (size_t)e1*16 + rb) = pack4(c1);
  *(unsigned long long*)(msgs + (size_t)e2*16 + rb) = pack4(c2);
  *(unsigned long long*)(msgs + (size_t)e3*16 + rb) = pack4(c3);
}

// block per dst: 16 row-streams, gather rows via eperm (padded ids), 4-way MLP unroll
__global__ void k_rgcn1_reduce(const unsigned short* __restrict__ msgs, const int* __restrict__ off,
                               const int* __restrict__ eperm,
                               const float* __restrict__ xd, const float* __restrict__ root,
                               float* __restrict__ xd1, unsigned short* __restrict__ xd1b){
  __shared__ float red[16][32];
  int d = blockIdx.x;
  int tid = threadIdx.x;
  int cp = tid & 15, r = tid >> 4;
  int o0 = off[d], cnt = off[d+1] - o0;
  float s0 = 0.f, s1 = 0.f;
  int i = r;
  for(; i + 48 < cnt; i += 64){
    int e0 = eperm[o0 + i],      e1 = eperm[o0 + i + 16];
    int e2 = eperm[o0 + i + 32], e3 = eperm[o0 + i + 48];
    unsigned int v0 = *(const unsigned int*)(msgs + (size_t)e0*32 + cp*2);
    unsigned int v1 = *(const unsigned int*)(msgs + (size_t)e1*32 + cp*2);
    unsigned int v2 = *(const unsigned int*)(msgs + (size_t)e2*32 + cp*2);
    unsigned int v3 = *(const unsigned int*)(msgs + (size_t)e3*32 + cp*2);
    s0 += bf2f(v0 & 0xffffu) + bf2f(v1 & 0xffffu) + bf2f(v2 & 0xffffu) + bf2f(v3 & 0xffffu);
    s1 += bf2f(v0 >> 16)     + bf2f(v1 >> 16)     + bf2f(v2 >> 16)     + bf2f(v3 >> 16);
  }
  for(; i < cnt; i += 16){
    int e0 = eperm[o0 + i];
    unsigned int v = *(const unsigned int*)(msgs + (size_t)e0*32 + cp*2);
    s0 += bf2f(v & 0xffffu); s1 += bf2f(v >> 16);
  }
  red[r][cp*2] = s0; red[r][cp*2+1] = s1;
  __syncthreads();
  if(tid < 32){
    float tot = 0.f;
    #pragma unroll
    for(int r2 = 0; r2 < 16; r2++) tot += red[r2][tid];
    float rr = 0.f;
    const float* x = xd + d*64;
    #pragma unroll 8
    for(int i2 = 0; i2 < 64; i2++) rr = fmaf(x[i2], root[i2*32 + tid], rr);
    float v = fmaxf(tot / fmaxf((float)cnt, 1.0f) + rr, 0.f);
    xd1[d*32 + tid] = v;
    xd1b[d*32 + tid] = (unsigned short)f2bf(v);
  }
}

__global__ void k_rgcn2_reduce(const unsigned short* __restrict__ msgs, const int* __restrict__ off,
                               const int* __restrict__ eperm,
                               const float* __restrict__ xd1, const float* __restrict__ root,
                               float* __restrict__ out){
  __shared__ float red[32][16];
  int d = blockIdx.x;
  int tid = threadIdx.x;
  int cp = tid & 7, r = tid >> 3;
  int o0 = off[d], cnt = off[d+1] - o0;
  float s0 = 0.f, s1 = 0.f;
  int i = r;
  for(; i + 96 < cnt; i += 128){
    int e0 = eperm[o0 + i],      e1 = eperm[o0 + i + 32];
    int e2 = eperm[o0 + i + 64], e3 = eperm[o0 + i + 96];
    unsigned int v0 = *(const unsigned int*)(msgs + (size_t)e0*16 + cp*2);
    unsigned int v1 = *(const unsigned int*)(msgs + (size_t)e1*16 + cp*2);
    unsigned int v2 = *(const unsigned int*)(msgs + (size_t)e2*16 + cp*2);
    unsigned int v3 = *(const unsigned int*)(msgs + (size_t)e3*16 + cp*2);
    s0 += bf2f(v0 & 0xffffu) + bf2f(v1 & 0xffffu) + bf2f(v2 & 0xffffu) + bf2f(v3 & 0xffffu);
    s1 += bf2f(v0 >> 16)     + bf2f(v1 >> 16)     + bf2f(v2 >> 16)     + bf2f(v3 >> 16);
  }
  for(; i < cnt; i += 32){
    int e0 = eperm[o0 + i];
    unsigned int v = *(const unsigned int*)(msgs + (size_t)e0*16 + cp*2);
    s0 += bf2f(v & 0xffffu); s1 += bf2f(v >> 16);
  }
  red[r][cp*2] = s0; red[r][cp*2+1] = s1;
  __syncthreads();
  if(tid < 16){
    float tot = 0.f;
    #pragma unroll
    for(int r2 = 0; r2 < 32; r2++) tot += red[r2][tid];
    float rr = 0.f;
    const float* x = xd1 + d*32;
    #pragma unroll 8
    for(int i2 = 0; i2 < 32; i2++) rr = fmaf(x[i2], root[i2*16 + tid], rr);
    out[d*16 + tid] = tot / fmaxf((float)cnt, 1.0f) + rr;
  }
}

// ======================= fallback (round-1) kernels =======================

#define O_CNTPP   0
#define O_DIS     20000
#define O_H1      40000
#define O_AGG1    680000
#define O_H2      1320000
#define O_AGG2    1640000
#define O_DPSUM   1960000
#define O_DPCNT   2024000
#define O_XD      2028000
#define O_WET1    2284000
#define O_WET2    2546144
#define O_CNTDD   2611680
#define O_RSUM1   2615680
#define O_XD1     2743680
#define O_RSUM2   2871680

__global__ void k_count_int(const int* __restrict__ dst, int ne, int* __restrict__ cnt){
  int i = blockIdx.x*256 + threadIdx.x;
  if(i < ne) atomicAdd(&cnt[dst[i]], 1);
}

__global__ void k_dis(const int* __restrict__ cnt, float* __restrict__ dis, int n){
  int i = blockIdx.x*256 + threadIdx.x;
  if(i < n) dis[i] = rsqrtf((float)cnt[i] + 1.0f);
}

template<int NC>
__global__ void k_gcn_init(const float* __restrict__ h, const float* __restrict__ dis,
                           const float* __restrict__ b, float* __restrict__ agg, int n){
  int i = blockIdx.x*256 + threadIdx.x;
  if(i < n*NC){
    int r = i / NC, c = i % NC;
    float d = dis[r];
    agg[i] = fmaf(h[i], d*d, b[c]);
  }
}

template<int NC>
__global__ void k_gcn_scatter(const float* __restrict__ h, const float* __restrict__ dis,
                              const int* __restrict__ src, const int* __restrict__ dst,
                              int ne, float* __restrict__ agg){
  int gid = blockIdx.x*256 + threadIdx.x;
  int e = gid / NC, j = gid % NC;
  if(e >= ne) return;
  int s = src[e], d = dst[e];
  atomicAdd(&agg[d*NC + j], h[s*NC + j] * dis[s] * dis[d]);
}

__global__ void k_dp_scatter(const float* __restrict__ xp2, const int* __restrict__ src,
                             const int* __restrict__ dst, float* __restrict__ dpsum,
                             int* __restrict__ dpcnt){
  int gid = blockIdx.x*256 + threadIdx.x;
  int e = gid >> 4, j = gid & 15;
  if(e >= EDP) return;
  int s = src[e], d = dst[e] - NPROT;
  atomicAdd(&dpsum[d*16 + j], xp2[s*16 + j]);
  if(j == 0) atomicAdd(&dpcnt[d], 1);
}

__global__ void k_hier(const float* __restrict__ dpsum, const int* __restrict__ dpcnt,
                       const float* __restrict__ hg, float* __restrict__ xd){
  int gid = blockIdx.x*256 + threadIdx.x;
  int d = gid >> 4, j = gid & 15;
  if(d >= NDRUG) return;
  float inv = 1.0f / fmaxf((float)dpcnt[d], 1.0f);
  float acc = 0.f;
  #pragma unroll
  for(int k = 0; k < 16; k++) acc = fmaf(dpsum[d*16 + k] * inv, hg[k*16 + j], acc);
  xd[d*64 + 48 + j] = acc;
}

__global__ void k_embed(const float* __restrict__ xdrug, const float* __restrict__ embed,
                        float* __restrict__ xd){
  __shared__ float xs[64][65];
  __shared__ float es[64][48];
  int tid = threadIdx.x;
  int r = tid & 63;
  int cg = tid >> 6;
  int row0 = blockIdx.x * 64;
  int k0c = blockIdx.y * 512;
  float acc[12];
  #pragma unroll
  for(int j = 0; j < 12; j++) acc[j] = 0.f;
  for(int kt = 0; kt < 512; kt += 64){
    int k0 = k0c + kt;
    if(k0 >= INDRUG) break;
    __syncthreads();
    #pragma unroll
    for(int i = 0; i < 4; i++){
      int lin = tid + i*256;
      int rr = lin >> 4, kc = lin & 15;
      int grow = row0 + rr, gk = k0 + kc*4;
      float4 v = make_float4(0.f,0.f,0.f,0.f);
      if(grow < NDRUG && gk + 3 < INDRUG)
        v = *(const float4*)&xdrug[(size_t)grow * INDRUG + gk];
      xs[rr][kc*4+0]=v.x; xs[rr][kc*4+1]=v.y; xs[rr][kc*4+2]=v.z; xs[rr][kc*4+3]=v.w;
    }
    #pragma unroll
    for(int i = 0; i < 3; i++){
      int lin = tid + i*256;
      int kk = lin / 12, jc = lin % 12;
      float4 v = make_float4(0.f,0.f,0.f,0.f);
      if(k0 + kk < INDRUG)
        v = *(const float4*)&embed[(size_t)(k0 + kk) * NEMBED + jc*4];
      *(float4*)&es[kk][jc*4] = v;
    }
    __syncthreads();
    #pragma unroll 8
    for(int kk = 0; kk < 64; kk++){
      float xv = xs[r][kk];
      const float4* ep = (const float4*)&es[kk][cg*12];
      float4 e0 = ep[0], e1 = ep[1], e2 = ep[2];
      acc[0]=fmaf(xv,e0.x,acc[0]);  acc[1]=fmaf(xv,e0.y,acc[1]);
      acc[2]=fmaf(xv,e0.z,acc[2]);  acc[3]=fmaf(xv,e0.w,acc[3]);
      acc[4]=fmaf(xv,e1.x,acc[4]);  acc[5]=fmaf(xv,e1.y,acc[5]);
      acc[6]=fmaf(xv,e1.z,acc[6]);  acc[7]=fmaf(xv,e1.w,acc[7]);
      acc[8]=fmaf(xv,e2.x,acc[8]);  acc[9]=fmaf(xv,e2.y,acc[9]);
      acc[10]=fmaf(xv,e2.z,acc[10]); acc[11]=fmaf(xv,e2.w,acc[11]);
    }
  }
  int grow = row0 + r;
  if(grow < NDRUG){
    #pragma unroll
    for(int j = 0; j < 12; j++)
      atomicAdd(&xd[grow*64 + cg*12 + j], acc[j]);
  }
}

__global__ void k_embed_fin(float* __restrict__ xd, const float* __restrict__ dnorm){
  int gid = blockIdx.x*256 + threadIdx.x;
  if(gid >= NDRUG*48) return;
  int d = gid / 48, j = gid % 48;
  xd[d*64 + j] = xd[d*64 + j] / dnorm[d];
}

__global__ void k_rgcn1(const float* __restrict__ xd, const int* __restrict__ src,
                        const int* __restrict__ dst, const int* __restrict__ et,
                        const float* __restrict__ wet, float* __restrict__ rsum){
  int tid = threadIdx.x;
  int e = blockIdx.x*64 + (tid >> 2);
  if(e >= EDD) return;
  int jg = tid & 3;
  int s = src[e], d = dst[e], t = et[e];
  const float* x = xd + s*64;
  const float* w = wet + t*2048 + jg*8;
  float acc[8] = {0,0,0,0,0,0,0,0};
  #pragma unroll 8
  for(int i = 0; i < 64; i++){
    float xv = x[i];
    const float4* wp = (const float4*)(w + i*32);
    float4 w0 = wp[0], w1 = wp[1];
    acc[0]=fmaf(xv,w0.x,acc[0]); acc[1]=fmaf(xv,w0.y,acc[1]);
    acc[2]=fmaf(xv,w0.z,acc[2]); acc[3]=fmaf(xv,w0.w,acc[3]);
    acc[4]=fmaf(xv,w1.x,acc[4]); acc[5]=fmaf(xv,w1.y,acc[5]);
    acc[6]=fmaf(xv,w1.z,acc[6]); acc[7]=fmaf(xv,w1.w,acc[7]);
  }
  float* outp = rsum + d*32 + jg*8;
  #pragma unroll
  for(int j = 0; j < 8; j++) atomicAdd(&outp[j], acc[j]);
}

__global__ void k_rgcn2(const float* __restrict__ xd1, const int* __restrict__ src,
                        const int* __restrict__ dst, const int* __restrict__ et,
                        const float* __restrict__ wet, float* __restrict__ rsum){
  int tid = threadIdx.x;
  int e = blockIdx.x*128 + (tid >> 1);
  if(e >= EDD) return;
  int jg = tid & 1;
  int s = src[e], d = dst[e], t = et[e];
  const float* x = xd1 + s*32;
  const float* w = wet + t*512 + jg*8;
  float acc[8] = {0,0,0,0,0,0,0,0};
  #pragma unroll 8
  for(int i = 0; i < 32; i++){
    float xv = x[i];
    const float4* wp = (const float4*)(w + i*16);
    float4 w0 = wp[0], w1 = wp[1];
    acc[0]=fmaf(xv,w0.x,acc[0]); acc[1]=fmaf(xv,w0.y,acc[1]);
    acc[2]=fmaf(xv,w0.z,acc[2]); acc[3]=fmaf(xv,w0.w,acc[3]);
    acc[4]=fmaf(xv,w1.x,acc[4]); acc[5]=fmaf(xv,w1.y,acc[5]);
    acc[6]=fmaf(xv,w1.z,acc[6]); acc[7]=fmaf(xv,w1.w,acc[7]);
  }
  float* outp = rsum + d*16 + jg*8;
  #pragma unroll
  for(int j = 0; j < 8; j++) atomicAdd(&outp[j], acc[j]);
}

__global__ void k_root1(const float* __restrict__ rsum, const int* __restrict__ cnt,
                        const float* __restrict__ xd, const float* __restrict__ root,
                        float* __restrict__ xd1){
  int gid = blockIdx.x*256 + threadIdx.x;
  int d = gid >> 5, j = gid & 31;
  if(d >= NDRUG) return;
  float inv = 1.0f / fmaxf((float)cnt[d], 1.0f);
  float acc = rsum[d*32 + j] * inv;
  #pragma unroll
  for(int i = 0; i < 64; i++) acc = fmaf(xd[d*64 + i], root[i*32 + j], acc);
  xd1[d*32 + j] = fmaxf(acc, 0.f);
}

__global__ void k_root2(const float* __restrict__ rsum, const int* __restrict__ cnt,
                        const float* __restrict__ xd1, const float* __restrict__ root,
                        float* __restrict__ out){
  int gid = blockIdx.x*256 + threadIdx.x;
  int d = gid >> 4, j = gid & 15;
  if(d >= NDRUG) return;
  float inv = 1.0f / fmaxf((float)cnt[d], 1.0f);
  float acc = rsum[d*16 + j] * inv;
  #pragma unroll
  for(int i = 0; i < 32; i++) acc = fmaf(xd1[d*32 + i], root[i*16 + j], acc);
  out[d*16 + j] = acc;
}

// ======================= launch =======================

extern "C" void kernel_launch(void* const* d_in, const int* in_sizes, int n_in,
                              void* d_out, int out_size, void* d_ws, size_t ws_size,
                              hipStream_t stream){
  const float* x_drug  = (const float*)d_in[0];
  const float* d_norm  = (const float*)d_in[1];
  const float* x_prot  = (const float*)d_in[2];
  const int*   pp_ei   = (const int*)d_in[3];
  const int*   dp_ei   = (const int*)d_in[4];
  const int*   dd_ei   = (const int*)d_in[6];
  const int*   dd_et   = (const int*)d_in[7];
  const int*   dd_rl   = (const int*)d_in[8];
  const float* embed   = (const float*)d_in[9];
  const float* W1      = (const float*)d_in[10];
  const float* b1      = (const float*)d_in[11];
  const float* W2      = (const float*)d_in[12];
  const float* b2      = (const float*)d_in[13];
  const float* hgw     = (const float*)d_in[14];
  const float* att1    = (const float*)d_in[15];
  const float* basis1  = (const float*)d_in[16];
  const float* root1   = (const float*)d_in[17];
  const float* att2    = (const float*)d_in[18];
  const float* basis2  = (const float*)d_in[19];
  const float* root2   = (const float*)d_in[20];
  float* out = (float*)d_out;
  float* ws = (float*)d_ws;

  const int* pp_src = pp_ei;
  const int* pp_dst = pp_ei + EPP;
  const int* dp_src = dp_ei;
  const int* dp_dst = dp_ei + EDP;
  const int* dd_src = dd_ei;
  const int* dd_dst = dd_ei + EDD;

  // ---- fast-path ws layout ----
  auto pad = [](size_t n){ return (n + 15) & ~(size_t)15; };
  size_t o = 0;
  size_t oPPOFF = o; o += pad(NPROT + 1);
  size_t oDPOFF = o; o += pad(NDRUG + 1);
  size_t oDDOFF = o; o += pad(NDRUG + 1);
  size_t oDIS   = o; o += pad(NPROT);
  size_t oH1    = o; o += pad((size_t)NPROT*32);
  size_t oH2    = o; o += pad((size_t)NPROT*16);
  size_t oAGG2  = o; o += pad((size_t)NPROT*16);
  size_t oXD    = o; o += pad((size_t)NDRUG*64);
  size_t oXD1   = o; o += pad((size_t)NDRUG*32);
  size_t oXDB   = o; o += pad((size_t)NDRUG*32);
  size_t oXD1B  = o; o += pad((size_t)NDRUG*16);
  size_t oWETB1 = o; o += pad((size_t)NET*1024);
  size_t oWETB2 = o; o += pad((size_t)NET*256);
  size_t oEMBB  = o; o += pad((size_t)125*768);   // 125*1536 ushort
  size_t oSRCPP = o; o += pad(EPP);
  size_t oSRCDP = o; o += pad(EDP);
  size_t oEPERM = o; o += pad(EDD);
  size_t oPSTART= o; o += pad(NET + 1);
  size_t oPBLK  = o; o += pad(PBLKS);
  size_t oPSRC  = o; o += pad(PEDD);
  size_t oPMAPE = o; o += pad(EDD);
  size_t oCNT   = o; o += pad(NPROT);
  size_t oPSUM  = o; o += pad((size_t)SCANG*NPROT);
  size_t oGH    = o; o += pad((size_t)NBLK*NPROT);
  // msgs region, aliased with xdp (disjoint lifetimes):
  size_t msgsN  = (size_t)PEDD*16;
  size_t xdpN   = (size_t)KSPLIT*NDRUG*48;
  size_t bigN   = msgsN > xdpN ? msgsN : xdpN;
  size_t oMSGS  = o; o += pad(bigN);
  size_t need_bytes = o * 4;

  if(ws_size >= need_bytes){
    // =================== FAST PATH ===================
    int* ppoff = (int*)(ws + oPPOFF);
    int* dpoff = (int*)(ws + oDPOFF);
    int* ddoff = (int*)(ws + oDDOFF);
    float* dis = ws + oDIS;
    float* h1  = ws + oH1;
    float* h2  = ws + oH2;
    float* agg2= ws + oAGG2;
    float* xd  = ws + oXD;
    float* xd1 = ws + oXD1;
    unsigned short* xdb  = (unsigned short*)(ws + oXDB);
    unsigned short* xd1b = (unsigned short*)(ws + oXD1B);
    unsigned short* wetb1 = (unsigned short*)(ws + oWETB1);
    unsigned short* wetb2 = (unsigned short*)(ws + oWETB2);
    unsigned short* embb  = (unsigned short*)(ws + oEMBB);
    int* srcpp = (int*)(ws + oSRCPP);
    int* srcdp = (int*)(ws + oSRCDP);
    int* eperm = (int*)(ws + oEPERM);
    int* pstart= (int*)(ws + oPSTART);
    int* pblk  = (int*)(ws + oPBLK);
    int* psrc  = (int*)(ws + oPSRC);
    int* pmape = (int*)(ws + oPMAPE);
    int* cnt   = (int*)(ws + oCNT);
    int* psum  = (int*)(ws + oPSUM);
    int* gh    = (int*)(ws + oGH);
    float* xdp = ws + oMSGS;                              // alias (dead before msgs)
    unsigned short* msgs = (unsigned short*)(ws + oMSGS);

    // ---- padded edge layout prep ----
    hipMemsetAsync(pblk, 0, PBLKS*sizeof(int), stream);
    hipMemsetAsync(psrc, 0, PEDD*sizeof(int), stream);
    k_pstart<<<1,NET,0,stream>>>(dd_rl, pstart, pblk);
    k_pmap<<<(EDD+255)/256,256,0,stream>>>(dd_et, dd_src, dd_rl, pstart, psrc, pmape);

    // ---- PP CSR (LDS hist, 2 passes of 10000 bins, 2-phase scan) ----
    k_hist<10000><<<NBLK,256,0,stream>>>(pp_dst, EPP, 0, 0,     gh, NPROT);
    k_hist<10000><<<NBLK,256,0,stream>>>(pp_dst, EPP, 0, 10000, gh, NPROT);
    {
      dim3 gs((NPROT+255)/256, SCANG);
      k_scan_p1<<<gs,256,0,stream>>>(gh, psum, NPROT);
      k_scan_p2<<<gs,256,0,stream>>>(gh, psum, cnt, NPROT);
    }
    k_scan_off<<<1,1024,0,stream>>>(cnt, ppoff, NPROT);
    k_scatter<10000,0><<<NBLK,256,0,stream>>>(pp_dst, pp_src, EPP, 0, 0,     gh, ppoff, NPROT, srcpp);
    k_scatter<10000,0><<<NBLK,256,0,stream>>>(pp_dst, pp_src, EPP, 0, 10000, gh, ppoff, NPROT, srcpp);
    k_dis_off<<<(NPROT+255)/256,256,0,stream>>>(ppoff, dis, NPROT);

    // ---- PP GCN (pre-scaled features) ----
    k_gemm_s<<<(NPROT*32+255)/256,256,0,stream>>>(x_prot, W1, dis, h1, NPROT);
    k_gcn_gather1<<<NPROT,256,0,stream>>>(h1, dis, ppoff, srcpp, b1, W2, h2);
    k_gcn_gather2<<<NPROT,256,0,stream>>>(h2, dis, ppoff, srcpp, b2, agg2);

    // ---- DP CSR + hierarchy ----
    k_hist<4000><<<NBLK,256,0,stream>>>(dp_dst, EDP, NPROT, 0, gh, NDRUG);
    {
      dim3 gs((NDRUG+255)/256, SCANG);
      k_scan_p1<<<gs,256,0,stream>>>(gh, psum, NDRUG);
      k_scan_p2<<<gs,256,0,stream>>>(gh, psum, cnt, NDRUG);
    }
    k_scan_off<<<1,1024,0,stream>>>(cnt, dpoff, NDRUG);
    k_scatter<4000,0><<<NBLK,256,0,stream>>>(dp_dst, dp_src, EDP, NPROT, 0, gh, dpoff, NDRUG, srcdp);
    k_dp_gather<<<NDRUG,256,0,stream>>>(agg2, dpoff, srcdp, hgw, xd, xdb);

    // ---- drug embedding via MFMA (xdp aliased; consumed by fin2) ----
    k_embb<<<(125*1536+255)/256,256,0,stream>>>(embed, embb);
    {
      dim3 g(63, KSPLIT);
      k_embed_m<<<g,256,0,stream>>>(x_drug, embb, xdp);
    }
    k_embed_fin2<<<(NDRUG*48+255)/256,256,0,stream>>>(xdp, d_norm, xd, xdb);

    // ---- RGCN prep (wetb built directly from att/basis) ----
    k_wetb1<<<(NET*2048+255)/256,256,0,stream>>>(att1, basis1, wetb1);
    k_wetb2<<<(NET*512+255)/256,256,0,stream>>>(att2, basis2, wetb2);
    k_hist<4000><<<NBLK,256,0,stream>>>(dd_dst, EDD, 0, 0, gh, NDRUG);
    {
      dim3 gs((NDRUG+255)/256, SCANG);
      k_scan_p1<<<gs,256,0,stream>>>(gh, psum, NDRUG);
      k_scan_p2<<<gs,256,0,stream>>>(gh, psum, cnt, NDRUG);
    }
    k_scan_off<<<1,1024,0,stream>>>(cnt, ddoff, NDRUG);
    // eperm[pos] = padded edge id
    k_scatter<4000,0><<<NBLK,256,0,stream>>>(dd_dst, pmape, EDD, 0, 0, gh, ddoff, NDRUG, eperm);

    // ---- RGCN layer 1 (MFMA, padded, branch-free) ----
    k_rgcn1_msgsM<<<PBLKS,256,0,stream>>>(xdb, psrc, pblk, wetb1, msgs);
    k_rgcn1_reduce<<<NDRUG,256,0,stream>>>(msgs, ddoff, eperm, xd, root1, xd1, xd1b);
    // ---- RGCN layer 2 ----
    k_rgcn2_msgsM<<<PBLKS,256,0,stream>>>(xd1b, psrc, pblk, wetb2, msgs);
    k_rgcn2_reduce<<<NDRUG,256,0,stream>>>(msgs, ddoff, eperm, xd1, root2, out);
  } else {
    // =================== FALLBACK (round-1, atomic) ===================
    int*   cnt_pp = (int*)(ws + O_CNTPP);
    float* dis    = ws + O_DIS;
    float* h1     = ws + O_H1;
    float* agg1   = ws + O_AGG1;
    float* h2     = ws + O_H2;
    float* agg2   = ws + O_AGG2;
    float* dpsum  = ws + O_DPSUM;
    int*   dpcnt  = (int*)(ws + O_DPCNT);
    float* xd     = ws + O_XD;
    float* wet1   = ws + O_WET1;
    float* wet2   = ws + O_WET2;
    int*   cntdd  = (int*)(ws + O_CNTDD);
    float* rsum1  = ws + O_RSUM1;
    float* xd1    = ws + O_XD1;
    float* rsum2  = ws + O_RSUM2;

    hipMemsetAsync(cnt_pp, 0, NPROT*sizeof(int), stream);
    hipMemsetAsync(dpsum,  0, (64000 + 4000)*sizeof(float), stream);
    hipMemsetAsync(xd,     0, NDRUG*64*sizeof(float), stream);
    hipMemsetAsync(cntdd,  0, NDRUG*sizeof(int), stream);
    hipMemsetAsync(rsum1,  0, NDRUG*32*sizeof(float), stream);
    hipMemsetAsync(rsum2,  0, NDRUG*16*sizeof(float), stream);

    k_count_int<<<(EPP+255)/256,256,0,stream>>>(pp_dst, EPP, cnt_pp);
    k_dis<<<(NPROT+255)/256,256,0,stream>>>(cnt_pp, dis, NPROT);
    k_gemm<64,32,false><<<(NPROT*32+255)/256,256,0,stream>>>(x_prot, W1, h1, NPROT);
    k_gcn_init<32><<<(NPROT*32+255)/256,256,0,stream>>>(h1, dis, b1, agg1, NPROT);
    k_gcn_scatter<32><<<(EPP*32)/256,256,0,stream>>>(h1, dis, pp_src, pp_dst, EPP, agg1);
    k_gemm<32,16,true><<<(NPROT*16+255)/256,256,0,stream>>>(agg1, W2, h2, NPROT);
    k_gcn_init<16><<<(NPROT*16+255)/256,256,0,stream>>>(h2, dis, b2, agg2, NPROT);
    k_gcn_scatter<16><<<(EPP*16)/256,256,0,stream>>>(h2, dis, pp_src, pp_dst, EPP, agg2);
    k_dp_scatter<<<(EDP*16)/256,256,0,stream>>>(agg2, dp_src, dp_dst, dpsum, dpcnt);
    k_hier<<<(NDRUG*16+255)/256,256,0,stream>>>(dpsum, dpcnt, hgw, xd);
    {
      dim3 g((NDRUG+63)/64, 8);
      k_embed<<<g,256,0,stream>>>(x_drug, embed, xd);
    }
    k_embed_fin<<<(NDRUG*48+255)/256,256,0,stream>>>(xd, d_norm);
    k_wet<<<(NET*2048+255)/256,256,0,stream>>>(att1, basis1, wet1, 2048);
    k_wet<<<(NET*512+255)/256,256,0,stream>>>(att2, basis2, wet2, 512);
    k_count_int<<<(EDD+255)/256,256,0,stream>>>(dd_dst, EDD, cntdd);
    k_rgcn1<<<EDD/64,256,0,stream>>>(xd, dd_src, dd_dst, dd_et, wet1, rsum1);
    k_root1<<<(NDRUG*32+255)/256,256,0,stream>>>(rsum1, cntdd, xd, root1, xd1);
    k_rgcn2<<<(EDD+127)/128,256,0,stream>>>(xd1, dd_src, dd_dst, dd_et, wet2, rsum2);
    k_root2<<<(NDRUG*16+255)/256,256,0,stream>>>(rsum2, cntdd, xd1, root2, out);
  }
}

// Round 23
// 342.222 us; speedup vs baseline: 1.4978x; 1.0339x over previous
//
#include <hip/hip_runtime.h>

#define NPROT 20000
#define NDRUG 4000
#define INDRUG 4000
#define NET 128
#define NBASE 32
#define NEMBED 48
#define PDDIM 16
#define H1C 32
#define H2C 16
#define RGCNIN 64
#define EPP 800000
#define EDP 400000
#define EDD 1000000
#define NBLK 256
#define SCANG 8             // b-groups for 2-phase scan (256/32)
#define EKCH 160            // 5 k-steps of 32 per chunk
#define KSPLIT 25           // 4000 / 160
#define PBLKS 4035          // ceil(EDD/256) + NET
#define PEDD (PBLKS*256)    // padded edge capacity (1032960)

typedef __attribute__((ext_vector_type(8))) __bf16 bf16x8;
typedef __attribute__((ext_vector_type(4))) float f32x4;

__device__ __forceinline__ unsigned int f2bf(float f){
  unsigned int u = __float_as_uint(f);
  u += 0x7fffu + ((u >> 16) & 1u);     // RNE
  return u >> 16;
}
__device__ __forceinline__ float bf2f(unsigned int s){
  return __uint_as_float(s << 16);
}
__device__ __forceinline__ unsigned long long pack4(const f32x4& c){
  unsigned long long lo = (unsigned long long)(f2bf(c[0]) | (f2bf(c[1]) << 16));
  unsigned long long hi = (unsigned long long)(f2bf(c[2]) | (f2bf(c[3]) << 16));
  return lo | (hi << 32);
}

// ======================= shared kernels =======================

template<int K, int NC, bool RELU_IN>
__global__ void k_gemm(const float* __restrict__ A, const float* __restrict__ W,
                       float* __restrict__ C, int M){
  __shared__ float Ws[K*NC];
  for(int i = threadIdx.x; i < K*NC; i += 256) Ws[i] = W[i];
  __syncthreads();
  int idx = blockIdx.x*256 + threadIdx.x;
  int row = idx / NC, col = idx % NC;
  if(row >= M) return;
  const float* a = A + row*K;
  float acc = 0.f;
  #pragma unroll
  for(int k = 0; k < K; k++){
    float v = a[k];
    if(RELU_IN) v = fmaxf(v, 0.f);
    acc = fmaf(v, Ws[k*NC + col], acc);
  }
  C[idx] = acc;
}

// h1s = (x_prot @ W1) * dis[row]   (K=64, NC=32)
__global__ void k_gemm_s(const float* __restrict__ A, const float* __restrict__ W,
                         const float* __restrict__ dis, float* __restrict__ C, int M){
  __shared__ float Ws[64*32];
  for(int i = threadIdx.x; i < 64*32; i += 256) Ws[i] = W[i];
  __syncthreads();
  int idx = blockIdx.x*256 + threadIdx.x;
  int row = idx >> 5, col = idx & 31;
  if(row >= M) return;
  const float* a = A + row*64;
  float acc = 0.f;
  #pragma unroll
  for(int k = 0; k < 64; k++)
    acc = fmaf(a[k], Ws[k*32 + col], acc);
  C[idx] = acc * dis[row];
}

__global__ void k_wet(const float* __restrict__ att, const float* __restrict__ basis,
                      float* __restrict__ wet, int inout){
  int gid = blockIdx.x*256 + threadIdx.x;
  if(gid >= NET * inout) return;
  int et = gid / inout, ij = gid % inout;
  float acc = 0.f;
  #pragma unroll
  for(int b = 0; b < NBASE; b++)
    acc = fmaf(att[et*NBASE + b], basis[b*inout + ij], acc);
  wet[gid] = acc;
}

// bf16 fragment build DIRECT from att/basis: wetb1[et][f][l][j], f = kt*2+nt
__global__ void k_wetb1(const float* __restrict__ att, const float* __restrict__ basis,
                        unsigned short* __restrict__ wetb){
  int gid = blockIdx.x*256 + threadIdx.x;
  if(gid >= NET*2048) return;
  int et = gid >> 11, r = gid & 2047;
  int f = r >> 9, l = (r >> 3) & 63, j = r & 7;
  int kt = f >> 1, nt = f & 1;
  int k = kt*32 + ((l >> 4) << 3) + j;
  int c = nt*16 + (l & 15);
  float acc = 0.f;
  #pragma unroll
  for(int b = 0; b < NBASE; b++)
    acc = fmaf(att[et*NBASE + b], basis[b*2048 + k*32 + c], acc);
  wetb[gid] = (unsigned short)f2bf(acc);
}

__global__ void k_wetb2(const float* __restrict__ att, const float* __restrict__ basis,
                        unsigned short* __restrict__ wetb){
  int gid = blockIdx.x*256 + threadIdx.x;
  if(gid >= NET*512) return;
  int et = gid >> 9, r = gid & 511;
  int l = r >> 3, j = r & 7;
  int k = ((l >> 4) << 3) + j;
  int c = l & 15;
  float acc = 0.f;
  #pragma unroll
  for(int b = 0; b < NBASE; b++)
    acc = fmaf(att[et*NBASE + b], basis[b*512 + k*16 + c], acc);
  wetb[gid] = (unsigned short)f2bf(acc);
}

// embed B-fragment table: embb[kt][f][l][j], kt=0..124, f=0..2
__global__ void k_embb(const float* __restrict__ embed, unsigned short* __restrict__ embb){
  int gid = blockIdx.x*256 + threadIdx.x;
  if(gid >= 125*1536) return;
  int kt = gid / 1536, r = gid % 1536;
  int f = r / 512, l = (r >> 3) & 63, j = r & 7;
  int k = kt*32 + ((l >> 4) << 3) + j;
  int c = f*16 + (l & 15);
  embb[gid] = (unsigned short)f2bf(embed[k*48 + c]);
}

// ======================= padded edge layout =======================

__global__ void k_pstart(const int* __restrict__ range, int* __restrict__ pstart,
                         int* __restrict__ pblk){
  __shared__ int ps[NET];
  int t = threadIdx.x;
  int cnt = range[t*2+1] - range[t*2];
  int padc = (cnt + 255) & ~255;
  ps[t] = padc;
  __syncthreads();
  int myoff = 0;
  for(int i = 0; i < t; i++) myoff += ps[i];
  pstart[t] = myoff;
  if(t == NET-1) pstart[NET] = myoff + padc;
  int b0 = myoff >> 8, nb = padc >> 8;
  for(int i = 0; i < nb; i++) pblk[b0 + i] = t;
}

__global__ void k_pmap(const int* __restrict__ et, const int* __restrict__ src,
                       const int* __restrict__ range, const int* __restrict__ pstart,
                       int* __restrict__ psrc, int* __restrict__ pmape){
  int e = blockIdx.x*256 + threadIdx.x;
  if(e >= EDD) return;
  int t = et[e];
  int p = pstart[t] + (e - range[t*2]);
  psrc[p] = src[e];
  pmape[e] = p;
}

// iperm init: padding slots dump to [EDD, EDD+32768) (never read)
__global__ void k_iota(int* __restrict__ iperm){
  int p = blockIdx.x*256 + threadIdx.x;
  if(p < PEDD) iperm[p] = EDD + (p & 32767);
}

// ======================= fast path: CSR build (LDS hist, 2-phase scan) =======================

template<int PB>
__global__ void k_hist(const int* __restrict__ dst, int ne, int sub, int b0,
                       int* __restrict__ gh, int bins){
  __shared__ int h[PB];
  for(int i = threadIdx.x; i < PB; i += 256) h[i] = 0;
  __syncthreads();
  int chunk = (ne + NBLK - 1) / NBLK;
  int s0 = blockIdx.x*chunk, s1 = min(s0 + chunk, ne);
  for(int i = s0 + threadIdx.x; i < s1; i += 256){
    int b = dst[i] - sub - b0;
    if(b >= 0 && b < PB) atomicAdd(&h[b], 1);
  }
  __syncthreads();
  for(int i = threadIdx.x; i < PB; i += 256) gh[(size_t)blockIdx.x*bins + b0 + i] = h[i];
}

// phase 1: psum[g][bin] = sum of gh[b][bin] for b in group g (32 rows)
__global__ void k_scan_p1(const int* __restrict__ gh, int* __restrict__ psum, int bins){
  int bin = blockIdx.x*256 + threadIdx.x;
  int g = blockIdx.y;
  if(bin >= bins) return;
  int s = 0;
  #pragma unroll 8
  for(int b = g*32; b < g*32 + 32; b++) s += gh[(size_t)b*bins + bin];
  psum[(size_t)g*bins + bin] = s;
}

// phase 2: exclusive prefix within column; g==SCANG-1 writes cnt
__global__ void k_scan_p2(int* __restrict__ gh, const int* __restrict__ psum,
                          int* __restrict__ cnt, int bins){
  int bin = blockIdx.x*256 + threadIdx.x;
  int g = blockIdx.y;
  if(bin >= bins) return;
  int run = 0;
  for(int gg = 0; gg < g; gg++) run += psum[(size_t)gg*bins + bin];
  #pragma unroll 8
  for(int b = g*32; b < g*32 + 32; b++){
    int v = gh[(size_t)b*bins + bin];
    gh[(size_t)b*bins + bin] = run;
    run += v;
  }
  if(g == SCANG-1) cnt[bin] = run;
}

__global__ void k_scan_off(const int* __restrict__ cnt, int* __restrict__ off, int bins){
  __shared__ int ps[1024];
  int t = threadIdx.x;
  int C = (bins + 1023) >> 10;
  int lo = t*C, hi = min(lo + C, bins);
  int s = 0;
  for(int i = lo; i < hi; i++) s += cnt[i];
  ps[t] = s;
  __syncthreads();
  for(int d = 1; d < 1024; d <<= 1){
    int v = (t >= d) ? ps[t-d] : 0;
    __syncthreads();
    ps[t] += v;
    __syncthreads();
  }
  int run = ps[t] - s;   // exclusive
  for(int i = lo; i < hi; i++){ off[i] = run; run += cnt[i]; }
  if(t == 1023) off[bins] = ps[1023];
}

// MODE 0: outp[pos] = src[e]   MODE 1: outp[src[e]] = pos (inverse perm)
template<int PB, int MODE>
__global__ void k_scatter(const int* __restrict__ dst, const int* __restrict__ src,
                          int ne, int sub, int b0, const int* __restrict__ gh,
                          const int* __restrict__ off, int bins, int* __restrict__ outp){
  __shared__ int h[PB];
  for(int i = threadIdx.x; i < PB; i += 256)
    h[i] = off[b0 + i] + gh[(size_t)blockIdx.x*bins + b0 + i];
  __syncthreads();
  int chunk = (ne + NBLK - 1) / NBLK;
  int s0 = blockIdx.x*chunk, s1 = min(s0 + chunk, ne);
  for(int i = s0 + threadIdx.x; i < s1; i += 256){
    int b = dst[i] - sub - b0;
    if(b >= 0 && b < PB){
      int p = atomicAdd(&h[b], 1);
      if(MODE == 0) outp[p] = src[i];
      else          outp[src[i]] = p;
    }
  }
}

__global__ void k_dis_off(const int* __restrict__ off, float* __restrict__ dis, int n){
  int i = blockIdx.x*256 + threadIdx.x;
  if(i < n) dis[i] = rsqrtf((float)(off[i+1] - off[i]) + 1.0f);
}

// ======================= fast path: gathers (block per dst, MLP-unrolled) =======================

// h1s = h1*dis (pre-scaled). h2out written pre-scaled by dis[d] for layer 2.
__global__ void k_gcn_gather1(const float* __restrict__ hs, const float* __restrict__ dis,
                              const int* __restrict__ off, const int* __restrict__ srcperm,
                              const float* __restrict__ b1, const float* __restrict__ W2,
                              float* __restrict__ h2s){
  __shared__ float red[4][32];
  __shared__ float m[32];
  __shared__ float W2s[512];
  int d = blockIdx.x, tid = threadIdx.x;
  for(int i = tid; i < 512; i += 256) W2s[i] = W2[i];
  int col = tid & 31, g = tid >> 5;     // 8 groups
  int o0 = off[d], cnt = off[d+1] - o0;
  float s0 = 0.f, s1 = 0.f, s2 = 0.f, s3 = 0.f;
  int i = g;
  for(; i + 24 < cnt; i += 32){
    int j0 = srcperm[o0 + i],      j1 = srcperm[o0 + i + 8];
    int j2 = srcperm[o0 + i + 16], j3 = srcperm[o0 + i + 24];
    s0 += hs[j0*32 + col]; s1 += hs[j1*32 + col];
    s2 += hs[j2*32 + col]; s3 += hs[j3*32 + col];
  }
  for(; i < cnt; i += 8) s0 += hs[srcperm[o0 + i]*32 + col];
  float s = (s0 + s1) + (s2 + s3);
  s += __shfl_xor(s, 32);
  int wv = tid >> 6, lane = tid & 63;
  if(lane < 32) red[wv][lane] = s;
  __syncthreads();
  float dd = dis[d];
  if(tid < 32){
    float v = (red[0][tid]+red[1][tid]+red[2][tid]+red[3][tid] + hs[d*32 + tid])*dd + b1[tid];
    m[tid] = fmaxf(v, 0.f);
  }
  __syncthreads();
  if(tid < 16){
    float acc = 0.f;
    #pragma unroll
    for(int k = 0; k < 32; k++) acc = fmaf(m[k], W2s[k*16 + tid], acc);
    h2s[d*16 + tid] = acc * dd;       // pre-scale for layer 2
  }
}

// agg2 = (sum_src h2s[src] + h2s[d])*dis[d] + b2   (true agg2, unscaled output)
__global__ void k_gcn_gather2(const float* __restrict__ hs, const float* __restrict__ dis,
                              const int* __restrict__ off, const int* __restrict__ srcperm,
                              const float* __restrict__ b, float* __restrict__ agg){
  __shared__ float red[4][16];
  int d = blockIdx.x;
  int tid = threadIdx.x;
  int col = tid & 15;
  int g = tid >> 4;                    // 16 groups
  int o0 = off[d], cnt = off[d+1] - o0;
  float s0 = 0.f, s1 = 0.f;
  int i = g;
  for(; i + 16 < cnt; i += 32){
    int j0 = srcperm[o0 + i], j1 = srcperm[o0 + i + 16];
    s0 += hs[j0*16 + col];
    s1 += hs[j1*16 + col];
  }
  for(; i < cnt; i += 16) s0 += hs[srcperm[o0 + i]*16 + col];
  float s = s0 + s1;
  s += __shfl_xor(s, 32);
  s += __shfl_xor(s, 16);
  int wv = tid >> 6, lane = tid & 63;
  if(lane < 16) red[wv][lane] = s;
  __syncthreads();
  if(tid < 16){
    float tot = red[0][tid] + red[1][tid] + red[2][tid] + red[3][tid];
    float dd = dis[d];
    agg[d*16 + tid] = (tot + hs[d*16 + tid])*dd + b[tid];
  }
}

__global__ void k_dp_gather(const float* __restrict__ xp2, const int* __restrict__ off,
                            const int* __restrict__ srcperm, const float* __restrict__ hg,
                            float* __restrict__ xd, unsigned short* __restrict__ xdb){
  __shared__ float red[4][16];
  __shared__ float m[16];
  int d = blockIdx.x;
  int tid = threadIdx.x;
  int col = tid & 15, g = tid >> 4;
  int o0 = off[d], cnt = off[d+1] - o0;
  float s0 = 0.f, s1 = 0.f, s2 = 0.f, s3 = 0.f;
  int i = g;
  for(; i + 48 < cnt; i += 64){
    int j0 = srcperm[o0 + i],      j1 = srcperm[o0 + i + 16];
    int j2 = srcperm[o0 + i + 32], j3 = srcperm[o0 + i + 48];
    s0 += xp2[j0*16 + col]; s1 += xp2[j1*16 + col];
    s2 += xp2[j2*16 + col]; s3 += xp2[j3*16 + col];
  }
  for(; i < cnt; i += 16) s0 += xp2[srcperm[o0 + i]*16 + col];
  float s = (s0 + s1) + (s2 + s3);
  s += __shfl_xor(s, 32);
  s += __shfl_xor(s, 16);
  int wv = tid >> 6, lane = tid & 63;
  if(lane < 16) red[wv][lane] = s;
  __syncthreads();
  if(tid < 16) m[tid] = (red[0][tid]+red[1][tid]+red[2][tid]+red[3][tid]) / fmaxf((float)cnt, 1.f);
  __syncthreads();
  if(tid < 16){
    float acc = 0.f;
    #pragma unroll
    for(int k = 0; k < 16; k++) acc = fmaf(m[k], hg[k*16 + tid], acc);
    xd[d*64 + 48 + tid] = acc;
    xdb[d*64 + 48 + tid] = (unsigned short)f2bf(acc);
  }
}

// ======================= fast path: embed GEMM via MFMA =======================

__global__ __launch_bounds__(256) void k_embed_m(
    const float* __restrict__ xdrug, const unsigned short* __restrict__ embb,
    float* __restrict__ xdp){
  int tid = threadIdx.x;
  int wv = tid >> 6, l = tid & 63;
  int rt = blockIdx.x*4 + wv;            // row tile (16 rows)
  int row = rt*16 + (l & 15);
  int kg = (l >> 4) << 3;
  int cb = blockIdx.y * EKCH;
  bool valid = row < NDRUG;
  const float* xr = xdrug + (size_t)row * INDRUG;
  f32x4 z = {0.f,0.f,0.f,0.f};
  f32x4 c0 = z, c1 = z, c2 = z;
  #pragma unroll
  for(int ks = 0; ks < EKCH/32; ks++){
    int k0 = cb + ks*32;
    float4 u = make_float4(0,0,0,0), v = make_float4(0,0,0,0);
    if(valid){
      u = *(const float4*)(xr + k0 + kg);
      v = *(const float4*)(xr + k0 + kg + 4);
    }
    bf16x8 a;
    a[0] = (__bf16)u.x; a[1] = (__bf16)u.y; a[2] = (__bf16)u.z; a[3] = (__bf16)u.w;
    a[4] = (__bf16)v.x; a[5] = (__bf16)v.y; a[6] = (__bf16)v.z; a[7] = (__bf16)v.w;
    const unsigned short* bb = embb + (size_t)(k0 >> 5)*1536 + l*8;
    bf16x8 b0 = *(const bf16x8*)(bb);
    bf16x8 b1 = *(const bf16x8*)(bb + 512);
    bf16x8 b2 = *(const bf16x8*)(bb + 1024);
    c0 = __builtin_amdgcn_mfma_f32_16x16x32_bf16(a, b0, c0, 0,0,0);
    c1 = __builtin_amdgcn_mfma_f32_16x16x32_bf16(a, b1, c1, 0,0,0);
    c2 = __builtin_amdgcn_mfma_f32_16x16x32_bf16(a, b2, c2, 0,0,0);
  }
  int col = l & 15, rb = (l >> 4) << 2;
  float* op = xdp + (size_t)blockIdx.y * NDRUG * 48;
  #pragma unroll
  for(int r = 0; r < 4; r++){
    int ro = rt*16 + rb + r;
    if(ro < NDRUG){
      op[ro*48 + col]       = c0[r];
      op[ro*48 + 16 + col]  = c1[r];
      op[ro*48 + 32 + col]  = c2[r];
    }
  }
}

__global__ void k_embed_fin2(const float* __restrict__ xdp, const float* __restrict__ dnorm,
                             float* __restrict__ xd, unsigned short* __restrict__ xdb){
  int gid = blockIdx.x*256 + threadIdx.x;
  if(gid >= NDRUG*48) return;
  int d = gid / 48, j = gid % 48;
  float s = 0.f;
  for(int y = 0; y < KSPLIT; y++) s += xdp[(size_t)y*NDRUG*48 + gid];
  float v = s / dnorm[d];
  xd[d*64 + j] = v;
  xdb[d*64 + j] = (unsigned short)f2bf(v);
}

// ======================= RGCN msgs via MFMA (padded, branch-free, CSR-ordered output) =======================

__global__ __launch_bounds__(256) void k_rgcn1_msgsM(
    const unsigned short* __restrict__ xdb, const int* __restrict__ psrc,
    const int* __restrict__ pblk, const unsigned short* __restrict__ wetb,
    const int* __restrict__ iperm, unsigned short* __restrict__ msgs){
  int tid = threadIdx.x;
  int wv = tid >> 6, l = tid & 63;
  int t0 = pblk[blockIdx.x];
  const unsigned short* wb = wetb + (size_t)t0*2048 + l*8;
  bf16x8 w00 = *(const bf16x8*)(wb);
  bf16x8 w01 = *(const bf16x8*)(wb + 512);
  bf16x8 w10 = *(const bf16x8*)(wb + 1024);
  bf16x8 w11 = *(const bf16x8*)(wb + 1536);
  int eb = blockIdx.x*256 + wv*64;
  int col = l & 15;
  int g4 = (l >> 4) << 3;
  int rb = (l >> 4) << 2;
  int e0 = eb + col, e1 = eb + 16 + col, e2 = eb + 32 + col, e3 = eb + 48 + col;
  int s0 = psrc[e0], s1 = psrc[e1], s2 = psrc[e2], s3 = psrc[e3];
  int p0 = iperm[e0], p1 = iperm[e1], p2 = iperm[e2], p3 = iperm[e3];
  const unsigned short* x0 = xdb + (size_t)s0*64 + g4;
  const unsigned short* x1 = xdb + (size_t)s1*64 + g4;
  const unsigned short* x2 = xdb + (size_t)s2*64 + g4;
  const unsigned short* x3 = xdb + (size_t)s3*64 + g4;
  bf16x8 a00 = *(const bf16x8*)(x0), a01 = *(const bf16x8*)(x0 + 32);
  bf16x8 a10 = *(const bf16x8*)(x1), a11 = *(const bf16x8*)(x1 + 32);
  bf16x8 a20 = *(const bf16x8*)(x2), a21 = *(const bf16x8*)(x2 + 32);
  bf16x8 a30 = *(const bf16x8*)(x3), a31 = *(const bf16x8*)(x3 + 32);
  f32x4 z = {0.f,0.f,0.f,0.f};
  f32x4 c00=z,c01=z,c10=z,c11=z,c20=z,c21=z,c30=z,c31=z;
  c00 = __builtin_amdgcn_mfma_f32_16x16x32_bf16(w00, a00, c00, 0,0,0);
  c00 = __builtin_amdgcn_mfma_f32_16x16x32_bf16(w10, a01, c00, 0,0,0);
  c01 = __builtin_amdgcn_mfma_f32_16x16x32_bf16(w01, a00, c01, 0,0,0);
  c01 = __builtin_amdgcn_mfma_f32_16x16x32_bf16(w11, a01, c01, 0,0,0);
  c10 = __builtin_amdgcn_mfma_f32_16x16x32_bf16(w00, a10, c10, 0,0,0);
  c10 = __builtin_amdgcn_mfma_f32_16x16x32_bf16(w10, a11, c10, 0,0,0);
  c11 = __builtin_amdgcn_mfma_f32_16x16x32_bf16(w01, a10, c11, 0,0,0);
  c11 = __builtin_amdgcn_mfma_f32_16x16x32_bf16(w11, a11, c11, 0,0,0);
  c20 = __builtin_amdgcn_mfma_f32_16x16x32_bf16(w00, a20, c20, 0,0,0);
  c20 = __builtin_amdgcn_mfma_f32_16x16x32_bf16(w10, a21, c20, 0,0,0);
  c21 = __builtin_amdgcn_mfma_f32_16x16x32_bf16(w01, a20, c21, 0,0,0);
  c21 = __builtin_amdgcn_mfma_f32_16x16x32_bf16(w11, a21, c21, 0,0,0);
  c30 = __builtin_amdgcn_mfma_f32_16x16x32_bf16(w00, a30, c30, 0,0,0);
  c30 = __builtin_amdgcn_mfma_f32_16x16x32_bf16(w10, a31, c30, 0,0,0);
  c31 = __builtin_amdgcn_mfma_f32_16x16x32_bf16(w01, a30, c31, 0,0,0);
  c31 = __builtin_amdgcn_mfma_f32_16x16x32_bf16(w11, a31, c31, 0,0,0);
  *(unsigned long long*)(msgs + (size_t)p0*32 + rb)      = pack4(c00);
  *(unsigned long long*)(msgs + (size_t)p0*32 + 16 + rb) = pack4(c01);
  *(unsigned long long*)(msgs + (size_t)p1*32 + rb)      = pack4(c10);
  *(unsigned long long*)(msgs + (size_t)p1*32 + 16 + rb) = pack4(c11);
  *(unsigned long long*)(msgs + (size_t)p2*32 + rb)      = pack4(c20);
  *(unsigned long long*)(msgs + (size_t)p2*32 + 16 + rb) = pack4(c21);
  *(unsigned long long*)(msgs + (size_t)p3*32 + rb)      = pack4(c30);
  *(unsigned long long*)(msgs + (size_t)p3*32 + 16 + rb) = pack4(c31);
}

__global__ __launch_bounds__(256) void k_rgcn2_msgsM(
    const unsigned short* __restrict__ xd1b, const int* __restrict__ psrc,
    const int* __restrict__ pblk, const unsigned short* __restrict__ wetb,
    const int* __restrict__ iperm, unsigned short* __restrict__ msgs){
  int tid = threadIdx.x;
  int wv = tid >> 6, l = tid & 63;
  int t0 = pblk[blockIdx.x];
  bf16x8 w0 = *(const bf16x8*)(wetb + (size_t)t0*512 + l*8);
  int eb = blockIdx.x*256 + wv*64;
  int col = l & 15;
  int g4 = (l >> 4) << 3;
  int rb = (l >> 4) << 2;
  int e0 = eb + col, e1 = eb + 16 + col, e2 = eb + 32 + col, e3 = eb + 48 + col;
  int s0 = psrc[e0], s1 = psrc[e1], s2 = psrc[e2], s3 = psrc[e3];
  int p0 = iperm[e0], p1 = iperm[e1], p2 = iperm[e2], p3 = iperm[e3];
  bf16x8 a0 = *(const bf16x8*)(xd1b + (size_t)s0*32 + g4);
  bf16x8 a1 = *(const bf16x8*)(xd1b + (size_t)s1*32 + g4);
  bf16x8 a2 = *(const bf16x8*)(xd1b + (size_t)s2*32 + g4);
  bf16x8 a3 = *(const bf16x8*)(xd1b + (size_t)s3*32 + g4);
  f32x4 z = {0.f,0.f,0.f,0.f};
  f32x4 c0=z,c1=z,c2=z,c3=z;
  c0 = __builtin_amdgcn_mfma_f32_16x16x32_bf16(w0, a0, c0, 0,0,0);
  c1 = __builtin_amdgcn_mfma_f32_16x16x32_bf16(w0, a1, c1, 0,0,0);
  c2 = __builtin_amdgcn_mfma_f32_16x16x32_bf16(w0, a2, c2, 0,0,0);
  c3 = __builtin_amdgcn_mfma_f32_16x16x32_bf16(w0, a3, c3, 0,0,0);
  *(unsigned long long*)(msgs + (size_t)p0*16 + rb) = pack4(c0);
  *(unsigned long long*)(msgs + (size_t)p1*16 + rb) = pack4(c1);
  *(unsigned long long*)(msgs + (size_t)p2*16 + rb) = pack4(c2);
  *(unsigned long long*)(msgs + (size_t)p3*16 + rb) = pack4(c3);
}

// block per dst: 16 row-streams, SEQUENTIAL msgs rows (CSR-ordered), 4-way unroll
__global__ void k_rgcn1_reduce(const unsigned short* __restrict__ msgs, const int* __restrict__ off,
                               const float* __restrict__ xd, const float* __restrict__ root,
                               float* __restrict__ xd1, unsigned short* __restrict__ xd1b){
  __shared__ float red[16][32];
  int d = blockIdx.x;
  int tid = threadIdx.x;
  int cp = tid & 15, r = tid >> 4;
  int o0 = off[d], cnt = off[d+1] - o0;
  float s0 = 0.f, s1 = 0.f;
  int i = r;
  for(; i + 48 < cnt; i += 64){
    unsigned int v0 = *(const unsigned int*)(msgs + (size_t)(o0+i)*32 + cp*2);
    unsigned int v1 = *(const unsigned int*)(msgs + (size_t)(o0+i+16)*32 + cp*2);
    unsigned int v2 = *(const unsigned int*)(msgs + (size_t)(o0+i+32)*32 + cp*2);
    unsigned int v3 = *(const unsigned int*)(msgs + (size_t)(o0+i+48)*32 + cp*2);
    s0 += bf2f(v0 & 0xffffu) + bf2f(v1 & 0xffffu) + bf2f(v2 & 0xffffu) + bf2f(v3 & 0xffffu);
    s1 += bf2f(v0 >> 16)     + bf2f(v1 >> 16)     + bf2f(v2 >> 16)     + bf2f(v3 >> 16);
  }
  for(; i < cnt; i += 16){
    unsigned int v = *(const unsigned int*)(msgs + (size_t)(o0+i)*32 + cp*2);
    s0 += bf2f(v & 0xffffu); s1 += bf2f(v >> 16);
  }
  red[r][cp*2] = s0; red[r][cp*2+1] = s1;
  __syncthreads();
  if(tid < 32){
    float tot = 0.f;
    #pragma unroll
    for(int r2 = 0; r2 < 16; r2++) tot += red[r2][tid];
    float rr = 0.f;
    const float* x = xd + d*64;
    #pragma unroll 8
    for(int i2 = 0; i2 < 64; i2++) rr = fmaf(x[i2], root[i2*32 + tid], rr);
    float v = fmaxf(tot / fmaxf((float)cnt, 1.0f) + rr, 0.f);
    xd1[d*32 + tid] = v;
    xd1b[d*32 + tid] = (unsigned short)f2bf(v);
  }
}

__global__ void k_rgcn2_reduce(const unsigned short* __restrict__ msgs, const int* __restrict__ off,
                               const float* __restrict__ xd1, const float* __restrict__ root,
                               float* __restrict__ out){
  __shared__ float red[32][16];
  int d = blockIdx.x;
  int tid = threadIdx.x;
  int cp = tid & 7, r = tid >> 3;
  int o0 = off[d], cnt = off[d+1] - o0;
  float s0 = 0.f, s1 = 0.f;
  int i = r;
  for(; i + 96 < cnt; i += 128){
    unsigned int v0 = *(const unsigned int*)(msgs + (size_t)(o0+i)*16 + cp*2);
    unsigned int v1 = *(const unsigned int*)(msgs + (size_t)(o0+i+32)*16 + cp*2);
    unsigned int v2 = *(const unsigned int*)(msgs + (size_t)(o0+i+64)*16 + cp*2);
    unsigned int v3 = *(const unsigned int*)(msgs + (size_t)(o0+i+96)*16 + cp*2);
    s0 += bf2f(v0 & 0xffffu) + bf2f(v1 & 0xffffu) + bf2f(v2 & 0xffffu) + bf2f(v3 & 0xffffu);
    s1 += bf2f(v0 >> 16)     + bf2f(v1 >> 16)     + bf2f(v2 >> 16)     + bf2f(v3 >> 16);
  }
  for(; i < cnt; i += 32){
    unsigned int v = *(const unsigned int*)(msgs + (size_t)(o0+i)*16 + cp*2);
    s0 += bf2f(v & 0xffffu); s1 += bf2f(v >> 16);
  }
  red[r][cp*2] = s0; red[r][cp*2+1] = s1;
  __syncthreads();
  if(tid < 16){
    float tot = 0.f;
    #pragma unroll
    for(int r2 = 0; r2 < 32; r2++) tot += red[r2][tid];
    float rr = 0.f;
    const float* x = xd1 + d*32;
    #pragma unroll 8
    for(int i2 = 0; i2 < 32; i2++) rr = fmaf(x[i2], root[i2*16 + tid], rr);
    out[d*16 + tid] = tot / fmaxf((float)cnt, 1.0f) + rr;
  }
}

// ======================= fallback (round-1) kernels =======================

#define O_CNTPP   0
#define O_DIS     20000
#define O_H1      40000
#define O_AGG1    680000
#define O_H2      1320000
#define O_AGG2    1640000
#define O_DPSUM   1960000
#define O_DPCNT   2024000
#define O_XD      2028000
#define O_WET1    2284000
#define O_WET2    2546144
#define O_CNTDD   2611680
#define O_RSUM1   2615680
#define O_XD1     2743680
#define O_RSUM2   2871680

__global__ void k_count_int(const int* __restrict__ dst, int ne, int* __restrict__ cnt){
  int i = blockIdx.x*256 + threadIdx.x;
  if(i < ne) atomicAdd(&cnt[dst[i]], 1);
}

__global__ void k_dis(const int* __restrict__ cnt, float* __restrict__ dis, int n){
  int i = blockIdx.x*256 + threadIdx.x;
  if(i < n) dis[i] = rsqrtf((float)cnt[i] + 1.0f);
}

template<int NC>
__global__ void k_gcn_init(const float* __restrict__ h, const float* __restrict__ dis,
                           const float* __restrict__ b, float* __restrict__ agg, int n){
  int i = blockIdx.x*256 + threadIdx.x;
  if(i < n*NC){
    int r = i / NC, c = i % NC;
    float d = dis[r];
    agg[i] = fmaf(h[i], d*d, b[c]);
  }
}

template<int NC>
__global__ void k_gcn_scatter(const float* __restrict__ h, const float* __restrict__ dis,
                              const int* __restrict__ src, const int* __restrict__ dst,
                              int ne, float* __restrict__ agg){
  int gid = blockIdx.x*256 + threadIdx.x;
  int e = gid / NC, j = gid % NC;
  if(e >= ne) return;
  int s = src[e], d = dst[e];
  atomicAdd(&agg[d*NC + j], h[s*NC + j] * dis[s] * dis[d]);
}

__global__ void k_dp_scatter(const float* __restrict__ xp2, const int* __restrict__ src,
                             const int* __restrict__ dst, float* __restrict__ dpsum,
                             int* __restrict__ dpcnt){
  int gid = blockIdx.x*256 + threadIdx.x;
  int e = gid >> 4, j = gid & 15;
  if(e >= EDP) return;
  int s = src[e], d = dst[e] - NPROT;
  atomicAdd(&dpsum[d*16 + j], xp2[s*16 + j]);
  if(j == 0) atomicAdd(&dpcnt[d], 1);
}

__global__ void k_hier(const float* __restrict__ dpsum, const int* __restrict__ dpcnt,
                       const float* __restrict__ hg, float* __restrict__ xd){
  int gid = blockIdx.x*256 + threadIdx.x;
  int d = gid >> 4, j = gid & 15;
  if(d >= NDRUG) return;
  float inv = 1.0f / fmaxf((float)dpcnt[d], 1.0f);
  float acc = 0.f;
  #pragma unroll
  for(int k = 0; k < 16; k++) acc = fmaf(dpsum[d*16 + k] * inv, hg[k*16 + j], acc);
  xd[d*64 + 48 + j] = acc;
}

__global__ void k_embed(const float* __restrict__ xdrug, const float* __restrict__ embed,
                        float* __restrict__ xd){
  __shared__ float xs[64][65];
  __shared__ float es[64][48];
  int tid = threadIdx.x;
  int r = tid & 63;
  int cg = tid >> 6;
  int row0 = blockIdx.x * 64;
  int k0c = blockIdx.y * 512;
  float acc[12];
  #pragma unroll
  for(int j = 0; j < 12; j++) acc[j] = 0.f;
  for(int kt = 0; kt < 512; kt += 64){
    int k0 = k0c + kt;
    if(k0 >= INDRUG) break;
    __syncthreads();
    #pragma unroll
    for(int i = 0; i < 4; i++){
      int lin = tid + i*256;
      int rr = lin >> 4, kc = lin & 15;
      int grow = row0 + rr, gk = k0 + kc*4;
      float4 v = make_float4(0.f,0.f,0.f,0.f);
      if(grow < NDRUG && gk + 3 < INDRUG)
        v = *(const float4*)&xdrug[(size_t)grow * INDRUG + gk];
      xs[rr][kc*4+0]=v.x; xs[rr][kc*4+1]=v.y; xs[rr][kc*4+2]=v.z; xs[rr][kc*4+3]=v.w;
    }
    #pragma unroll
    for(int i = 0; i < 3; i++){
      int lin = tid + i*256;
      int kk = lin / 12, jc = lin % 12;
      float4 v = make_float4(0.f,0.f,0.f,0.f);
      if(k0 + kk < INDRUG)
        v = *(const float4*)&embed[(size_t)(k0 + kk) * NEMBED + jc*4];
      *(float4*)&es[kk][jc*4] = v;
    }
    __syncthreads();
    #pragma unroll 8
    for(int kk = 0; kk < 64; kk++){
      float xv = xs[r][kk];
      const float4* ep = (const float4*)&es[kk][cg*12];
      float4 e0 = ep[0], e1 = ep[1], e2 = ep[2];
      acc[0]=fmaf(xv,e0.x,acc[0]);  acc[1]=fmaf(xv,e0.y,acc[1]);
      acc[2]=fmaf(xv,e0.z,acc[2]);  acc[3]=fmaf(xv,e0.w,acc[3]);
      acc[4]=fmaf(xv,e1.x,acc[4]);  acc[5]=fmaf(xv,e1.y,acc[5]);
      acc[6]=fmaf(xv,e1.z,acc[6]);  acc[7]=fmaf(xv,e1.w,acc[7]);
      acc[8]=fmaf(xv,e2.x,acc[8]);  acc[9]=fmaf(xv,e2.y,acc[9]);
      acc[10]=fmaf(xv,e2.z,acc[10]); acc[11]=fmaf(xv,e2.w,acc[11]);
    }
  }
  int grow = row0 + r;
  if(grow < NDRUG){
    #pragma unroll
    for(int j = 0; j < 12; j++)
      atomicAdd(&xd[grow*64 + cg*12 + j], acc[j]);
  }
}

__global__ void k_embed_fin(float* __restrict__ xd, const float* __restrict__ dnorm){
  int gid = blockIdx.x*256 + threadIdx.x;
  if(gid >= NDRUG*48) return;
  int d = gid / 48, j = gid % 48;
  xd[d*64 + j] = xd[d*64 + j] / dnorm[d];
}

__global__ void k_rgcn1(const float* __restrict__ xd, const int* __restrict__ src,
                        const int* __restrict__ dst, const int* __restrict__ et,
                        const float* __restrict__ wet, float* __restrict__ rsum){
  int tid = threadIdx.x;
  int e = blockIdx.x*64 + (tid >> 2);
  if(e >= EDD) return;
  int jg = tid & 3;
  int s = src[e], d = dst[e], t = et[e];
  const float* x = xd + s*64;
  const float* w = wet + t*2048 + jg*8;
  float acc[8] = {0,0,0,0,0,0,0,0};
  #pragma unroll 8
  for(int i = 0; i < 64; i++){
    float xv = x[i];
    const float4* wp = (const float4*)(w + i*32);
    float4 w0 = wp[0], w1 = wp[1];
    acc[0]=fmaf(xv,w0.x,acc[0]); acc[1]=fmaf(xv,w0.y,acc[1]);
    acc[2]=fmaf(xv,w0.z,acc[2]); acc[3]=fmaf(xv,w0.w,acc[3]);
    acc[4]=fmaf(xv,w1.x,acc[4]); acc[5]=fmaf(xv,w1.y,acc[5]);
    acc[6]=fmaf(xv,w1.z,acc[6]); acc[7]=fmaf(xv,w1.w,acc[7]);
  }
  float* outp = rsum + d*32 + jg*8;
  #pragma unroll
  for(int j = 0; j < 8; j++) atomicAdd(&outp[j], acc[j]);
}

__global__ void k_rgcn2(const float* __restrict__ xd1, const int* __restrict__ src,
                        const int* __restrict__ dst, const int* __restrict__ et,
                        const float* __restrict__ wet, float* __restrict__ rsum){
  int tid = threadIdx.x;
  int e = blockIdx.x*128 + (tid >> 1);
  if(e >= EDD) return;
  int jg = tid & 1;
  int s = src[e], d = dst[e], t = et[e];
  const float* x = xd1 + s*32;
  const float* w = wet + t*512 + jg*8;
  float acc[8] = {0,0,0,0,0,0,0,0};
  #pragma unroll 8
  for(int i = 0; i < 32; i++){
    float xv = x[i];
    const float4* wp = (const float4*)(w + i*16);
    float4 w0 = wp[0], w1 = wp[1];
    acc[0]=fmaf(xv,w0.x,acc[0]); acc[1]=fmaf(xv,w0.y,acc[1]);
    acc[2]=fmaf(xv,w0.z,acc[2]); acc[3]=fmaf(xv,w0.w,acc[3]);
    acc[4]=fmaf(xv,w1.x,acc[4]); acc[5]=fmaf(xv,w1.y,acc[5]);
    acc[6]=fmaf(xv,w1.z,acc[6]); acc[7]=fmaf(xv,w1.w,acc[7]);
  }
  float* outp = rsum + d*16 + jg*8;
  #pragma unroll
  for(int j = 0; j < 8; j++) atomicAdd(&outp[j], acc[j]);
}

__global__ void k_root1(const float* __restrict__ rsum, const int* __restrict__ cnt,
                        const float* __restrict__ xd, const float* __restrict__ root,
                        float* __restrict__ xd1){
  int gid = blockIdx.x*256 + threadIdx.x;
  int d = gid >> 5, j = gid & 31;
  if(d >= NDRUG) return;
  float inv = 1.0f / fmaxf((float)cnt[d], 1.0f);
  float acc = rsum[d*32 + j] * inv;
  #pragma unroll
  for(int i = 0; i < 64; i++) acc = fmaf(xd[d*64 + i], root[i*32 + j], acc);
  xd1[d*32 + j] = fmaxf(acc, 0.f);
}

__global__ void k_root2(const float* __restrict__ rsum, const int* __restrict__ cnt,
                        const float* __restrict__ xd1, const float* __restrict__ root,
                        float* __restrict__ out){
  int gid = blockIdx.x*256 + threadIdx.x;
  int d = gid >> 4, j = gid & 15;
  if(d >= NDRUG) return;
  float inv = 1.0f / fmaxf((float)cnt[d], 1.0f);
  float acc = rsum[d*16 + j] * inv;
  #pragma unroll
  for(int i = 0; i < 32; i++) acc = fmaf(xd1[d*32 + i], root[i*16 + j], acc);
  out[d*16 + j] = acc;
}

// ======================= launch =======================

extern "C" void kernel_launch(void* const* d_in, const int* in_sizes, int n_in,
                              void* d_out, int out_size, void* d_ws, size_t ws_size,
                              hipStream_t stream){
  const float* x_drug  = (const float*)d_in[0];
  const float* d_norm  = (const float*)d_in[1];
  const float* x_prot  = (const float*)d_in[2];
  const int*   pp_ei   = (const int*)d_in[3];
  const int*   dp_ei   = (const int*)d_in[4];
  const int*   dd_ei   = (const int*)d_in[6];
  const int*   dd_et   = (const int*)d_in[7];
  const int*   dd_rl   = (const int*)d_in[8];
  const float* embed   = (const float*)d_in[9];
  const float* W1      = (const float*)d_in[10];
  const float* b1      = (const float*)d_in[11];
  const float* W2      = (const float*)d_in[12];
  const float* b2      = (const float*)d_in[13];
  const float* hgw     = (const float*)d_in[14];
  const float* att1    = (const float*)d_in[15];
  const float* basis1  = (const float*)d_in[16];
  const float* root1   = (const float*)d_in[17];
  const float* att2    = (const float*)d_in[18];
  const float* basis2  = (const float*)d_in[19];
  const float* root2   = (const float*)d_in[20];
  float* out = (float*)d_out;
  float* ws = (float*)d_ws;

  const int* pp_src = pp_ei;
  const int* pp_dst = pp_ei + EPP;
  const int* dp_src = dp_ei;
  const int* dp_dst = dp_ei + EDP;
  const int* dd_src = dd_ei;
  const int* dd_dst = dd_ei + EDD;

  // ---- fast-path ws layout ----
  auto pad = [](size_t n){ return (n + 15) & ~(size_t)15; };
  size_t o = 0;
  size_t oPPOFF = o; o += pad(NPROT + 1);
  size_t oDPOFF = o; o += pad(NDRUG + 1);
  size_t oDDOFF = o; o += pad(NDRUG + 1);
  size_t oDIS   = o; o += pad(NPROT);
  size_t oH1    = o; o += pad((size_t)NPROT*32);
  size_t oH2    = o; o += pad((size_t)NPROT*16);
  size_t oAGG2  = o; o += pad((size_t)NPROT*16);
  size_t oXD    = o; o += pad((size_t)NDRUG*64);
  size_t oXD1   = o; o += pad((size_t)NDRUG*32);
  size_t oXDB   = o; o += pad((size_t)NDRUG*32);
  size_t oXD1B  = o; o += pad((size_t)NDRUG*16);
  size_t oWETB1 = o; o += pad((size_t)NET*1024);
  size_t oWETB2 = o; o += pad((size_t)NET*256);
  size_t oEMBB  = o; o += pad((size_t)125*768);   // 125*1536 ushort
  size_t oSRCPP = o; o += pad(EPP);
  size_t oSRCDP = o; o += pad(EDP);
  size_t oIPERM = o; o += pad(PEDD);
  size_t oPSTART= o; o += pad(NET + 1);
  size_t oPBLK  = o; o += pad(PBLKS);
  size_t oPSRC  = o; o += pad(PEDD);
  size_t oPMAPE = o; o += pad(EDD);
  size_t oCNT   = o; o += pad(NPROT);
  size_t oPSUM  = o; o += pad((size_t)SCANG*NPROT);
  size_t oGH    = o; o += pad((size_t)NBLK*NPROT);
  // msgs region, aliased with xdp (disjoint lifetimes):
  size_t msgsN  = (size_t)PEDD*16;
  size_t xdpN   = (size_t)KSPLIT*NDRUG*48;
  size_t bigN   = msgsN > xdpN ? msgsN : xdpN;
  size_t oMSGS  = o; o += pad(bigN);
  size_t need_bytes = o * 4;

  if(ws_size >= need_bytes){
    // =================== FAST PATH ===================
    int* ppoff = (int*)(ws + oPPOFF);
    int* dpoff = (int*)(ws + oDPOFF);
    int* ddoff = (int*)(ws + oDDOFF);
    float* dis = ws + oDIS;
    float* h1  = ws + oH1;
    float* h2  = ws + oH2;
    float* agg2= ws + oAGG2;
    float* xd  = ws + oXD;
    float* xd1 = ws + oXD1;
    unsigned short* xdb  = (unsigned short*)(ws + oXDB);
    unsigned short* xd1b = (unsigned short*)(ws + oXD1B);
    unsigned short* wetb1 = (unsigned short*)(ws + oWETB1);
    unsigned short* wetb2 = (unsigned short*)(ws + oWETB2);
    unsigned short* embb  = (unsigned short*)(ws + oEMBB);
    int* srcpp = (int*)(ws + oSRCPP);
    int* srcdp = (int*)(ws + oSRCDP);
    int* iperm = (int*)(ws + oIPERM);
    int* pstart= (int*)(ws + oPSTART);
    int* pblk  = (int*)(ws + oPBLK);
    int* psrc  = (int*)(ws + oPSRC);
    int* pmape = (int*)(ws + oPMAPE);
    int* cnt   = (int*)(ws + oCNT);
    int* psum  = (int*)(ws + oPSUM);
    int* gh    = (int*)(ws + oGH);
    float* xdp = ws + oMSGS;                              // alias (dead before msgs)
    unsigned short* msgs = (unsigned short*)(ws + oMSGS);

    // ---- padded edge layout prep ----
    hipMemsetAsync(pblk, 0, PBLKS*sizeof(int), stream);
    hipMemsetAsync(psrc, 0, PEDD*sizeof(int), stream);
    k_pstart<<<1,NET,0,stream>>>(dd_rl, pstart, pblk);
    k_pmap<<<(EDD+255)/256,256,0,stream>>>(dd_et, dd_src, dd_rl, pstart, psrc, pmape);
    k_iota<<<(PEDD+255)/256,256,0,stream>>>(iperm);

    // ---- PP CSR (LDS hist, 2 passes of 10000 bins, 2-phase scan) ----
    k_hist<10000><<<NBLK,256,0,stream>>>(pp_dst, EPP, 0, 0,     gh, NPROT);
    k_hist<10000><<<NBLK,256,0,stream>>>(pp_dst, EPP, 0, 10000, gh, NPROT);
    {
      dim3 gs((NPROT+255)/256, SCANG);
      k_scan_p1<<<gs,256,0,stream>>>(gh, psum, NPROT);
      k_scan_p2<<<gs,256,0,stream>>>(gh, psum, cnt, NPROT);
    }
    k_scan_off<<<1,1024,0,stream>>>(cnt, ppoff, NPROT);
    k_scatter<10000,0><<<NBLK,256,0,stream>>>(pp_dst, pp_src, EPP, 0, 0,     gh, ppoff, NPROT, srcpp);
    k_scatter<10000,0><<<NBLK,256,0,stream>>>(pp_dst, pp_src, EPP, 0, 10000, gh, ppoff, NPROT, srcpp);
    k_dis_off<<<(NPROT+255)/256,256,0,stream>>>(ppoff, dis, NPROT);

    // ---- PP GCN (pre-scaled features) ----
    k_gemm_s<<<(NPROT*32+255)/256,256,0,stream>>>(x_prot, W1, dis, h1, NPROT);
    k_gcn_gather1<<<NPROT,256,0,stream>>>(h1, dis, ppoff, srcpp, b1, W2, h2);
    k_gcn_gather2<<<NPROT,256,0,stream>>>(h2, dis, ppoff, srcpp, b2, agg2);

    // ---- DP CSR + hierarchy ----
    k_hist<4000><<<NBLK,256,0,stream>>>(dp_dst, EDP, NPROT, 0, gh, NDRUG);
    {
      dim3 gs((NDRUG+255)/256, SCANG);
      k_scan_p1<<<gs,256,0,stream>>>(gh, psum, NDRUG);
      k_scan_p2<<<gs,256,0,stream>>>(gh, psum, cnt, NDRUG);
    }
    k_scan_off<<<1,1024,0,stream>>>(cnt, dpoff, NDRUG);
    k_scatter<4000,0><<<NBLK,256,0,stream>>>(dp_dst, dp_src, EDP, NPROT, 0, gh, dpoff, NDRUG, srcdp);
    k_dp_gather<<<NDRUG,256,0,stream>>>(agg2, dpoff, srcdp, hgw, xd, xdb);

    // ---- drug embedding via MFMA (xdp aliased; consumed by fin2) ----
    k_embb<<<(125*1536+255)/256,256,0,stream>>>(embed, embb);
    {
      dim3 g(63, KSPLIT);
      k_embed_m<<<g,256,0,stream>>>(x_drug, embb, xdp);
    }
    k_embed_fin2<<<(NDRUG*48+255)/256,256,0,stream>>>(xdp, d_norm, xd, xdb);

    // ---- RGCN prep (wetb built directly from att/basis) ----
    k_wetb1<<<(NET*2048+255)/256,256,0,stream>>>(att1, basis1, wetb1);
    k_wetb2<<<(NET*512+255)/256,256,0,stream>>>(att2, basis2, wetb2);
    k_hist<4000><<<NBLK,256,0,stream>>>(dd_dst, EDD, 0, 0, gh, NDRUG);
    {
      dim3 gs((NDRUG+255)/256, SCANG);
      k_scan_p1<<<gs,256,0,stream>>>(gh, psum, NDRUG);
      k_scan_p2<<<gs,256,0,stream>>>(gh, psum, cnt, NDRUG);
    }
    k_scan_off<<<1,1024,0,stream>>>(cnt, ddoff, NDRUG);
    // iperm[padded id] = CSR position (MODE 1)
    k_scatter<4000,1><<<NBLK,256,0,stream>>>(dd_dst, pmape, EDD, 0, 0, gh, ddoff, NDRUG, iperm);

    // ---- RGCN layer 1 (MFMA, CSR-ordered msgs, streaming reduce) ----
    k_rgcn1_msgsM<<<PBLKS,256,0,stream>>>(xdb, psrc, pblk, wetb1, iperm, msgs);
    k_rgcn1_reduce<<<NDRUG,256,0,stream>>>(msgs, ddoff, xd, root1, xd1, xd1b);
    // ---- RGCN layer 2 ----
    k_rgcn2_msgsM<<<PBLKS,256,0,stream>>>(xd1b, psrc, pblk, wetb2, iperm, msgs);
    k_rgcn2_reduce<<<NDRUG,256,0,stream>>>(msgs, ddoff, xd1, root2, out);
  } else {
    // =================== FALLBACK (round-1, atomic) ===================
    int*   cnt_pp = (int*)(ws + O_CNTPP);
    float* dis    = ws + O_DIS;
    float* h1     = ws + O_H1;
    float* agg1   = ws + O_AGG1;
    float* h2     = ws + O_H2;
    float* agg2   = ws + O_AGG2;
    float* dpsum  = ws + O_DPSUM;
    int*   dpcnt  = (int*)(ws + O_DPCNT);
    float* xd     = ws + O_XD;
    float* wet1   = ws + O_WET1;
    float* wet2   = ws + O_WET2;
    int*   cntdd  = (int*)(ws + O_CNTDD);
    float* rsum1  = ws + O_RSUM1;
    float* xd1    = ws + O_XD1;
    float* rsum2  = ws + O_RSUM2;

    hipMemsetAsync(cnt_pp, 0, NPROT*sizeof(int), stream);
    hipMemsetAsync(dpsum,  0, (64000 + 4000)*sizeof(float), stream);
    hipMemsetAsync(xd,     0, NDRUG*64*sizeof(float), stream);
    hipMemsetAsync(cntdd,  0, NDRUG*sizeof(int), stream);
    hipMemsetAsync(rsum1,  0, NDRUG*32*sizeof(float), stream);
    hipMemsetAsync(rsum2,  0, NDRUG*16*sizeof(float), stream);

    k_count_int<<<(EPP+255)/256,256,0,stream>>>(pp_dst, EPP, cnt_pp);
    k_dis<<<(NPROT+255)/256,256,0,stream>>>(cnt_pp, dis, NPROT);
    k_gemm<64,32,false><<<(NPROT*32+255)/256,256,0,stream>>>(x_prot, W1, h1, NPROT);
    k_gcn_init<32><<<(NPROT*32+255)/256,256,0,stream>>>(h1, dis, b1, agg1, NPROT);
    k_gcn_scatter<32><<<(EPP*32)/256,256,0,stream>>>(h1, dis, pp_src, pp_dst, EPP, agg1);
    k_gemm<32,16,true><<<(NPROT*16+255)/256,256,0,stream>>>(agg1, W2, h2, NPROT);
    k_gcn_init<16><<<(NPROT*16+255)/256,256,0,stream>>>(h2, dis, b2, agg2, NPROT);
    k_gcn_scatter<16><<<(EPP*16)/256,256,0,stream>>>(h2, dis, pp_src, pp_dst, EPP, agg2);
    k_dp_scatter<<<(EDP*16)/256,256,0,stream>>>(agg2, dp_src, dp_dst, dpsum, dpcnt);
    k_hier<<<(NDRUG*16+255)/256,256,0,stream>>>(dpsum, dpcnt, hgw, xd);
    {
      dim3 g((NDRUG+63)/64, 8);
      k_embed<<<g,256,0,stream>>>(x_drug, embed, xd);
    }
    k_embed_fin<<<(NDRUG*48+255)/256,256,0,stream>>>(xd, d_norm);
    k_wet<<<(NET*2048+255)/256,256,0,stream>>>(att1, basis1, wet1, 2048);
    k_wet<<<(NET*512+255)/256,256,0,stream>>>(att2, basis2, wet2, 512);
    k_count_int<<<(EDD+255)/256,256,0,stream>>>(dd_dst, EDD, cntdd);
    k_rgcn1<<<EDD/64,256,0,stream>>>(xd, dd_src, dd_dst, dd_et, wet1, rsum1);
    k_root1<<<(NDRUG*32+255)/256,256,0,stream>>>(rsum1, cntdd, xd, root1, xd1);
    k_rgcn2<<<(EDD+127)/128,256,0,stream>>>(xd1, dd_src, dd_dst, dd_et, wet2, rsum2);
    k_root2<<<(NDRUG*16+255)/256,256,0,stream>>>(rsum2, cntdd, xd1, root2, out);
  }
}

// Round 24
// 326.087 us; speedup vs baseline: 1.5720x; 1.0495x over previous
//
#include <hip/hip_runtime.h>

#define NPROT 20000
#define NDRUG 4000
#define INDRUG 4000
#define NET 128
#define NBASE 32
#define NEMBED 48
#define PDDIM 16
#define H1C 32
#define H2C 16
#define RGCNIN 64
#define EPP 800000
#define EDP 400000
#define EDD 1000000
#define NBLK 256
#define SCANG 8             // b-groups for 2-phase scan (256/32)
#define EKCH 160            // 5 k-steps of 32 per chunk
#define KSPLIT 25           // 4000 / 160
#define PBLKS 4035          // ceil(EDD/256) + NET
#define PEDD (PBLKS*256)    // padded edge capacity (1032960)

typedef __attribute__((ext_vector_type(8))) __bf16 bf16x8;
typedef __attribute__((ext_vector_type(4))) float f32x4;

__device__ __forceinline__ unsigned int f2bf(float f){
  unsigned int u = __float_as_uint(f);
  u += 0x7fffu + ((u >> 16) & 1u);     // RNE
  return u >> 16;
}
__device__ __forceinline__ float bf2f(unsigned int s){
  return __uint_as_float(s << 16);
}
__device__ __forceinline__ unsigned long long pack4(const f32x4& c){
  unsigned long long lo = (unsigned long long)(f2bf(c[0]) | (f2bf(c[1]) << 16));
  unsigned long long hi = (unsigned long long)(f2bf(c[2]) | (f2bf(c[3]) << 16));
  return lo | (hi << 32);
}

// ======================= shared kernels =======================

template<int K, int NC, bool RELU_IN>
__global__ void k_gemm(const float* __restrict__ A, const float* __restrict__ W,
                       float* __restrict__ C, int M){
  __shared__ float Ws[K*NC];
  for(int i = threadIdx.x; i < K*NC; i += 256) Ws[i] = W[i];
  __syncthreads();
  int idx = blockIdx.x*256 + threadIdx.x;
  int row = idx / NC, col = idx % NC;
  if(row >= M) return;
  const float* a = A + row*K;
  float acc = 0.f;
  #pragma unroll
  for(int k = 0; k < K; k++){
    float v = a[k];
    if(RELU_IN) v = fmaxf(v, 0.f);
    acc = fmaf(v, Ws[k*NC + col], acc);
  }
  C[idx] = acc;
}

// h1s = (x_prot @ W1) * dis[row]   (K=64, NC=32)
__global__ void k_gemm_s(const float* __restrict__ A, const float* __restrict__ W,
                         const float* __restrict__ dis, float* __restrict__ C, int M){
  __shared__ float Ws[64*32];
  for(int i = threadIdx.x; i < 64*32; i += 256) Ws[i] = W[i];
  __syncthreads();
  int idx = blockIdx.x*256 + threadIdx.x;
  int row = idx >> 5, col = idx & 31;
  if(row >= M) return;
  const float* a = A + row*64;
  float acc = 0.f;
  #pragma unroll
  for(int k = 0; k < 64; k++)
    acc = fmaf(a[k], Ws[k*32 + col], acc);
  C[idx] = acc * dis[row];
}

__global__ void k_wet(const float* __restrict__ att, const float* __restrict__ basis,
                      float* __restrict__ wet, int inout){
  int gid = blockIdx.x*256 + threadIdx.x;
  if(gid >= NET * inout) return;
  int et = gid / inout, ij = gid % inout;
  float acc = 0.f;
  #pragma unroll
  for(int b = 0; b < NBASE; b++)
    acc = fmaf(att[et*NBASE + b], basis[b*inout + ij], acc);
  wet[gid] = acc;
}

// bf16 fragment build DIRECT from att/basis: wetb1[et][f][l][j], f = kt*2+nt
__global__ void k_wetb1(const float* __restrict__ att, const float* __restrict__ basis,
                        unsigned short* __restrict__ wetb){
  int gid = blockIdx.x*256 + threadIdx.x;
  if(gid >= NET*2048) return;
  int et = gid >> 11, r = gid & 2047;
  int f = r >> 9, l = (r >> 3) & 63, j = r & 7;
  int kt = f >> 1, nt = f & 1;
  int k = kt*32 + ((l >> 4) << 3) + j;
  int c = nt*16 + (l & 15);
  float acc = 0.f;
  #pragma unroll
  for(int b = 0; b < NBASE; b++)
    acc = fmaf(att[et*NBASE + b], basis[b*2048 + k*32 + c], acc);
  wetb[gid] = (unsigned short)f2bf(acc);
}

__global__ void k_wetb2(const float* __restrict__ att, const float* __restrict__ basis,
                        unsigned short* __restrict__ wetb){
  int gid = blockIdx.x*256 + threadIdx.x;
  if(gid >= NET*512) return;
  int et = gid >> 9, r = gid & 511;
  int l = r >> 3, j = r & 7;
  int k = ((l >> 4) << 3) + j;
  int c = l & 15;
  float acc = 0.f;
  #pragma unroll
  for(int b = 0; b < NBASE; b++)
    acc = fmaf(att[et*NBASE + b], basis[b*512 + k*16 + c], acc);
  wetb[gid] = (unsigned short)f2bf(acc);
}

// embed B-fragment table: embb[kt][f][l][j], kt=0..124, f=0..2
__global__ void k_embb(const float* __restrict__ embed, unsigned short* __restrict__ embb){
  int gid = blockIdx.x*256 + threadIdx.x;
  if(gid >= 125*1536) return;
  int kt = gid / 1536, r = gid % 1536;
  int f = r / 512, l = (r >> 3) & 63, j = r & 7;
  int k = kt*32 + ((l >> 4) << 3) + j;
  int c = f*16 + (l & 15);
  embb[gid] = (unsigned short)f2bf(embed[k*48 + c]);
}

// ======================= padded edge layout =======================

__global__ void k_pstart(const int* __restrict__ range, int* __restrict__ pstart,
                         int* __restrict__ pblk){
  __shared__ int ps[NET];
  int t = threadIdx.x;
  int cnt = range[t*2+1] - range[t*2];
  int padc = (cnt + 255) & ~255;
  ps[t] = padc;
  __syncthreads();
  int myoff = 0;
  for(int i = 0; i < t; i++) myoff += ps[i];
  pstart[t] = myoff;
  if(t == NET-1) pstart[NET] = myoff + padc;
  int b0 = myoff >> 8, nb = padc >> 8;
  for(int i = 0; i < nb; i++) pblk[b0 + i] = t;
}

__global__ void k_pmap(const int* __restrict__ et, const int* __restrict__ src,
                       const int* __restrict__ range, const int* __restrict__ pstart,
                       int* __restrict__ psrc, int* __restrict__ pmape){
  int e = blockIdx.x*256 + threadIdx.x;
  if(e >= EDD) return;
  int t = et[e];
  int p = pstart[t] + (e - range[t*2]);
  psrc[p] = src[e];
  pmape[e] = p;
}

// iperm init: padding slots dump to [EDD, EDD+32768) (never read)
__global__ void k_iota(int* __restrict__ iperm){
  int p = blockIdx.x*256 + threadIdx.x;
  if(p < PEDD) iperm[p] = EDD + (p & 32767);
}

// ======================= fast path: CSR build (u16 gh, packed-LDS hist, 2-phase scan) =======================

// single-pass histogram over PB bins; LDS packs 2 u16 counters per u32 word.
// per-block chunk <= ceil(ne/NBLK) < 65536 so halves never overflow.
template<int PB>
__global__ void k_hist(const int* __restrict__ dst, int ne, int sub,
                       unsigned short* __restrict__ gh, int bins){
  __shared__ unsigned int h[PB/2];
  for(int i = threadIdx.x; i < PB/2; i += 256) h[i] = 0;
  __syncthreads();
  int chunk = (ne + NBLK - 1) / NBLK;
  int s0 = blockIdx.x*chunk, s1 = min(s0 + chunk, ne);
  for(int i = s0 + threadIdx.x; i < s1; i += 256){
    int b = dst[i] - sub;
    if(b >= 0 && b < PB) atomicAdd(&h[b >> 1], 1u << ((b & 1) * 16));
  }
  __syncthreads();
  unsigned int* go = (unsigned int*)(gh + (size_t)blockIdx.x*bins);
  for(int i = threadIdx.x; i < PB/2; i += 256) go[i] = h[i];
}

// phase 1: psum[g][bin] = sum of gh[b][bin] for b in group g (32 rows)
__global__ void k_scan_p1(const unsigned short* __restrict__ gh, int* __restrict__ psum,
                          int bins){
  int bin = blockIdx.x*256 + threadIdx.x;
  int g = blockIdx.y;
  if(bin >= bins) return;
  int s = 0;
  #pragma unroll 8
  for(int b = g*32; b < g*32 + 32; b++) s += gh[(size_t)b*bins + bin];
  psum[(size_t)g*bins + bin] = s;
}

// phase 2: exclusive prefix within column (fits u16: max = node degree); g==SCANG-1 writes cnt
__global__ void k_scan_p2(unsigned short* __restrict__ gh, const int* __restrict__ psum,
                          int* __restrict__ cnt, int bins){
  int bin = blockIdx.x*256 + threadIdx.x;
  int g = blockIdx.y;
  if(bin >= bins) return;
  int run = 0;
  for(int gg = 0; gg < g; gg++) run += psum[(size_t)gg*bins + bin];
  #pragma unroll 8
  for(int b = g*32; b < g*32 + 32; b++){
    int v = gh[(size_t)b*bins + bin];
    gh[(size_t)b*bins + bin] = (unsigned short)run;
    run += v;
  }
  if(g == SCANG-1) cnt[bin] = run;
}

__global__ void k_scan_off(const int* __restrict__ cnt, int* __restrict__ off, int bins){
  __shared__ int ps[1024];
  int t = threadIdx.x;
  int C = (bins + 1023) >> 10;
  int lo = t*C, hi = min(lo + C, bins);
  int s = 0;
  for(int i = lo; i < hi; i++) s += cnt[i];
  ps[t] = s;
  __syncthreads();
  for(int d = 1; d < 1024; d <<= 1){
    int v = (t >= d) ? ps[t-d] : 0;
    __syncthreads();
    ps[t] += v;
    __syncthreads();
  }
  int run = ps[t] - s;   // exclusive
  for(int i = lo; i < hi; i++){ off[i] = run; run += cnt[i]; }
  if(t == 1023) off[bins] = ps[1023];
}

// MODE 0: outp[pos] = src[e]   MODE 1: outp[src[e]] = pos (inverse perm)
template<int PB, int MODE>
__global__ void k_scatter(const int* __restrict__ dst, const int* __restrict__ src,
                          int ne, int sub, int b0, const unsigned short* __restrict__ gh,
                          const int* __restrict__ off, int bins, int* __restrict__ outp){
  __shared__ int h[PB];
  for(int i = threadIdx.x; i < PB; i += 256)
    h[i] = off[b0 + i] + gh[(size_t)blockIdx.x*bins + b0 + i];
  __syncthreads();
  int chunk = (ne + NBLK - 1) / NBLK;
  int s0 = blockIdx.x*chunk, s1 = min(s0 + chunk, ne);
  for(int i = s0 + threadIdx.x; i < s1; i += 256){
    int b = dst[i] - sub - b0;
    if(b >= 0 && b < PB){
      int p = atomicAdd(&h[b], 1);
      if(MODE == 0) outp[p] = src[i];
      else          outp[src[i]] = p;
    }
  }
}

__global__ void k_dis_off(const int* __restrict__ off, float* __restrict__ dis, int n){
  int i = blockIdx.x*256 + threadIdx.x;
  if(i < n) dis[i] = rsqrtf((float)(off[i+1] - off[i]) + 1.0f);
}

// ======================= fast path: gathers (block per dst, MLP-unrolled) =======================

// h1s = h1*dis (pre-scaled). h2out written pre-scaled by dis[d] for layer 2.
__global__ void k_gcn_gather1(const float* __restrict__ hs, const float* __restrict__ dis,
                              const int* __restrict__ off, const int* __restrict__ srcperm,
                              const float* __restrict__ b1, const float* __restrict__ W2,
                              float* __restrict__ h2s){
  __shared__ float red[4][32];
  __shared__ float m[32];
  __shared__ float W2s[512];
  int d = blockIdx.x, tid = threadIdx.x;
  for(int i = tid; i < 512; i += 256) W2s[i] = W2[i];
  int col = tid & 31, g = tid >> 5;     // 8 groups
  int o0 = off[d], cnt = off[d+1] - o0;
  float s0 = 0.f, s1 = 0.f, s2 = 0.f, s3 = 0.f;
  int i = g;
  for(; i + 24 < cnt; i += 32){
    int j0 = srcperm[o0 + i],      j1 = srcperm[o0 + i + 8];
    int j2 = srcperm[o0 + i + 16], j3 = srcperm[o0 + i + 24];
    s0 += hs[j0*32 + col]; s1 += hs[j1*32 + col];
    s2 += hs[j2*32 + col]; s3 += hs[j3*32 + col];
  }
  for(; i < cnt; i += 8) s0 += hs[srcperm[o0 + i]*32 + col];
  float s = (s0 + s1) + (s2 + s3);
  s += __shfl_xor(s, 32);
  int wv = tid >> 6, lane = tid & 63;
  if(lane < 32) red[wv][lane] = s;
  __syncthreads();
  float dd = dis[d];
  if(tid < 32){
    float v = (red[0][tid]+red[1][tid]+red[2][tid]+red[3][tid] + hs[d*32 + tid])*dd + b1[tid];
    m[tid] = fmaxf(v, 0.f);
  }
  __syncthreads();
  if(tid < 16){
    float acc = 0.f;
    #pragma unroll
    for(int k = 0; k < 32; k++) acc = fmaf(m[k], W2s[k*16 + tid], acc);
    h2s[d*16 + tid] = acc * dd;       // pre-scale for layer 2
  }
}

// agg2 = (sum_src h2s[src] + h2s[d])*dis[d] + b2   (true agg2, unscaled output)
__global__ void k_gcn_gather2(const float* __restrict__ hs, const float* __restrict__ dis,
                              const int* __restrict__ off, const int* __restrict__ srcperm,
                              const float* __restrict__ b, float* __restrict__ agg){
  __shared__ float red[4][16];
  int d = blockIdx.x;
  int tid = threadIdx.x;
  int col = tid & 15;
  int g = tid >> 4;                    // 16 groups
  int o0 = off[d], cnt = off[d+1] - o0;
  float s0 = 0.f, s1 = 0.f;
  int i = g;
  for(; i + 16 < cnt; i += 32){
    int j0 = srcperm[o0 + i], j1 = srcperm[o0 + i + 16];
    s0 += hs[j0*16 + col];
    s1 += hs[j1*16 + col];
  }
  for(; i < cnt; i += 16) s0 += hs[srcperm[o0 + i]*16 + col];
  float s = s0 + s1;
  s += __shfl_xor(s, 32);
  s += __shfl_xor(s, 16);
  int wv = tid >> 6, lane = tid & 63;
  if(lane < 16) red[wv][lane] = s;
  __syncthreads();
  if(tid < 16){
    float tot = red[0][tid] + red[1][tid] + red[2][tid] + red[3][tid];
    float dd = dis[d];
    agg[d*16 + tid] = (tot + hs[d*16 + tid])*dd + b[tid];
  }
}

__global__ void k_dp_gather(const float* __restrict__ xp2, const int* __restrict__ off,
                            const int* __restrict__ srcperm, const float* __restrict__ hg,
                            float* __restrict__ xd, unsigned short* __restrict__ xdb){
  __shared__ float red[4][16];
  __shared__ float m[16];
  int d = blockIdx.x;
  int tid = threadIdx.x;
  int col = tid & 15, g = tid >> 4;
  int o0 = off[d], cnt = off[d+1] - o0;
  float s0 = 0.f, s1 = 0.f, s2 = 0.f, s3 = 0.f;
  int i = g;
  for(; i + 48 < cnt; i += 64){
    int j0 = srcperm[o0 + i],      j1 = srcperm[o0 + i + 16];
    int j2 = srcperm[o0 + i + 32], j3 = srcperm[o0 + i + 48];
    s0 += xp2[j0*16 + col]; s1 += xp2[j1*16 + col];
    s2 += xp2[j2*16 + col]; s3 += xp2[j3*16 + col];
  }
  for(; i < cnt; i += 16) s0 += xp2[srcperm[o0 + i]*16 + col];
  float s = (s0 + s1) + (s2 + s3);
  s += __shfl_xor(s, 32);
  s += __shfl_xor(s, 16);
  int wv = tid >> 6, lane = tid & 63;
  if(lane < 16) red[wv][lane] = s;
  __syncthreads();
  if(tid < 16) m[tid] = (red[0][tid]+red[1][tid]+red[2][tid]+red[3][tid]) / fmaxf((float)cnt, 1.f);
  __syncthreads();
  if(tid < 16){
    float acc = 0.f;
    #pragma unroll
    for(int k = 0; k < 16; k++) acc = fmaf(m[k], hg[k*16 + tid], acc);
    xd[d*64 + 48 + tid] = acc;
    xdb[d*64 + 48 + tid] = (unsigned short)f2bf(acc);
  }
}

// ======================= fast path: embed GEMM via MFMA =======================

__global__ __launch_bounds__(256) void k_embed_m(
    const float* __restrict__ xdrug, const unsigned short* __restrict__ embb,
    float* __restrict__ xdp){
  int tid = threadIdx.x;
  int wv = tid >> 6, l = tid & 63;
  int rt = blockIdx.x*4 + wv;            // row tile (16 rows)
  int row = rt*16 + (l & 15);
  int kg = (l >> 4) << 3;
  int cb = blockIdx.y * EKCH;
  bool valid = row < NDRUG;
  const float* xr = xdrug + (size_t)row * INDRUG;
  f32x4 z = {0.f,0.f,0.f,0.f};
  f32x4 c0 = z, c1 = z, c2 = z;
  #pragma unroll
  for(int ks = 0; ks < EKCH/32; ks++){
    int k0 = cb + ks*32;
    float4 u = make_float4(0,0,0,0), v = make_float4(0,0,0,0);
    if(valid){
      u = *(const float4*)(xr + k0 + kg);
      v = *(const float4*)(xr + k0 + kg + 4);
    }
    bf16x8 a;
    a[0] = (__bf16)u.x; a[1] = (__bf16)u.y; a[2] = (__bf16)u.z; a[3] = (__bf16)u.w;
    a[4] = (__bf16)v.x; a[5] = (__bf16)v.y; a[6] = (__bf16)v.z; a[7] = (__bf16)v.w;
    const unsigned short* bb = embb + (size_t)(k0 >> 5)*1536 + l*8;
    bf16x8 b0 = *(const bf16x8*)(bb);
    bf16x8 b1 = *(const bf16x8*)(bb + 512);
    bf16x8 b2 = *(const bf16x8*)(bb + 1024);
    c0 = __builtin_amdgcn_mfma_f32_16x16x32_bf16(a, b0, c0, 0,0,0);
    c1 = __builtin_amdgcn_mfma_f32_16x16x32_bf16(a, b1, c1, 0,0,0);
    c2 = __builtin_amdgcn_mfma_f32_16x16x32_bf16(a, b2, c2, 0,0,0);
  }
  int col = l & 15, rb = (l >> 4) << 2;
  float* op = xdp + (size_t)blockIdx.y * NDRUG * 48;
  #pragma unroll
  for(int r = 0; r < 4; r++){
    int ro = rt*16 + rb + r;
    if(ro < NDRUG){
      op[ro*48 + col]       = c0[r];
      op[ro*48 + 16 + col]  = c1[r];
      op[ro*48 + 32 + col]  = c2[r];
    }
  }
}

__global__ void k_embed_fin2(const float* __restrict__ xdp, const float* __restrict__ dnorm,
                             float* __restrict__ xd, unsigned short* __restrict__ xdb){
  int gid = blockIdx.x*256 + threadIdx.x;
  if(gid >= NDRUG*48) return;
  int d = gid / 48, j = gid % 48;
  float s = 0.f;
  for(int y = 0; y < KSPLIT; y++) s += xdp[(size_t)y*NDRUG*48 + gid];
  float v = s / dnorm[d];
  xd[d*64 + j] = v;
  xdb[d*64 + j] = (unsigned short)f2bf(v);
}

// ======================= RGCN msgs via MFMA (padded, branch-free, CSR-ordered output) =======================

__global__ __launch_bounds__(256) void k_rgcn1_msgsM(
    const unsigned short* __restrict__ xdb, const int* __restrict__ psrc,
    const int* __restrict__ pblk, const unsigned short* __restrict__ wetb,
    const int* __restrict__ iperm, unsigned short* __restrict__ msgs){
  int tid = threadIdx.x;
  int wv = tid >> 6, l = tid & 63;
  int t0 = pblk[blockIdx.x];
  const unsigned short* wb = wetb + (size_t)t0*2048 + l*8;
  bf16x8 w00 = *(const bf16x8*)(wb);
  bf16x8 w01 = *(const bf16x8*)(wb + 512);
  bf16x8 w10 = *(const bf16x8*)(wb + 1024);
  bf16x8 w11 = *(const bf16x8*)(wb + 1536);
  int eb = blockIdx.x*256 + wv*64;
  int col = l & 15;
  int g4 = (l >> 4) << 3;
  int rb = (l >> 4) << 2;
  int e0 = eb + col, e1 = eb + 16 + col, e2 = eb + 32 + col, e3 = eb + 48 + col;
  int s0 = psrc[e0], s1 = psrc[e1], s2 = psrc[e2], s3 = psrc[e3];
  int p0 = iperm[e0], p1 = iperm[e1], p2 = iperm[e2], p3 = iperm[e3];
  const unsigned short* x0 = xdb + (size_t)s0*64 + g4;
  const unsigned short* x1 = xdb + (size_t)s1*64 + g4;
  const unsigned short* x2 = xdb + (size_t)s2*64 + g4;
  const unsigned short* x3 = xdb + (size_t)s3*64 + g4;
  bf16x8 a00 = *(const bf16x8*)(x0), a01 = *(const bf16x8*)(x0 + 32);
  bf16x8 a10 = *(const bf16x8*)(x1), a11 = *(const bf16x8*)(x1 + 32);
  bf16x8 a20 = *(const bf16x8*)(x2), a21 = *(const bf16x8*)(x2 + 32);
  bf16x8 a30 = *(const bf16x8*)(x3), a31 = *(const bf16x8*)(x3 + 32);
  f32x4 z = {0.f,0.f,0.f,0.f};
  f32x4 c00=z,c01=z,c10=z,c11=z,c20=z,c21=z,c30=z,c31=z;
  c00 = __builtin_amdgcn_mfma_f32_16x16x32_bf16(w00, a00, c00, 0,0,0);
  c00 = __builtin_amdgcn_mfma_f32_16x16x32_bf16(w10, a01, c00, 0,0,0);
  c01 = __builtin_amdgcn_mfma_f32_16x16x32_bf16(w01, a00, c01, 0,0,0);
  c01 = __builtin_amdgcn_mfma_f32_16x16x32_bf16(w11, a01, c01, 0,0,0);
  c10 = __builtin_amdgcn_mfma_f32_16x16x32_bf16(w00, a10, c10, 0,0,0);
  c10 = __builtin_amdgcn_mfma_f32_16x16x32_bf16(w10, a11, c10, 0,0,0);
  c11 = __builtin_amdgcn_mfma_f32_16x16x32_bf16(w01, a10, c11, 0,0,0);
  c11 = __builtin_amdgcn_mfma_f32_16x16x32_bf16(w11, a11, c11, 0,0,0);
  c20 = __builtin_amdgcn_mfma_f32_16x16x32_bf16(w00, a20, c20, 0,0,0);
  c20 = __builtin_amdgcn_mfma_f32_16x16x32_bf16(w10, a21, c20, 0,0,0);
  c21 = __builtin_amdgcn_mfma_f32_16x16x32_bf16(w01, a20, c21, 0,0,0);
  c21 = __builtin_amdgcn_mfma_f32_16x16x32_bf16(w11, a21, c21, 0,0,0);
  c30 = __builtin_amdgcn_mfma_f32_16x16x32_bf16(w00, a30, c30, 0,0,0);
  c30 = __builtin_amdgcn_mfma_f32_16x16x32_bf16(w10, a31, c30, 0,0,0);
  c31 = __builtin_amdgcn_mfma_f32_16x16x32_bf16(w01, a30, c31, 0,0,0);
  c31 = __builtin_amdgcn_mfma_f32_16x16x32_bf16(w11, a31, c31, 0,0,0);
  *(unsigned long long*)(msgs + (size_t)p0*32 + rb)      = pack4(c00);
  *(unsigned long long*)(msgs + (size_t)p0*32 + 16 + rb) = pack4(c01);
  *(unsigned long long*)(msgs + (size_t)p1*32 + rb)      = pack4(c10);
  *(unsigned long long*)(msgs + (size_t)p1*32 + 16 + rb) = pack4(c11);
  *(unsigned long long*)(msgs + (size_t)p2*32 + rb)      = pack4(c20);
  *(unsigned long long*)(msgs + (size_t)p2*32 + 16 + rb) = pack4(c21);
  *(unsigned long long*)(msgs + (size_t)p3*32 + rb)      = pack4(c30);
  *(unsigned long long*)(msgs + (size_t)p3*32 + 16 + rb) = pack4(c31);
}

__global__ __launch_bounds__(256) void k_rgcn2_msgsM(
    const unsigned short* __restrict__ xd1b, const int* __restrict__ psrc,
    const int* __restrict__ pblk, const unsigned short* __restrict__ wetb,
    const int* __restrict__ iperm, unsigned short* __restrict__ msgs){
  int tid = threadIdx.x;
  int wv = tid >> 6, l = tid & 63;
  int t0 = pblk[blockIdx.x];
  bf16x8 w0 = *(const bf16x8*)(wetb + (size_t)t0*512 + l*8);
  int eb = blockIdx.x*256 + wv*64;
  int col = l & 15;
  int g4 = (l >> 4) << 3;
  int rb = (l >> 4) << 2;
  int e0 = eb + col, e1 = eb + 16 + col, e2 = eb + 32 + col, e3 = eb + 48 + col;
  int s0 = psrc[e0], s1 = psrc[e1], s2 = psrc[e2], s3 = psrc[e3];
  int p0 = iperm[e0], p1 = iperm[e1], p2 = iperm[e2], p3 = iperm[e3];
  bf16x8 a0 = *(const bf16x8*)(xd1b + (size_t)s0*32 + g4);
  bf16x8 a1 = *(const bf16x8*)(xd1b + (size_t)s1*32 + g4);
  bf16x8 a2 = *(const bf16x8*)(xd1b + (size_t)s2*32 + g4);
  bf16x8 a3 = *(const bf16x8*)(xd1b + (size_t)s3*32 + g4);
  f32x4 z = {0.f,0.f,0.f,0.f};
  f32x4 c0=z,c1=z,c2=z,c3=z;
  c0 = __builtin_amdgcn_mfma_f32_16x16x32_bf16(w0, a0, c0, 0,0,0);
  c1 = __builtin_amdgcn_mfma_f32_16x16x32_bf16(w0, a1, c1, 0,0,0);
  c2 = __builtin_amdgcn_mfma_f32_16x16x32_bf16(w0, a2, c2, 0,0,0);
  c3 = __builtin_amdgcn_mfma_f32_16x16x32_bf16(w0, a3, c3, 0,0,0);
  *(unsigned long long*)(msgs + (size_t)p0*16 + rb) = pack4(c0);
  *(unsigned long long*)(msgs + (size_t)p1*16 + rb) = pack4(c1);
  *(unsigned long long*)(msgs + (size_t)p2*16 + rb) = pack4(c2);
  *(unsigned long long*)(msgs + (size_t)p3*16 + rb) = pack4(c3);
}

// block per dst: 16 row-streams, SEQUENTIAL msgs rows (CSR-ordered), 4-way unroll
__global__ void k_rgcn1_reduce(const unsigned short* __restrict__ msgs, const int* __restrict__ off,
                               const float* __restrict__ xd, const float* __restrict__ root,
                               float* __restrict__ xd1, unsigned short* __restrict__ xd1b){
  __shared__ float red[16][32];
  int d = blockIdx.x;
  int tid = threadIdx.x;
  int cp = tid & 15, r = tid >> 4;
  int o0 = off[d], cnt = off[d+1] - o0;
  float s0 = 0.f, s1 = 0.f;
  int i = r;
  for(; i + 48 < cnt; i += 64){
    unsigned int v0 = *(const unsigned int*)(msgs + (size_t)(o0+i)*32 + cp*2);
    unsigned int v1 = *(const unsigned int*)(msgs + (size_t)(o0+i+16)*32 + cp*2);
    unsigned int v2 = *(const unsigned int*)(msgs + (size_t)(o0+i+32)*32 + cp*2);
    unsigned int v3 = *(const unsigned int*)(msgs + (size_t)(o0+i+48)*32 + cp*2);
    s0 += bf2f(v0 & 0xffffu) + bf2f(v1 & 0xffffu) + bf2f(v2 & 0xffffu) + bf2f(v3 & 0xffffu);
    s1 += bf2f(v0 >> 16)     + bf2f(v1 >> 16)     + bf2f(v2 >> 16)     + bf2f(v3 >> 16);
  }
  for(; i < cnt; i += 16){
    unsigned int v = *(const unsigned int*)(msgs + (size_t)(o0+i)*32 + cp*2);
    s0 += bf2f(v & 0xffffu); s1 += bf2f(v >> 16);
  }
  red[r][cp*2] = s0; red[r][cp*2+1] = s1;
  __syncthreads();
  if(tid < 32){
    float tot = 0.f;
    #pragma unroll
    for(int r2 = 0; r2 < 16; r2++) tot += red[r2][tid];
    float rr = 0.f;
    const float* x = xd + d*64;
    #pragma unroll 8
    for(int i2 = 0; i2 < 64; i2++) rr = fmaf(x[i2], root[i2*32 + tid], rr);
    float v = fmaxf(tot / fmaxf((float)cnt, 1.0f) + rr, 0.f);
    xd1[d*32 + tid] = v;
    xd1b[d*32 + tid] = (unsigned short)f2bf(v);
  }
}

__global__ void k_rgcn2_reduce(const unsigned short* __restrict__ msgs, const int* __restrict__ off,
                               const float* __restrict__ xd1, const float* __restrict__ root,
                               float* __restrict__ out){
  __shared__ float red[32][16];
  int d = blockIdx.x;
  int tid = threadIdx.x;
  int cp = tid & 7, r = tid >> 3;
  int o0 = off[d], cnt = off[d+1] - o0;
  float s0 = 0.f, s1 = 0.f;
  int i = r;
  for(; i + 96 < cnt; i += 128){
    unsigned int v0 = *(const unsigned int*)(msgs + (size_t)(o0+i)*16 + cp*2);
    unsigned int v1 = *(const unsigned int*)(msgs + (size_t)(o0+i+32)*16 + cp*2);
    unsigned int v2 = *(const unsigned int*)(msgs + (size_t)(o0+i+64)*16 + cp*2);
    unsigned int v3 = *(const unsigned int*)(msgs + (size_t)(o0+i+96)*16 + cp*2);
    s0 += bf2f(v0 & 0xffffu) + bf2f(v1 & 0xffffu) + bf2f(v2 & 0xffffu) + bf2f(v3 & 0xffffu);
    s1 += bf2f(v0 >> 16)     + bf2f(v1 >> 16)     + bf2f(v2 >> 16)     + bf2f(v3 >> 16);
  }
  for(; i < cnt; i += 32){
    unsigned int v = *(const unsigned int*)(msgs + (size_t)(o0+i)*16 + cp*2);
    s0 += bf2f(v & 0xffffu); s1 += bf2f(v >> 16);
  }
  red[r][cp*2] = s0; red[r][cp*2+1] = s1;
  __syncthreads();
  if(tid < 16){
    float tot = 0.f;
    #pragma unroll
    for(int r2 = 0; r2 < 32; r2++) tot += red[r2][tid];
    float rr = 0.f;
    const float* x = xd1 + d*32;
    #pragma unroll 8
    for(int i2 = 0; i2 < 32; i2++) rr = fmaf(x[i2], root[i2*16 + tid], rr);
    out[d*16 + tid] = tot / fmaxf((float)cnt, 1.0f) + rr;
  }
}

// ======================= fallback (round-1) kernels =======================

#define O_CNTPP   0
#define O_DIS     20000
#define O_H1      40000
#define O_AGG1    680000
#define O_H2      1320000
#define O_AGG2    1640000
#define O_DPSUM   1960000
#define O_DPCNT   2024000
#define O_XD      2028000
#define O_WET1    2284000
#define O_WET2    2546144
#define O_CNTDD   2611680
#define O_RSUM1   2615680
#define O_XD1     2743680
#define O_RSUM2   2871680

__global__ void k_count_int(const int* __restrict__ dst, int ne, int* __restrict__ cnt){
  int i = blockIdx.x*256 + threadIdx.x;
  if(i < ne) atomicAdd(&cnt[dst[i]], 1);
}

__global__ void k_dis(const int* __restrict__ cnt, float* __restrict__ dis, int n){
  int i = blockIdx.x*256 + threadIdx.x;
  if(i < n) dis[i] = rsqrtf((float)cnt[i] + 1.0f);
}

template<int NC>
__global__ void k_gcn_init(const float* __restrict__ h, const float* __restrict__ dis,
                           const float* __restrict__ b, float* __restrict__ agg, int n){
  int i = blockIdx.x*256 + threadIdx.x;
  if(i < n*NC){
    int r = i / NC, c = i % NC;
    float d = dis[r];
    agg[i] = fmaf(h[i], d*d, b[c]);
  }
}

template<int NC>
__global__ void k_gcn_scatter(const float* __restrict__ h, const float* __restrict__ dis,
                              const int* __restrict__ src, const int* __restrict__ dst,
                              int ne, float* __restrict__ agg){
  int gid = blockIdx.x*256 + threadIdx.x;
  int e = gid / NC, j = gid % NC;
  if(e >= ne) return;
  int s = src[e], d = dst[e];
  atomicAdd(&agg[d*NC + j], h[s*NC + j] * dis[s] * dis[d]);
}

__global__ void k_dp_scatter(const float* __restrict__ xp2, const int* __restrict__ src,
                             const int* __restrict__ dst, float* __restrict__ dpsum,
                             int* __restrict__ dpcnt){
  int gid = blockIdx.x*256 + threadIdx.x;
  int e = gid >> 4, j = gid & 15;
  if(e >= EDP) return;
  int s = src[e], d = dst[e] - NPROT;
  atomicAdd(&dpsum[d*16 + j], xp2[s*16 + j]);
  if(j == 0) atomicAdd(&dpcnt[d], 1);
}

__global__ void k_hier(const float* __restrict__ dpsum, const int* __restrict__ dpcnt,
                       const float* __restrict__ hg, float* __restrict__ xd){
  int gid = blockIdx.x*256 + threadIdx.x;
  int d = gid >> 4, j = gid & 15;
  if(d >= NDRUG) return;
  float inv = 1.0f / fmaxf((float)dpcnt[d], 1.0f);
  float acc = 0.f;
  #pragma unroll
  for(int k = 0; k < 16; k++) acc = fmaf(dpsum[d*16 + k] * inv, hg[k*16 + j], acc);
  xd[d*64 + 48 + j] = acc;
}

__global__ void k_embed(const float* __restrict__ xdrug, const float* __restrict__ embed,
                        float* __restrict__ xd){
  __shared__ float xs[64][65];
  __shared__ float es[64][48];
  int tid = threadIdx.x;
  int r = tid & 63;
  int cg = tid >> 6;
  int row0 = blockIdx.x * 64;
  int k0c = blockIdx.y * 512;
  float acc[12];
  #pragma unroll
  for(int j = 0; j < 12; j++) acc[j] = 0.f;
  for(int kt = 0; kt < 512; kt += 64){
    int k0 = k0c + kt;
    if(k0 >= INDRUG) break;
    __syncthreads();
    #pragma unroll
    for(int i = 0; i < 4; i++){
      int lin = tid + i*256;
      int rr = lin >> 4, kc = lin & 15;
      int grow = row0 + rr, gk = k0 + kc*4;
      float4 v = make_float4(0.f,0.f,0.f,0.f);
      if(grow < NDRUG && gk + 3 < INDRUG)
        v = *(const float4*)&xdrug[(size_t)grow * INDRUG + gk];
      xs[rr][kc*4+0]=v.x; xs[rr][kc*4+1]=v.y; xs[rr][kc*4+2]=v.z; xs[rr][kc*4+3]=v.w;
    }
    #pragma unroll
    for(int i = 0; i < 3; i++){
      int lin = tid + i*256;
      int kk = lin / 12, jc = lin % 12;
      float4 v = make_float4(0.f,0.f,0.f,0.f);
      if(k0 + kk < INDRUG)
        v = *(const float4*)&embed[(size_t)(k0 + kk) * NEMBED + jc*4];
      *(float4*)&es[kk][jc*4] = v;
    }
    __syncthreads();
    #pragma unroll 8
    for(int kk = 0; kk < 64; kk++){
      float xv = xs[r][kk];
      const float4* ep = (const float4*)&es[kk][cg*12];
      float4 e0 = ep[0], e1 = ep[1], e2 = ep[2];
      acc[0]=fmaf(xv,e0.x,acc[0]);  acc[1]=fmaf(xv,e0.y,acc[1]);
      acc[2]=fmaf(xv,e0.z,acc[2]);  acc[3]=fmaf(xv,e0.w,acc[3]);
      acc[4]=fmaf(xv,e1.x,acc[4]);  acc[5]=fmaf(xv,e1.y,acc[5]);
      acc[6]=fmaf(xv,e1.z,acc[6]);  acc[7]=fmaf(xv,e1.w,acc[7]);
      acc[8]=fmaf(xv,e2.x,acc[8]);  acc[9]=fmaf(xv,e2.y,acc[9]);
      acc[10]=fmaf(xv,e2.z,acc[10]); acc[11]=fmaf(xv,e2.w,acc[11]);
    }
  }
  int grow = row0 + r;
  if(grow < NDRUG){
    #pragma unroll
    for(int j = 0; j < 12; j++)
      atomicAdd(&xd[grow*64 + cg*12 + j], acc[j]);
  }
}

__global__ void k_embed_fin(float* __restrict__ xd, const float* __restrict__ dnorm){
  int gid = blockIdx.x*256 + threadIdx.x;
  if(gid >= NDRUG*48) return;
  int d = gid / 48, j = gid % 48;
  xd[d*64 + j] = xd[d*64 + j] / dnorm[d];
}

__global__ void k_rgcn1(const float* __restrict__ xd, const int* __restrict__ src,
                        const int* __restrict__ dst, const int* __restrict__ et,
                        const float* __restrict__ wet, float* __restrict__ rsum){
  int tid = threadIdx.x;
  int e = blockIdx.x*64 + (tid >> 2);
  if(e >= EDD) return;
  int jg = tid & 3;
  int s = src[e], d = dst[e], t = et[e];
  const float* x = xd + s*64;
  const float* w = wet + t*2048 + jg*8;
  float acc[8] = {0,0,0,0,0,0,0,0};
  #pragma unroll 8
  for(int i = 0; i < 64; i++){
    float xv = x[i];
    const float4* wp = (const float4*)(w + i*32);
    float4 w0 = wp[0], w1 = wp[1];
    acc[0]=fmaf(xv,w0.x,acc[0]); acc[1]=fmaf(xv,w0.y,acc[1]);
    acc[2]=fmaf(xv,w0.z,acc[2]); acc[3]=fmaf(xv,w0.w,acc[3]);
    acc[4]=fmaf(xv,w1.x,acc[4]); acc[5]=fmaf(xv,w1.y,acc[5]);
    acc[6]=fmaf(xv,w1.z,acc[6]); acc[7]=fmaf(xv,w1.w,acc[7]);
  }
  float* outp = rsum + d*32 + jg*8;
  #pragma unroll
  for(int j = 0; j < 8; j++) atomicAdd(&outp[j], acc[j]);
}

__global__ void k_rgcn2(const float* __restrict__ xd1, const int* __restrict__ src,
                        const int* __restrict__ dst, const int* __restrict__ et,
                        const float* __restrict__ wet, float* __restrict__ rsum){
  int tid = threadIdx.x;
  int e = blockIdx.x*128 + (tid >> 1);
  if(e >= EDD) return;
  int jg = tid & 1;
  int s = src[e], d = dst[e], t = et[e];
  const float* x = xd1 + s*32;
  const float* w = wet + t*512 + jg*8;
  float acc[8] = {0,0,0,0,0,0,0,0};
  #pragma unroll 8
  for(int i = 0; i < 32; i++){
    float xv = x[i];
    const float4* wp = (const float4*)(w + i*16);
    float4 w0 = wp[0], w1 = wp[1];
    acc[0]=fmaf(xv,w0.x,acc[0]); acc[1]=fmaf(xv,w0.y,acc[1]);
    acc[2]=fmaf(xv,w0.z,acc[2]); acc[3]=fmaf(xv,w0.w,acc[3]);
    acc[4]=fmaf(xv,w1.x,acc[4]); acc[5]=fmaf(xv,w1.y,acc[5]);
    acc[6]=fmaf(xv,w1.z,acc[6]); acc[7]=fmaf(xv,w1.w,acc[7]);
  }
  float* outp = rsum + d*16 + jg*8;
  #pragma unroll
  for(int j = 0; j < 8; j++) atomicAdd(&outp[j], acc[j]);
}

__global__ void k_root1(const float* __restrict__ rsum, const int* __restrict__ cnt,
                        const float* __restrict__ xd, const float* __restrict__ root,
                        float* __restrict__ xd1){
  int gid = blockIdx.x*256 + threadIdx.x;
  int d = gid >> 5, j = gid & 31;
  if(d >= NDRUG) return;
  float inv = 1.0f / fmaxf((float)cnt[d], 1.0f);
  float acc = rsum[d*32 + j] * inv;
  #pragma unroll
  for(int i = 0; i < 64; i++) acc = fmaf(xd[d*64 + i], root[i*32 + j], acc);
  xd1[d*32 + j] = fmaxf(acc, 0.f);
}

__global__ void k_root2(const float* __restrict__ rsum, const int* __restrict__ cnt,
                        const float* __restrict__ xd1, const float* __restrict__ root,
                        float* __restrict__ out){
  int gid = blockIdx.x*256 + threadIdx.x;
  int d = gid >> 4, j = gid & 15;
  if(d >= NDRUG) return;
  float inv = 1.0f / fmaxf((float)cnt[d], 1.0f);
  float acc = rsum[d*16 + j] * inv;
  #pragma unroll
  for(int i = 0; i < 32; i++) acc = fmaf(xd1[d*32 + i], root[i*16 + j], acc);
  out[d*16 + j] = acc;
}

// ======================= launch =======================

extern "C" void kernel_launch(void* const* d_in, const int* in_sizes, int n_in,
                              void* d_out, int out_size, void* d_ws, size_t ws_size,
                              hipStream_t stream){
  const float* x_drug  = (const float*)d_in[0];
  const float* d_norm  = (const float*)d_in[1];
  const float* x_prot  = (const float*)d_in[2];
  const int*   pp_ei   = (const int*)d_in[3];
  const int*   dp_ei   = (const int*)d_in[4];
  const int*   dd_ei   = (const int*)d_in[6];
  const int*   dd_et   = (const int*)d_in[7];
  const int*   dd_rl   = (const int*)d_in[8];
  const float* embed   = (const float*)d_in[9];
  const float* W1      = (const float*)d_in[10];
  const float* b1      = (const float*)d_in[11];
  const float* W2      = (const float*)d_in[12];
  const float* b2      = (const float*)d_in[13];
  const float* hgw     = (const float*)d_in[14];
  const float* att1    = (const float*)d_in[15];
  const float* basis1  = (const float*)d_in[16];
  const float* root1   = (const float*)d_in[17];
  const float* att2    = (const float*)d_in[18];
  const float* basis2  = (const float*)d_in[19];
  const float* root2   = (const float*)d_in[20];
  float* out = (float*)d_out;
  float* ws = (float*)d_ws;

  const int* pp_src = pp_ei;
  const int* pp_dst = pp_ei + EPP;
  const int* dp_src = dp_ei;
  const int* dp_dst = dp_ei + EDP;
  const int* dd_src = dd_ei;
  const int* dd_dst = dd_ei + EDD;

  // ---- fast-path ws layout (units: floats) ----
  auto pad = [](size_t n){ return (n + 15) & ~(size_t)15; };
  size_t o = 0;
  size_t oPPOFF = o; o += pad(NPROT + 1);
  size_t oDPOFF = o; o += pad(NDRUG + 1);
  size_t oDDOFF = o; o += pad(NDRUG + 1);
  size_t oDIS   = o; o += pad(NPROT);
  size_t oH1    = o; o += pad((size_t)NPROT*32);
  size_t oH2    = o; o += pad((size_t)NPROT*16);
  size_t oAGG2  = o; o += pad((size_t)NPROT*16);
  size_t oXD    = o; o += pad((size_t)NDRUG*64);
  size_t oXD1   = o; o += pad((size_t)NDRUG*32);
  size_t oXDB   = o; o += pad((size_t)NDRUG*32);
  size_t oXD1B  = o; o += pad((size_t)NDRUG*16);
  size_t oWETB1 = o; o += pad((size_t)NET*1024);
  size_t oWETB2 = o; o += pad((size_t)NET*256);
  size_t oEMBB  = o; o += pad((size_t)125*768);   // 125*1536 ushort
  size_t oSRCPP = o; o += pad(EPP);
  size_t oSRCDP = o; o += pad(EDP);
  size_t oIPERM = o; o += pad(PEDD);
  size_t oPSTART= o; o += pad(NET + 1);
  size_t oPBLK  = o; o += pad(PBLKS);
  size_t oPSRC  = o; o += pad(PEDD);
  size_t oPMAPE = o; o += pad(EDD);
  size_t oCNT   = o; o += pad(NPROT);
  size_t oPSUM  = o; o += pad((size_t)SCANG*NPROT);
  size_t oGH    = o; o += pad(((size_t)NBLK*NPROT)/2);    // u16 gh
  // msgs region, aliased with xdp (disjoint lifetimes):
  size_t msgsN  = (size_t)PEDD*16;
  size_t xdpN   = (size_t)KSPLIT*NDRUG*48;
  size_t bigN   = msgsN > xdpN ? msgsN : xdpN;
  size_t oMSGS  = o; o += pad(bigN);
  size_t need_bytes = o * 4;

  if(ws_size >= need_bytes){
    // =================== FAST PATH ===================
    int* ppoff = (int*)(ws + oPPOFF);
    int* dpoff = (int*)(ws + oDPOFF);
    int* ddoff = (int*)(ws + oDDOFF);
    float* dis = ws + oDIS;
    float* h1  = ws + oH1;
    float* h2  = ws + oH2;
    float* agg2= ws + oAGG2;
    float* xd  = ws + oXD;
    float* xd1 = ws + oXD1;
    unsigned short* xdb  = (unsigned short*)(ws + oXDB);
    unsigned short* xd1b = (unsigned short*)(ws + oXD1B);
    unsigned short* wetb1 = (unsigned short*)(ws + oWETB1);
    unsigned short* wetb2 = (unsigned short*)(ws + oWETB2);
    unsigned short* embb  = (unsigned short*)(ws + oEMBB);
    int* srcpp = (int*)(ws + oSRCPP);
    int* srcdp = (int*)(ws + oSRCDP);
    int* iperm = (int*)(ws + oIPERM);
    int* pstart= (int*)(ws + oPSTART);
    int* pblk  = (int*)(ws + oPBLK);
    int* psrc  = (int*)(ws + oPSRC);
    int* pmape = (int*)(ws + oPMAPE);
    int* cnt   = (int*)(ws + oCNT);
    int* psum  = (int*)(ws + oPSUM);
    unsigned short* gh = (unsigned short*)(ws + oGH);
    float* xdp = ws + oMSGS;                              // alias (dead before msgs)
    unsigned short* msgs = (unsigned short*)(ws + oMSGS);

    // ---- padded edge layout prep ----
    hipMemsetAsync(pblk, 0, PBLKS*sizeof(int), stream);
    hipMemsetAsync(psrc, 0, PEDD*sizeof(int), stream);
    k_pstart<<<1,NET,0,stream>>>(dd_rl, pstart, pblk);
    k_pmap<<<(EDD+255)/256,256,0,stream>>>(dd_et, dd_src, dd_rl, pstart, psrc, pmape);
    k_iota<<<(PEDD+255)/256,256,0,stream>>>(iperm);

    // ---- PP CSR (packed-LDS single-pass hist, u16 gh, 2-phase scan) ----
    k_hist<20000><<<NBLK,256,0,stream>>>(pp_dst, EPP, 0, gh, NPROT);
    {
      dim3 gs((NPROT+255)/256, SCANG);
      k_scan_p1<<<gs,256,0,stream>>>(gh, psum, NPROT);
      k_scan_p2<<<gs,256,0,stream>>>(gh, psum, cnt, NPROT);
    }
    k_scan_off<<<1,1024,0,stream>>>(cnt, ppoff, NPROT);
    k_scatter<10000,0><<<NBLK,256,0,stream>>>(pp_dst, pp_src, EPP, 0, 0,     gh, ppoff, NPROT, srcpp);
    k_scatter<10000,0><<<NBLK,256,0,stream>>>(pp_dst, pp_src, EPP, 0, 10000, gh, ppoff, NPROT, srcpp);
    k_dis_off<<<(NPROT+255)/256,256,0,stream>>>(ppoff, dis, NPROT);

    // ---- PP GCN (pre-scaled features) ----
    k_gemm_s<<<(NPROT*32+255)/256,256,0,stream>>>(x_prot, W1, dis, h1, NPROT);
    k_gcn_gather1<<<NPROT,256,0,stream>>>(h1, dis, ppoff, srcpp, b1, W2, h2);
    k_gcn_gather2<<<NPROT,256,0,stream>>>(h2, dis, ppoff, srcpp, b2, agg2);

    // ---- DP CSR + hierarchy ----
    k_hist<4000><<<NBLK,256,0,stream>>>(dp_dst, EDP, NPROT, gh, NDRUG);
    {
      dim3 gs((NDRUG+255)/256, SCANG);
      k_scan_p1<<<gs,256,0,stream>>>(gh, psum, NDRUG);
      k_scan_p2<<<gs,256,0,stream>>>(gh, psum, cnt, NDRUG);
    }
    k_scan_off<<<1,1024,0,stream>>>(cnt, dpoff, NDRUG);
    k_scatter<4000,0><<<NBLK,256,0,stream>>>(dp_dst, dp_src, EDP, NPROT, 0, gh, dpoff, NDRUG, srcdp);
    k_dp_gather<<<NDRUG,256,0,stream>>>(agg2, dpoff, srcdp, hgw, xd, xdb);

    // ---- drug embedding via MFMA (xdp aliased; consumed by fin2) ----
    k_embb<<<(125*1536+255)/256,256,0,stream>>>(embed, embb);
    {
      dim3 g(63, KSPLIT);
      k_embed_m<<<g,256,0,stream>>>(x_drug, embb, xdp);
    }
    k_embed_fin2<<<(NDRUG*48+255)/256,256,0,stream>>>(xdp, d_norm, xd, xdb);

    // ---- RGCN prep (wetb built directly from att/basis) ----
    k_wetb1<<<(NET*2048+255)/256,256,0,stream>>>(att1, basis1, wetb1);
    k_wetb2<<<(NET*512+255)/256,256,0,stream>>>(att2, basis2, wetb2);
    k_hist<4000><<<NBLK,256,0,stream>>>(dd_dst, EDD, 0, gh, NDRUG);
    {
      dim3 gs((NDRUG+255)/256, SCANG);
      k_scan_p1<<<gs,256,0,stream>>>(gh, psum, NDRUG);
      k_scan_p2<<<gs,256,0,stream>>>(gh, psum, cnt, NDRUG);
    }
    k_scan_off<<<1,1024,0,stream>>>(cnt, ddoff, NDRUG);
    // iperm[padded id] = CSR position (MODE 1)
    k_scatter<4000,1><<<NBLK,256,0,stream>>>(dd_dst, pmape, EDD, 0, 0, gh, ddoff, NDRUG, iperm);

    // ---- RGCN layer 1 (MFMA, CSR-ordered msgs, streaming reduce) ----
    k_rgcn1_msgsM<<<PBLKS,256,0,stream>>>(xdb, psrc, pblk, wetb1, iperm, msgs);
    k_rgcn1_reduce<<<NDRUG,256,0,stream>>>(msgs, ddoff, xd, root1, xd1, xd1b);
    // ---- RGCN layer 2 ----
    k_rgcn2_msgsM<<<PBLKS,256,0,stream>>>(xd1b, psrc, pblk, wetb2, iperm, msgs);
    k_rgcn2_reduce<<<NDRUG,256,0,stream>>>(msgs, ddoff, xd1, root2, out);
  } else {
    // =================== FALLBACK (round-1, atomic) ===================
    int*   cnt_pp = (int*)(ws + O_CNTPP);
    float* dis    = ws + O_DIS;
    float* h1     = ws + O_H1;
    float* agg1   = ws + O_AGG1;
    float* h2     = ws + O_H2;
    float* agg2   = ws + O_AGG2;
    float* dpsum  = ws + O_DPSUM;
    int*   dpcnt  = (int*)(ws + O_DPCNT);
    float* xd     = ws + O_XD;
    float* wet1   = ws + O_WET1;
    float* wet2   = ws + O_WET2;
    int*   cntdd  = (int*)(ws + O_CNTDD);
    float* rsum1  = ws + O_RSUM1;
    float* xd1    = ws + O_XD1;
    float* rsum2  = ws + O_RSUM2;

    hipMemsetAsync(cnt_pp, 0, NPROT*sizeof(int), stream);
    hipMemsetAsync(dpsum,  0, (64000 + 4000)*sizeof(float), stream);
    hipMemsetAsync(xd,     0, NDRUG*64*sizeof(float), stream);
    hipMemsetAsync(cntdd,  0, NDRUG*sizeof(int), stream);
    hipMemsetAsync(rsum1,  0, NDRUG*32*sizeof(float), stream);
    hipMemsetAsync(rsum2,  0, NDRUG*16*sizeof(float), stream);

    k_count_int<<<(EPP+255)/256,256,0,stream>>>(pp_dst, EPP, cnt_pp);
    k_dis<<<(NPROT+255)/256,256,0,stream>>>(cnt_pp, dis, NPROT);
    k_gemm<64,32,false><<<(NPROT*32+255)/256,256,0,stream>>>(x_prot, W1, h1, NPROT);
    k_gcn_init<32><<<(NPROT*32+255)/256,256,0,stream>>>(h1, dis, b1, agg1, NPROT);
    k_gcn_scatter<32><<<(EPP*32)/256,256,0,stream>>>(h1, dis, pp_src, pp_dst, EPP, agg1);
    k_gemm<32,16,true><<<(NPROT*16+255)/256,256,0,stream>>>(agg1, W2, h2, NPROT);
    k_gcn_init<16><<<(NPROT*16+255)/256,256,0,stream>>>(h2, dis, b2, agg2, NPROT);
    k_gcn_scatter<16><<<(EPP*16)/256,256,0,stream>>>(h2, dis, pp_src, pp_dst, EPP, agg2);
    k_dp_scatter<<<(EDP*16)/256,256,0,stream>>>(agg2, dp_src, dp_dst, dpsum, dpcnt);
    k_hier<<<(NDRUG*16+255)/256,256,0,stream>>>(dpsum, dpcnt, hgw, xd);
    {
      dim3 g((NDRUG+63)/64, 8);
      k_embed<<<g,256,0,stream>>>(x_drug, embed, xd);
    }
    k_embed_fin<<<(NDRUG*48+255)/256,256,0,stream>>>(xd, d_norm);
    k_wet<<<(NET*2048+255)/256,256,0,stream>>>(att1, basis1, wet1, 2048);
    k_wet<<<(NET*512+255)/256,256,0,stream>>>(att2, basis2, wet2, 512);
    k_count_int<<<(EDD+255)/256,256,0,stream>>>(dd_dst, EDD, cntdd);
    k_rgcn1<<<EDD/64,256,0,stream>>>(xd, dd_src, dd_dst, dd_et, wet1, rsum1);
    k_root1<<<(NDRUG*32+255)/256,256,0,stream>>>(rsum1, cntdd, xd, root1, xd1);
    k_rgcn2<<<(EDD+127)/128,256,0,stream>>>(xd1, dd_src, dd_dst, dd_et, wet2, rsum2);
    k_root2<<<(NDRUG*16+255)/256,256,0,stream>>>(rsum2, cntdd, xd1, root2, out);
  }
}